// Round 6
// baseline (1499.960 us; speedup 1.0000x reference)
//
#include <hip/hip_runtime.h>

typedef unsigned short ushort_t;
typedef unsigned int uint_t;
typedef __attribute__((ext_vector_type(8))) short short8;
typedef __attribute__((ext_vector_type(4))) float f32x4;

#define NN 50000
#define NE 800000
#define NGR 256

__device__ __forceinline__ ushort_t f2b_rn(float f) {
    uint_t u = __float_as_uint(f);
    return (ushort_t)((u + 0x7fffu + ((u >> 16) & 1u)) >> 16);
}

// ---------------- CSR build ----------------
__global__ void k_deg(const int* __restrict__ dst, int* __restrict__ deg, int E) {
    int i = blockIdx.x * 256 + threadIdx.x;
    if (i < E) atomicAdd(&deg[dst[i]], 1);
}

__global__ void k_scan1(const int* __restrict__ deg, int* __restrict__ rowp,
                        int* __restrict__ bsum, int M) {
    __shared__ int sm[256];
    int t = threadIdx.x, i = blockIdx.x * 256 + t;
    int v = (i < M) ? deg[i] + 1 : 0;   // +1 self loop
    sm[t] = v; __syncthreads();
    for (int off = 1; off < 256; off <<= 1) {
        int x = (t >= off) ? sm[t - off] : 0;
        __syncthreads();
        sm[t] += x;
        __syncthreads();
    }
    if (i < M) rowp[i] = sm[t] - v;     // exclusive
    if (t == 255) bsum[blockIdx.x] = sm[255];
}

__global__ void k_scan2(int* bsum, int NB) {
    __shared__ int sm[256];
    int t = threadIdx.x;
    int v = (t < NB) ? bsum[t] : 0;
    sm[t] = v; __syncthreads();
    for (int off = 1; off < 256; off <<= 1) {
        int x = (t >= off) ? sm[t - off] : 0;
        __syncthreads();
        sm[t] += x;
        __syncthreads();
    }
    if (t < NB) bsum[t] = sm[t] - v;    // exclusive block offsets
}

__global__ void k_scan3(int* rowp, const int* __restrict__ bsum, int M, int total) {
    int i = blockIdx.x * 256 + threadIdx.x;
    if (i < M) rowp[i] += bsum[blockIdx.x];
    if (i == 0) rowp[M] = total;
}

__global__ void k_fill(const int* __restrict__ src, const int* __restrict__ dst,
                       const int* __restrict__ rowp, int* __restrict__ cur,
                       int* __restrict__ colv, int E, int M) {
    int i = blockIdx.x * 256 + threadIdx.x;
    if (i < E) {
        int d = dst[i];
        int pos = rowp[d] + atomicAdd(&cur[d], 1);
        colv[pos] = src[i];
    } else if (i < E + M) {
        int nn = i - E;
        int pos = rowp[nn] + atomicAdd(&cur[nn], 1);
        colv[pos] = nn;
    }
}

// -------- weight transpose + hi/lo bf16 split: W[K][NC] fp32 -> wT{h,l}[NC][K] --------
__global__ void k_wsplit(const float* __restrict__ W, ushort_t* __restrict__ th,
                         ushort_t* __restrict__ tl, int K, int NC) {
    int i = blockIdx.x * 256 + threadIdx.x;
    if (i < K * NC) {
        int k = i / NC, n = i % NC;
        float f = W[i];
        uint_t u = __float_as_uint(f);
        ushort_t hi = (ushort_t)(u >> 16);                       // truncate
        float rem = f - __uint_as_float(u & 0xffff0000u);
        th[n * K + k] = hi;
        tl[n * K + k] = f2b_rn(rem);
    }
}

// ---------------- MFMA GEMM: H = A @ W via split-bf16 ----------------
template<int KD, int BN>
__global__ __launch_bounds__(256)
void k_mgemm(const float* __restrict__ A, const ushort_t* __restrict__ Bth,
             const ushort_t* __restrict__ Btl, float* __restrict__ Hout,
             int M, int NC) {
    constexpr int BM = 128, BK = 32, P = 40;
    __shared__ ushort_t Ah[BM * P];
    __shared__ ushort_t Al[BM * P];
    __shared__ ushort_t Bh[BN * P];
    __shared__ ushort_t Bl[BN * P];
    const int tid = threadIdx.x;
    const int m0 = blockIdx.x * BM;
    const int n0 = blockIdx.y * BN;
    const int wave = tid >> 6, lane = tid & 63;
    const int lrow = lane & 15, lq = lane >> 4;
    constexpr int RT = (BN == 128) ? 4 : 2;
    int wm, wn;
    if constexpr (BN == 128) { wm = (wave >> 1) * 64; wn = (wave & 1) * 64; }
    else                     { wm = wave * 32;        wn = 0; }

    f32x4 acc[RT][4] = {};

    for (int k0 = 0; k0 < KD; k0 += BK) {
        #pragma unroll
        for (int it = 0; it < 4; ++it) {
            int idx = (it * 256 + tid) * 4;
            int r = idx >> 5, kk = idx & 31;
            int gm = m0 + r;
            float4 v = make_float4(0.f, 0.f, 0.f, 0.f);
            if (gm < M) v = *(const float4*)(A + (size_t)gm * KD + (k0 + kk));
            float vv[4] = {v.x, v.y, v.z, v.w};
            ushort_t hs[4], ls[4];
            #pragma unroll
            for (int j = 0; j < 4; ++j) {
                uint_t u = __float_as_uint(vv[j]);
                hs[j] = (ushort_t)(u >> 16);
                float rem = vv[j] - __uint_as_float(u & 0xffff0000u);
                ls[j] = f2b_rn(rem);
            }
            uint2 ph, pl;
            ph.x = (uint_t)hs[0] | ((uint_t)hs[1] << 16);
            ph.y = (uint_t)hs[2] | ((uint_t)hs[3] << 16);
            pl.x = (uint_t)ls[0] | ((uint_t)ls[1] << 16);
            pl.y = (uint_t)ls[2] | ((uint_t)ls[3] << 16);
            *(uint2*)&Ah[r * P + kk] = ph;
            *(uint2*)&Al[r * P + kk] = pl;
        }
        {
            constexpr int BITERS = BN / 64;
            #pragma unroll
            for (int it = 0; it < BITERS; ++it) {
                int idx = (it * 256 + tid) * 8;
                int r = idx >> 5, kk = idx & 31;
                uint4 vh = *(const uint4*)(Bth + (size_t)(n0 + r) * KD + (k0 + kk));
                uint4 vl = *(const uint4*)(Btl + (size_t)(n0 + r) * KD + (k0 + kk));
                *(uint4*)&Bh[r * P + kk] = vh;
                *(uint4*)&Bl[r * P + kk] = vl;
            }
        }
        __syncthreads();
        short8 afh[RT], afl[RT], bfh[4], bfl[4];
        #pragma unroll
        for (int r = 0; r < RT; ++r) {
            afh[r] = *(const short8*)&Ah[(wm + r * 16 + lrow) * P + lq * 8];
            afl[r] = *(const short8*)&Al[(wm + r * 16 + lrow) * P + lq * 8];
        }
        #pragma unroll
        for (int c = 0; c < 4; ++c) {
            bfh[c] = *(const short8*)&Bh[(wn + c * 16 + lrow) * P + lq * 8];
            bfl[c] = *(const short8*)&Bl[(wn + c * 16 + lrow) * P + lq * 8];
        }
        #pragma unroll
        for (int r = 0; r < RT; ++r)
            #pragma unroll
            for (int c = 0; c < 4; ++c) {
                acc[r][c] = __builtin_amdgcn_mfma_f32_16x16x32_bf16(afh[r], bfh[c], acc[r][c], 0, 0, 0);
                acc[r][c] = __builtin_amdgcn_mfma_f32_16x16x32_bf16(afh[r], bfl[c], acc[r][c], 0, 0, 0);
                acc[r][c] = __builtin_amdgcn_mfma_f32_16x16x32_bf16(afl[r], bfh[c], acc[r][c], 0, 0, 0);
            }
        __syncthreads();
    }
    #pragma unroll
    for (int r = 0; r < RT; ++r) {
        #pragma unroll
        for (int c = 0; c < 4; ++c) {
            int colg = n0 + wn + c * 16 + lrow;
            #pragma unroll
            for (int j = 0; j < 4; ++j) {
                int row = m0 + wm + r * 16 + lq * 4 + j;
                if (row < M) Hout[(size_t)row * NC + colg] = acc[r][c][j];
            }
        }
    }
}

// ---------------- attention logits: al_s/al_d [N][H] ----------------
template<int H>
__global__ __launch_bounds__(256)
void k_al(const float* __restrict__ h, const float* __restrict__ a_s,
          const float* __restrict__ a_d, float* __restrict__ als,
          float* __restrict__ ald, int M) {
    int node = blockIdx.x * 4 + (threadIdx.x >> 6);
    if (node >= M) return;
    int lane = threadIdx.x & 63;
    constexpr int HC = H * 64;
    float ss[H], dd[H];
    #pragma unroll
    for (int j = 0; j < H; ++j) {
        float hv = h[(size_t)node * HC + j * 64 + lane];
        float ps = hv * a_s[j * 64 + lane];
        float pd = hv * a_d[j * 64 + lane];
        #pragma unroll
        for (int off = 32; off; off >>= 1) {
            ps += __shfl_xor(ps, off);
            pd += __shfl_xor(pd, off);
        }
        ss[j] = ps; dd[j] = pd;
    }
    if (lane == 0) {
        #pragma unroll
        for (int j = 0; j < H; ++j) {
            als[node * H + j] = ss[j];
            ald[node * H + j] = dd[j];
        }
    }
}

// ---- phase 1: per-(node,head) softmax shift: S = mx + log(den) (wave per node) ----
// alpha_edge = exp(e - S); den>=1 so +1e-16 is a no-op in fp32.
template<int H>
__global__ __launch_bounds__(256)
void k_att(const float* __restrict__ als, const float* __restrict__ ald,
           const int* __restrict__ rowp, const int* __restrict__ colv,
           float* __restrict__ sdn, int M) {
    constexpr int LPH = 64 / H;
    int node = blockIdx.x * 4 + (threadIdx.x >> 6);
    if (node >= M) return;
    int lane = threadIdx.x & 63;
    int rs = rowp[node], re = rowp[node + 1];
    int hh = lane / LPH;
    float ad = ald[node * H + hh];
    float mx = -3.0e38f;
    for (int i = rs + (lane % LPH); i < re; i += LPH) {
        int s = colv[i];
        float e = als[s * H + hh] + ad;
        e = e > 0.f ? e : 0.2f * e;
        mx = fmaxf(mx, e);
    }
    #pragma unroll
    for (int off = LPH >> 1; off; off >>= 1) mx = fmaxf(mx, __shfl_xor(mx, off));
    float den = 0.f;
    for (int i = rs + (lane % LPH); i < re; i += LPH) {
        int s = colv[i];
        float e = als[s * H + hh] + ad;
        e = e > 0.f ? e : 0.2f * e;
        den += __expf(e - mx);
    }
    #pragma unroll
    for (int off = LPH >> 1; off; off >>= 1) den += __shfl_xor(den, off);
    if ((lane % LPH) == 0) sdn[node * H + hh] = mx + __logf(den);
}

// ---- phase 2: chunked aggregation + bias + BN + ELU ----
// blockIdx.y = 16-dim chunk; gathered chunk footprint 50k*16*4B = 3.2MB (L2-resident).
// Wave per node: lane = e*16 + d  (4 edges x 16 dims in parallel).
template<int H>
__global__ __launch_bounds__(256)
void k_aggc(const float* __restrict__ h, const float* __restrict__ als,
            const float* __restrict__ ald, const float* __restrict__ sdn,
            const int* __restrict__ rowp, const int* __restrict__ colv,
            const float* __restrict__ bias, const float* __restrict__ gam,
            const float* __restrict__ bet, const float* __restrict__ mu,
            const float* __restrict__ var, float* __restrict__ xout, int M) {
    constexpr int HC = H * 64;
    int node = blockIdx.x * 4 + (threadIdx.x >> 6);
    if (node >= M) return;
    int lane = threadIdx.x & 63;
    int c0 = blockIdx.y * 16;           // chunk start dim; chunk lies in one head
    int hh = c0 >> 6;
    int d = lane & 15, eg = lane >> 4;
    int rs = rowp[node], re = rowp[node + 1];
    float adS = ald[node * H + hh] - sdn[node * H + hh];
    float acc = 0.f;
    for (int i = rs + eg; i < re; i += 4) {
        int s = colv[i];
        float e = als[s * H + hh] + (adS + sdn[node * H + hh]) - sdn[node * H + hh];
        // recompute exactly as phase 1: lrelu first, then shift
        float e0 = als[s * H + hh] + ald[node * H + hh];
        e0 = e0 > 0.f ? e0 : 0.2f * e0;
        float ee = __expf(e0 - sdn[node * H + hh]);
        acc += ee * h[(size_t)s * HC + c0 + d];
        (void)e;
    }
    acc += __shfl_xor(acc, 16);
    acc += __shfl_xor(acc, 32);
    if (lane < 16) {
        int dim = c0 + d;
        float o = acc + bias[dim];
        float bn = (o - mu[dim]) * rsqrtf(var[dim] + 1e-5f) * gam[dim] + bet[dim];
        xout[(size_t)node * HC + dim] = bn > 0.f ? bn : (__expf(bn) - 1.f);
    }
}

// ---------------- pooling (block per graph, batch sorted -> binary search) ----------------
__global__ void k_pool(const float* __restrict__ x, const int* __restrict__ batch,
                       float* __restrict__ pooled, int M) {
    int g = blockIdx.x, lane = threadIdx.x; // 64 threads
    int lo = 0, hi = M;
    while (lo < hi) { int mid = (lo + hi) >> 1; if (batch[mid] < g) lo = mid + 1; else hi = mid; }
    int s = lo;
    lo = 0; hi = M;
    while (lo < hi) { int mid = (lo + hi) >> 1; if (batch[mid] < g + 1) lo = mid + 1; else hi = mid; }
    int e = lo;
    float sum = 0.f, mx = -3.0e38f;
    for (int n = s; n < e; ++n) {
        float v = x[(size_t)n * 64 + lane];
        sum += v; mx = fmaxf(mx, v);
    }
    int cnt = e - s;
    float mean = sum / (float)(cnt > 1 ? cnt : 1);
    if (cnt == 0) mx = 0.f;
    pooled[g * 192 + lane] = mean;
    pooled[g * 192 + 64 + lane] = mx;
    pooled[g * 192 + 128 + lane] = sum;
}

// ---------------- final MLP ----------------
__global__ void k_fc(const float* __restrict__ pooled,
                     const float* __restrict__ fc1w, const float* __restrict__ fc1b,
                     const float* __restrict__ fc2w, const float* __restrict__ fc2b,
                     const float* __restrict__ fc3w, const float* __restrict__ fc3b,
                     float* __restrict__ out) {
    __shared__ float hb[192];
    __shared__ float h1[64];
    __shared__ float h2[32];
    int g = blockIdx.x, t = threadIdx.x; // 64 threads
    for (int j = t; j < 192; j += 64) hb[j] = pooled[g * 192 + j];
    __syncthreads();
    float s = fc1b[t];
    for (int k = 0; k < 192; ++k) s += hb[k] * fc1w[k * 64 + t];
    h1[t] = fmaxf(s, 0.f);
    __syncthreads();
    if (t < 32) {
        float s2 = fc2b[t];
        for (int k = 0; k < 64; ++k) s2 += h1[k] * fc2w[k * 32 + t];
        h2[t] = fmaxf(s2, 0.f);
    }
    __syncthreads();
    if (t == 0) {
        float s3 = fc3b[0];
        for (int k = 0; k < 32; ++k) s3 += h2[k] * fc3w[k];
        out[g] = s3;
    }
}

extern "C" void kernel_launch(void* const* d_in, const int* in_sizes, int n_in,
                              void* d_out, int out_size, void* d_ws, size_t ws_size,
                              hipStream_t stream) {
    const float* x0     = (const float*)d_in[0];
    const int* ei       = (const int*)d_in[1];
    const int* batch    = (const int*)d_in[2];
    const float* W[3]   = {(const float*)d_in[3],  (const float*)d_in[11], (const float*)d_in[19]};
    const float* AS[3]  = {(const float*)d_in[4],  (const float*)d_in[12], (const float*)d_in[20]};
    const float* AD[3]  = {(const float*)d_in[5],  (const float*)d_in[13], (const float*)d_in[21]};
    const float* BI[3]  = {(const float*)d_in[6],  (const float*)d_in[14], (const float*)d_in[22]};
    const float* GA[3]  = {(const float*)d_in[7],  (const float*)d_in[15], (const float*)d_in[23]};
    const float* BE[3]  = {(const float*)d_in[8],  (const float*)d_in[16], (const float*)d_in[24]};
    const float* MU[3]  = {(const float*)d_in[9],  (const float*)d_in[17], (const float*)d_in[25]};
    const float* VA[3]  = {(const float*)d_in[10], (const float*)d_in[18], (const float*)d_in[26]};
    const float* fc1w = (const float*)d_in[27];
    const float* fc1b = (const float*)d_in[28];
    const float* fc2w = (const float*)d_in[29];
    const float* fc2b = (const float*)d_in[30];
    const float* fc3w = (const float*)d_in[31];
    const float* fc3b = (const float*)d_in[32];

    // Tight layout: top of use = 108,863,488 B (< 108,953,600 B proven safe in R4).
    char* ws = (char*)d_ws;
    int*   rowp   = (int*)  (ws);                      // 200,004 B
    int*   colv   = (int*)  (ws + 200704);             // 3,400,000 B
    int*   bsum   = (int*)  (ws + 3600704);            // 1,024 B
    float* als    = (float*)(ws + 3602432);            // 800,000 B
    int*   cur    = (int*)  (ws + 3602432);            // 200,000 B (aliases als; dead before k_al)
    float* ald    = (float*)(ws + 4402432);            // 800,000 B
    float* sdn    = (float*)(ws + 5202432);            // 800,000 B
    ushort_t* wTh = (ushort_t*)(ws + 6002432);         // 131,072 B
    ushort_t* wTl = (ushort_t*)(ws + 6133504);         // 131,072 B
    float* pooled = (float*)(ws + 6264576);            // 196,608 B
    float* h_buf  = (float*)(ws + 6463488);            // 51,200,000 B
    float* x_buf  = (float*)(ws + 57663488);           // 51,200,000 B -> 108,863,488 B

    const int* esrc = ei;
    const int* edst = ei + NE;
    const int NB_SCAN = (NN + 255) / 256; // 196

    // CSR build
    hipMemsetAsync(cur, 0, NN * sizeof(int), stream);
    k_deg<<<(NE + 255) / 256, 256, 0, stream>>>(edst, cur, NE);
    k_scan1<<<NB_SCAN, 256, 0, stream>>>(cur, rowp, bsum, NN);
    k_scan2<<<1, 256, 0, stream>>>(bsum, NB_SCAN);
    k_scan3<<<NB_SCAN, 256, 0, stream>>>(rowp, bsum, NN, NE + NN);
    hipMemsetAsync(cur, 0, NN * sizeof(int), stream);
    k_fill<<<(NE + NN + 255) / 256, 256, 0, stream>>>(esrc, edst, rowp, cur, colv, NE, NN);

    const int GB = (NN + 127) / 128; // 391
    int nwb = (NN + 3) / 4;          // 12500

    // ---- layer 0 (K=128, HC=256, H=4)
    k_wsplit<<<(128 * 256 + 255) / 256, 256, 0, stream>>>(W[0], wTh, wTl, 128, 256);
    k_mgemm<128, 128><<<dim3(GB, 2), 256, 0, stream>>>(x0, wTh, wTl, h_buf, NN, 256);
    k_al<4><<<nwb, 256, 0, stream>>>(h_buf, AS[0], AD[0], als, ald, NN);
    k_att<4><<<nwb, 256, 0, stream>>>(als, ald, rowp, colv, sdn, NN);
    k_aggc<4><<<dim3(nwb, 16), 256, 0, stream>>>(h_buf, als, ald, sdn, rowp, colv,
                                                 BI[0], GA[0], BE[0], MU[0], VA[0], x_buf, NN);
    // ---- layer 1 (K=256, HC=256, H=4)
    k_wsplit<<<(256 * 256 + 255) / 256, 256, 0, stream>>>(W[1], wTh, wTl, 256, 256);
    k_mgemm<256, 128><<<dim3(GB, 2), 256, 0, stream>>>(x_buf, wTh, wTl, h_buf, NN, 256);
    k_al<4><<<nwb, 256, 0, stream>>>(h_buf, AS[1], AD[1], als, ald, NN);
    k_att<4><<<nwb, 256, 0, stream>>>(als, ald, rowp, colv, sdn, NN);
    k_aggc<4><<<dim3(nwb, 16), 256, 0, stream>>>(h_buf, als, ald, sdn, rowp, colv,
                                                 BI[1], GA[1], BE[1], MU[1], VA[1], x_buf, NN);
    // ---- layer 2 (K=256, HC=64, H=1)
    k_wsplit<<<(256 * 64 + 255) / 256, 256, 0, stream>>>(W[2], wTh, wTl, 256, 64);
    k_mgemm<256, 64><<<dim3(GB, 1), 256, 0, stream>>>(x_buf, wTh, wTl, h_buf, NN, 64);
    k_al<1><<<nwb, 256, 0, stream>>>(h_buf, AS[2], AD[2], als, ald, NN);
    k_att<1><<<nwb, 256, 0, stream>>>(als, ald, rowp, colv, sdn, NN);
    k_aggc<1><<<dim3(nwb, 4), 256, 0, stream>>>(h_buf, als, ald, sdn, rowp, colv,
                                                BI[2], GA[2], BE[2], MU[2], VA[2], x_buf, NN);

    // readout + MLP
    k_pool<<<NGR, 64, 0, stream>>>(x_buf, batch, pooled, NN);
    k_fc<<<NGR, 64, 0, stream>>>(pooled, fc1w, fc1b, fc2w, fc2b, fc3w, fc3b,
                                 (float*)d_out);
    (void)in_sizes; (void)n_in; (void)out_size; (void)ws_size;
}

// Round 7
// 763.475 us; speedup vs baseline: 1.9646x; 1.9646x over previous
//
#include <hip/hip_runtime.h>
#include <hip/hip_fp16.h>

typedef unsigned short ushort_t;
typedef unsigned int uint_t;
typedef __attribute__((ext_vector_type(8))) short short8;
typedef __attribute__((ext_vector_type(4))) float f32x4;

#define NN 50000
#define NE 800000
#define NGR 256

__device__ __forceinline__ ushort_t f2b_rn(float f) {
    uint_t u = __float_as_uint(f);
    return (ushort_t)((u + 0x7fffu + ((u >> 16) & 1u)) >> 16);
}

// ---------------- CSR build ----------------
__global__ void k_deg(const int* __restrict__ dst, int* __restrict__ deg, int E) {
    int i = blockIdx.x * 256 + threadIdx.x;
    if (i < E) atomicAdd(&deg[dst[i]], 1);
}

__global__ void k_scan1(const int* __restrict__ deg, int* __restrict__ rowp,
                        int* __restrict__ bsum, int M) {
    __shared__ int sm[256];
    int t = threadIdx.x, i = blockIdx.x * 256 + t;
    int v = (i < M) ? deg[i] + 1 : 0;   // +1 self loop
    sm[t] = v; __syncthreads();
    for (int off = 1; off < 256; off <<= 1) {
        int x = (t >= off) ? sm[t - off] : 0;
        __syncthreads();
        sm[t] += x;
        __syncthreads();
    }
    if (i < M) rowp[i] = sm[t] - v;     // exclusive
    if (t == 255) bsum[blockIdx.x] = sm[255];
}

__global__ void k_scan2(int* bsum, int NB) {
    __shared__ int sm[256];
    int t = threadIdx.x;
    int v = (t < NB) ? bsum[t] : 0;
    sm[t] = v; __syncthreads();
    for (int off = 1; off < 256; off <<= 1) {
        int x = (t >= off) ? sm[t - off] : 0;
        __syncthreads();
        sm[t] += x;
        __syncthreads();
    }
    if (t < NB) bsum[t] = sm[t] - v;    // exclusive block offsets
}

__global__ void k_scan3(int* rowp, const int* __restrict__ bsum, int M, int total) {
    int i = blockIdx.x * 256 + threadIdx.x;
    if (i < M) rowp[i] += bsum[blockIdx.x];
    if (i == 0) rowp[M] = total;
}

__global__ void k_fill(const int* __restrict__ src, const int* __restrict__ dst,
                       const int* __restrict__ rowp, int* __restrict__ cur,
                       int* __restrict__ colv, int E, int M) {
    int i = blockIdx.x * 256 + threadIdx.x;
    if (i < E) {
        int d = dst[i];
        int pos = rowp[d] + atomicAdd(&cur[d], 1);
        colv[pos] = src[i];
    } else if (i < E + M) {
        int nn = i - E;
        int pos = rowp[nn] + atomicAdd(&cur[nn], 1);
        colv[pos] = nn;
    }
}

// -------- weight transpose + hi/lo bf16 split: W[K][NC] fp32 -> wT{h,l}[NC][K] --------
__global__ void k_wsplit(const float* __restrict__ W, ushort_t* __restrict__ th,
                         ushort_t* __restrict__ tl, int K, int NC) {
    int i = blockIdx.x * 256 + threadIdx.x;
    if (i < K * NC) {
        int k = i / NC, n = i % NC;
        float f = W[i];
        uint_t u = __float_as_uint(f);
        ushort_t hi = (ushort_t)(u >> 16);                       // truncate
        float rem = f - __uint_as_float(u & 0xffff0000u);
        th[n * K + k] = hi;
        tl[n * K + k] = f2b_rn(rem);
    }
}

// ---------------- MFMA GEMM: H = A @ W via split-bf16, fp16 output ----------------
template<int KD, int BN>
__global__ __launch_bounds__(256)
void k_mgemm(const float* __restrict__ A, const ushort_t* __restrict__ Bth,
             const ushort_t* __restrict__ Btl, __half* __restrict__ Hout,
             int M, int NC) {
    constexpr int BM = 128, BK = 32, P = 40;
    __shared__ ushort_t Ah[BM * P];
    __shared__ ushort_t Al[BM * P];
    __shared__ ushort_t Bh[BN * P];
    __shared__ ushort_t Bl[BN * P];
    const int tid = threadIdx.x;
    const int m0 = blockIdx.x * BM;
    const int n0 = blockIdx.y * BN;
    const int wave = tid >> 6, lane = tid & 63;
    const int lrow = lane & 15, lq = lane >> 4;
    constexpr int RT = (BN == 128) ? 4 : 2;
    int wm, wn;
    if constexpr (BN == 128) { wm = (wave >> 1) * 64; wn = (wave & 1) * 64; }
    else                     { wm = wave * 32;        wn = 0; }

    f32x4 acc[RT][4] = {};

    for (int k0 = 0; k0 < KD; k0 += BK) {
        #pragma unroll
        for (int it = 0; it < 4; ++it) {
            int idx = (it * 256 + tid) * 4;
            int r = idx >> 5, kk = idx & 31;
            int gm = m0 + r;
            float4 v = make_float4(0.f, 0.f, 0.f, 0.f);
            if (gm < M) v = *(const float4*)(A + (size_t)gm * KD + (k0 + kk));
            float vv[4] = {v.x, v.y, v.z, v.w};
            ushort_t hs[4], ls[4];
            #pragma unroll
            for (int j = 0; j < 4; ++j) {
                uint_t u = __float_as_uint(vv[j]);
                hs[j] = (ushort_t)(u >> 16);
                float rem = vv[j] - __uint_as_float(u & 0xffff0000u);
                ls[j] = f2b_rn(rem);
            }
            uint2 ph, pl;
            ph.x = (uint_t)hs[0] | ((uint_t)hs[1] << 16);
            ph.y = (uint_t)hs[2] | ((uint_t)hs[3] << 16);
            pl.x = (uint_t)ls[0] | ((uint_t)ls[1] << 16);
            pl.y = (uint_t)ls[2] | ((uint_t)ls[3] << 16);
            *(uint2*)&Ah[r * P + kk] = ph;
            *(uint2*)&Al[r * P + kk] = pl;
        }
        {
            constexpr int BITERS = BN / 64;
            #pragma unroll
            for (int it = 0; it < BITERS; ++it) {
                int idx = (it * 256 + tid) * 8;
                int r = idx >> 5, kk = idx & 31;
                uint4 vh = *(const uint4*)(Bth + (size_t)(n0 + r) * KD + (k0 + kk));
                uint4 vl = *(const uint4*)(Btl + (size_t)(n0 + r) * KD + (k0 + kk));
                *(uint4*)&Bh[r * P + kk] = vh;
                *(uint4*)&Bl[r * P + kk] = vl;
            }
        }
        __syncthreads();
        short8 afh[RT], afl[RT], bfh[4], bfl[4];
        #pragma unroll
        for (int r = 0; r < RT; ++r) {
            afh[r] = *(const short8*)&Ah[(wm + r * 16 + lrow) * P + lq * 8];
            afl[r] = *(const short8*)&Al[(wm + r * 16 + lrow) * P + lq * 8];
        }
        #pragma unroll
        for (int c = 0; c < 4; ++c) {
            bfh[c] = *(const short8*)&Bh[(wn + c * 16 + lrow) * P + lq * 8];
            bfl[c] = *(const short8*)&Bl[(wn + c * 16 + lrow) * P + lq * 8];
        }
        #pragma unroll
        for (int r = 0; r < RT; ++r)
            #pragma unroll
            for (int c = 0; c < 4; ++c) {
                acc[r][c] = __builtin_amdgcn_mfma_f32_16x16x32_bf16(afh[r], bfh[c], acc[r][c], 0, 0, 0);
                acc[r][c] = __builtin_amdgcn_mfma_f32_16x16x32_bf16(afh[r], bfl[c], acc[r][c], 0, 0, 0);
                acc[r][c] = __builtin_amdgcn_mfma_f32_16x16x32_bf16(afl[r], bfh[c], acc[r][c], 0, 0, 0);
            }
        __syncthreads();
    }
    #pragma unroll
    for (int r = 0; r < RT; ++r) {
        #pragma unroll
        for (int c = 0; c < 4; ++c) {
            int colg = n0 + wn + c * 16 + lrow;
            #pragma unroll
            for (int j = 0; j < 4; ++j) {
                int row = m0 + wm + r * 16 + lq * 4 + j;
                if (row < M) Hout[(size_t)row * NC + colg] = __float2half(acc[r][c][j]);
            }
        }
    }
}

// ---------------- attention logits: al_s/al_d [N][H] (h in fp16) ----------------
template<int H>
__global__ __launch_bounds__(256)
void k_al(const __half* __restrict__ h, const float* __restrict__ a_s,
          const float* __restrict__ a_d, float* __restrict__ als,
          float* __restrict__ ald, int M) {
    int node = blockIdx.x * 4 + (threadIdx.x >> 6);
    if (node >= M) return;
    int lane = threadIdx.x & 63;
    constexpr int HC = H * 64;
    float ss[H], dd[H];
    #pragma unroll
    for (int j = 0; j < H; ++j) {
        float hv = __half2float(h[(size_t)node * HC + j * 64 + lane]);
        float ps = hv * a_s[j * 64 + lane];
        float pd = hv * a_d[j * 64 + lane];
        #pragma unroll
        for (int off = 32; off; off >>= 1) {
            ps += __shfl_xor(ps, off);
            pd += __shfl_xor(pd, off);
        }
        ss[j] = ps; dd[j] = pd;
    }
    if (lane == 0) {
        #pragma unroll
        for (int j = 0; j < H; ++j) {
            als[node * H + j] = ss[j];
            ald[node * H + j] = dd[j];
        }
    }
}

// ---- fused aggregation + bias + BN + ELU (wave per dst node, fp16 h gather) ----
template<int H>
__global__ __launch_bounds__(256)
void k_agg(const __half* __restrict__ h, const float* __restrict__ als,
           const float* __restrict__ ald, const int* __restrict__ rowp,
           const int* __restrict__ colv,
           const float* __restrict__ bias, const float* __restrict__ gam,
           const float* __restrict__ bet, const float* __restrict__ mu,
           const float* __restrict__ var, float* __restrict__ xout, int M) {
    constexpr int HC = H * 64;
    constexpr int LPH = 64 / H;     // lanes per head group (pass A parallelism)
    constexpr int D = HC / 64;      // dims per lane in pass B
    int node = blockIdx.x * 4 + (threadIdx.x >> 6);
    if (node >= M) return;
    int lane = threadIdx.x & 63;
    int rs = rowp[node], re = rowp[node + 1];
    int hh = lane / LPH;
    float ad = ald[node * H + hh];
    // pass A: per-head max of leaky_relu(al_s[src]+al_d[dst])
    float mx = -3.0e38f;
    for (int i = rs + (lane % LPH); i < re; i += LPH) {
        int s = colv[i];
        float e = als[s * H + hh] + ad;
        e = e > 0.f ? e : 0.2f * e;
        mx = fmaxf(mx, e);
    }
    #pragma unroll
    for (int off = LPH >> 1; off; off >>= 1) mx = fmaxf(mx, __shfl_xor(mx, off));
    // pass B: den = sum(ee), acc = sum(ee * h[src])
    float den = 0.f;
    float acc[D] = {0.f};
    for (int i = rs; i < re; ++i) {
        int s = colv[i];
        float e = als[s * H + hh] + ad;
        e = e > 0.f ? e : 0.2f * e;
        float ee = __expf(e - mx);
        den += ee;
        if constexpr (D == 4) {
            const __half2* hp2 = (const __half2*)(h + (size_t)s * HC + lane * 4);
            float2 f01 = __half22float2(hp2[0]);
            float2 f23 = __half22float2(hp2[1]);
            acc[0] += ee * f01.x; acc[1] += ee * f01.y;
            acc[2] += ee * f23.x; acc[3] += ee * f23.y;
        } else {
            acc[0] += ee * __half2float(h[(size_t)s * HC + lane]);
        }
    }
    float inv = 1.f / (den + 1e-16f);
    #pragma unroll
    for (int j = 0; j < D; ++j) {
        int d = lane * D + j;
        float o = acc[j] * inv + bias[d];
        float bn = (o - mu[d]) * rsqrtf(var[d] + 1e-5f) * gam[d] + bet[d];
        float el = bn > 0.f ? bn : (__expf(bn) - 1.f);
        xout[(size_t)node * HC + d] = el;
    }
}

// ---------------- pooling (block per graph, batch sorted -> binary search) ----------------
__global__ void k_pool(const float* __restrict__ x, const int* __restrict__ batch,
                       float* __restrict__ pooled, int M) {
    int g = blockIdx.x, lane = threadIdx.x; // 64 threads
    int lo = 0, hi = M;
    while (lo < hi) { int mid = (lo + hi) >> 1; if (batch[mid] < g) lo = mid + 1; else hi = mid; }
    int s = lo;
    lo = 0; hi = M;
    while (lo < hi) { int mid = (lo + hi) >> 1; if (batch[mid] < g + 1) lo = mid + 1; else hi = mid; }
    int e = lo;
    float sum = 0.f, mx = -3.0e38f;
    for (int n = s; n < e; ++n) {
        float v = x[(size_t)n * 64 + lane];
        sum += v; mx = fmaxf(mx, v);
    }
    int cnt = e - s;
    float mean = sum / (float)(cnt > 1 ? cnt : 1);
    if (cnt == 0) mx = 0.f;
    pooled[g * 192 + lane] = mean;
    pooled[g * 192 + 64 + lane] = mx;
    pooled[g * 192 + 128 + lane] = sum;
}

// ---------------- final MLP ----------------
__global__ void k_fc(const float* __restrict__ pooled,
                     const float* __restrict__ fc1w, const float* __restrict__ fc1b,
                     const float* __restrict__ fc2w, const float* __restrict__ fc2b,
                     const float* __restrict__ fc3w, const float* __restrict__ fc3b,
                     float* __restrict__ out) {
    __shared__ float hb[192];
    __shared__ float h1[64];
    __shared__ float h2[32];
    int g = blockIdx.x, t = threadIdx.x; // 64 threads
    for (int j = t; j < 192; j += 64) hb[j] = pooled[g * 192 + j];
    __syncthreads();
    float s = fc1b[t];
    for (int k = 0; k < 192; ++k) s += hb[k] * fc1w[k * 64 + t];
    h1[t] = fmaxf(s, 0.f);
    __syncthreads();
    if (t < 32) {
        float s2 = fc2b[t];
        for (int k = 0; k < 64; ++k) s2 += h1[k] * fc2w[k * 32 + t];
        h2[t] = fmaxf(s2, 0.f);
    }
    __syncthreads();
    if (t == 0) {
        float s3 = fc3b[0];
        for (int k = 0; k < 32; ++k) s3 += h2[k] * fc3w[k];
        out[g] = s3;
    }
}

extern "C" void kernel_launch(void* const* d_in, const int* in_sizes, int n_in,
                              void* d_out, int out_size, void* d_ws, size_t ws_size,
                              hipStream_t stream) {
    const float* x0     = (const float*)d_in[0];
    const int* ei       = (const int*)d_in[1];
    const int* batch    = (const int*)d_in[2];
    const float* W[3]   = {(const float*)d_in[3],  (const float*)d_in[11], (const float*)d_in[19]};
    const float* AS[3]  = {(const float*)d_in[4],  (const float*)d_in[12], (const float*)d_in[20]};
    const float* AD[3]  = {(const float*)d_in[5],  (const float*)d_in[13], (const float*)d_in[21]};
    const float* BI[3]  = {(const float*)d_in[6],  (const float*)d_in[14], (const float*)d_in[22]};
    const float* GA[3]  = {(const float*)d_in[7],  (const float*)d_in[15], (const float*)d_in[23]};
    const float* BE[3]  = {(const float*)d_in[8],  (const float*)d_in[16], (const float*)d_in[24]};
    const float* MU[3]  = {(const float*)d_in[9],  (const float*)d_in[17], (const float*)d_in[25]};
    const float* VA[3]  = {(const float*)d_in[10], (const float*)d_in[18], (const float*)d_in[26]};
    const float* fc1w = (const float*)d_in[27];
    const float* fc1b = (const float*)d_in[28];
    const float* fc2w = (const float*)d_in[29];
    const float* fc2b = (const float*)d_in[30];
    const float* fc3w = (const float*)d_in[31];
    const float* fc3b = (const float*)d_in[32];

    // fp16 h_buf: total top-of-use = 83,263,488 B (< 108,953,600 B proven safe).
    char* ws = (char*)d_ws;
    int*   rowp   = (int*)  (ws);                      // 200,004 B
    int*   colv   = (int*)  (ws + 200704);             // 3,400,000 B
    int*   bsum   = (int*)  (ws + 3600704);            // 1,024 B
    float* als    = (float*)(ws + 3602432);            // 800,000 B
    int*   cur    = (int*)  (ws + 3602432);            // 200,000 B (aliases als; dead before k_al)
    float* ald    = (float*)(ws + 4402432);            // 800,000 B
    ushort_t* wTh = (ushort_t*)(ws + 5202432);         // 131,072 B
    ushort_t* wTl = (ushort_t*)(ws + 5333504);         // 131,072 B
    float* pooled = (float*)(ws + 5464576);            // 196,608 B
    __half* h_buf = (__half*)(ws + 5661184);           // 25,600,000 B
    float* x_buf  = (float*)(ws + 31261184);           // 51,200,000 B -> 82,461,184 B

    const int* esrc = ei;
    const int* edst = ei + NE;
    const int NB_SCAN = (NN + 255) / 256; // 196

    // CSR build
    hipMemsetAsync(cur, 0, NN * sizeof(int), stream);
    k_deg<<<(NE + 255) / 256, 256, 0, stream>>>(edst, cur, NE);
    k_scan1<<<NB_SCAN, 256, 0, stream>>>(cur, rowp, bsum, NN);
    k_scan2<<<1, 256, 0, stream>>>(bsum, NB_SCAN);
    k_scan3<<<NB_SCAN, 256, 0, stream>>>(rowp, bsum, NN, NE + NN);
    hipMemsetAsync(cur, 0, NN * sizeof(int), stream);
    k_fill<<<(NE + NN + 255) / 256, 256, 0, stream>>>(esrc, edst, rowp, cur, colv, NE, NN);

    const int GB = (NN + 127) / 128; // 391
    int nwb = (NN + 3) / 4;          // 12500

    // ---- layer 0 (K=128, HC=256, H=4)
    k_wsplit<<<(128 * 256 + 255) / 256, 256, 0, stream>>>(W[0], wTh, wTl, 128, 256);
    k_mgemm<128, 128><<<dim3(GB, 2), 256, 0, stream>>>(x0, wTh, wTl, h_buf, NN, 256);
    k_al<4><<<nwb, 256, 0, stream>>>(h_buf, AS[0], AD[0], als, ald, NN);
    k_agg<4><<<nwb, 256, 0, stream>>>(h_buf, als, ald, rowp, colv,
                                      BI[0], GA[0], BE[0], MU[0], VA[0], x_buf, NN);
    // ---- layer 1 (K=256, HC=256, H=4)
    k_wsplit<<<(256 * 256 + 255) / 256, 256, 0, stream>>>(W[1], wTh, wTl, 256, 256);
    k_mgemm<256, 128><<<dim3(GB, 2), 256, 0, stream>>>(x_buf, wTh, wTl, h_buf, NN, 256);
    k_al<4><<<nwb, 256, 0, stream>>>(h_buf, AS[1], AD[1], als, ald, NN);
    k_agg<4><<<nwb, 256, 0, stream>>>(h_buf, als, ald, rowp, colv,
                                      BI[1], GA[1], BE[1], MU[1], VA[1], x_buf, NN);
    // ---- layer 2 (K=256, HC=64, H=1)
    k_wsplit<<<(256 * 64 + 255) / 256, 256, 0, stream>>>(W[2], wTh, wTl, 256, 64);
    k_mgemm<256, 64><<<dim3(GB, 1), 256, 0, stream>>>(x_buf, wTh, wTl, h_buf, NN, 64);
    k_al<1><<<nwb, 256, 0, stream>>>(h_buf, AS[2], AD[2], als, ald, NN);
    k_agg<1><<<nwb, 256, 0, stream>>>(h_buf, als, ald, rowp, colv,
                                      BI[2], GA[2], BE[2], MU[2], VA[2], x_buf, NN);

    // readout + MLP
    k_pool<<<NGR, 64, 0, stream>>>(x_buf, batch, pooled, NN);
    k_fc<<<NGR, 64, 0, stream>>>(pooled, fc1w, fc1b, fc2w, fc2b, fc3w, fc3b,
                                 (float*)d_out);
    (void)in_sizes; (void)n_in; (void)out_size; (void)ws_size;
}

// Round 8
// 751.524 us; speedup vs baseline: 1.9959x; 1.0159x over previous
//
#include <hip/hip_runtime.h>
#include <hip/hip_fp16.h>

typedef unsigned short ushort_t;
typedef unsigned int uint_t;
typedef __attribute__((ext_vector_type(8))) short short8;
typedef __attribute__((ext_vector_type(4))) float f32x4;

#define NN 50000
#define NE 800000
#define NGR 256

__device__ __forceinline__ ushort_t f2b_rn(float f) {
    uint_t u = __float_as_uint(f);
    return (ushort_t)((u + 0x7fffu + ((u >> 16) & 1u)) >> 16);
}

// async global->LDS, 16B per lane; LDS dest = wave-uniform base + lane*16
typedef __attribute__((address_space(3))) unsigned int as3_u32;
typedef const __attribute__((address_space(1))) unsigned int as1_u32c;
__device__ __forceinline__ void gld16(const ushort_t* g, void* lds_base) {
    __builtin_amdgcn_global_load_lds((as1_u32c*)g, (as3_u32*)lds_base, 16, 0, 0);
}

// ---------------- CSR build ----------------
__global__ void k_deg(const int* __restrict__ dst, int* __restrict__ deg, int E) {
    int i = blockIdx.x * 256 + threadIdx.x;
    if (i < E) atomicAdd(&deg[dst[i]], 1);
}

__global__ void k_scan1(const int* __restrict__ deg, int* __restrict__ rowp,
                        int* __restrict__ bsum, int M) {
    __shared__ int sm[256];
    int t = threadIdx.x, i = blockIdx.x * 256 + t;
    int v = (i < M) ? deg[i] + 1 : 0;   // +1 self loop
    sm[t] = v; __syncthreads();
    for (int off = 1; off < 256; off <<= 1) {
        int x = (t >= off) ? sm[t - off] : 0;
        __syncthreads();
        sm[t] += x;
        __syncthreads();
    }
    if (i < M) rowp[i] = sm[t] - v;     // exclusive
    if (t == 255) bsum[blockIdx.x] = sm[255];
}

__global__ void k_scan2(int* bsum, int NB) {
    __shared__ int sm[256];
    int t = threadIdx.x;
    int v = (t < NB) ? bsum[t] : 0;
    sm[t] = v; __syncthreads();
    for (int off = 1; off < 256; off <<= 1) {
        int x = (t >= off) ? sm[t - off] : 0;
        __syncthreads();
        sm[t] += x;
        __syncthreads();
    }
    if (t < NB) bsum[t] = sm[t] - v;    // exclusive block offsets
}

__global__ void k_scan3(int* rowp, const int* __restrict__ bsum, int M, int total) {
    int i = blockIdx.x * 256 + threadIdx.x;
    if (i < M) rowp[i] += bsum[blockIdx.x];
    if (i == 0) rowp[M] = total;
}

__global__ void k_fill(const int* __restrict__ src, const int* __restrict__ dst,
                       const int* __restrict__ rowp, int* __restrict__ cur,
                       int* __restrict__ colv, int E, int M) {
    int i = blockIdx.x * 256 + threadIdx.x;
    if (i < E) {
        int d = dst[i];
        int pos = rowp[d] + atomicAdd(&cur[d], 1);
        colv[pos] = src[i];
    } else if (i < E + M) {
        int nn = i - E;
        int pos = rowp[nn] + atomicAdd(&cur[nn], 1);
        colv[pos] = nn;
    }
}

// -------- weight transpose + hi/lo bf16 split: W[K][NC] fp32 -> wT{h,l}[NC][K] --------
__global__ void k_wsplit(const float* __restrict__ W, ushort_t* __restrict__ th,
                         ushort_t* __restrict__ tl, int K, int NC) {
    int i = blockIdx.x * 256 + threadIdx.x;
    if (i < K * NC) {
        int k = i / NC, n = i % NC;
        float f = W[i];
        uint_t u = __float_as_uint(f);
        ushort_t hi = (ushort_t)(u >> 16);                       // truncate
        float rem = f - __uint_as_float(u & 0xffff0000u);
        th[n * K + k] = hi;
        tl[n * K + k] = f2b_rn(rem);
    }
}

// -------- activation hi/lo bf16 split (x fp32 -> xh, xl), 4 elems/thread --------
__global__ void k_asplit(const float* __restrict__ x, ushort_t* __restrict__ xh,
                         ushort_t* __restrict__ xl, int n4) {
    int i = blockIdx.x * 256 + threadIdx.x;
    if (i < n4) {
        float4 v = ((const float4*)x)[i];
        float vv[4] = {v.x, v.y, v.z, v.w};
        ushort_t hs[4], ls[4];
        #pragma unroll
        for (int j = 0; j < 4; ++j) {
            uint_t u = __float_as_uint(vv[j]);
            hs[j] = (ushort_t)(u >> 16);
            float rem = vv[j] - __uint_as_float(u & 0xffff0000u);
            ls[j] = f2b_rn(rem);
        }
        uint2 ph, pl;
        ph.x = (uint_t)hs[0] | ((uint_t)hs[1] << 16);
        ph.y = (uint_t)hs[2] | ((uint_t)hs[3] << 16);
        pl.x = (uint_t)ls[0] | ((uint_t)ls[1] << 16);
        pl.y = (uint_t)ls[2] | ((uint_t)ls[3] << 16);
        ((uint2*)xh)[i] = ph;
        ((uint2*)xl)[i] = pl;
    }
}

// ---------------- MFMA GEMM: H = A @ W, all inputs pre-split bf16 ----------------
// A{h,l}[Mpad][KD] bf16 row-major; Bt{h,l}[NC][KD] bf16. acc = Ah*Bh + Ah*Bl + Al*Bh.
// Staging via global_load_lds (16B/lane), unpadded 64B LDS rows.
template<int KD, int BN>
__global__ __launch_bounds__(256)
void k_mgemm(const ushort_t* __restrict__ Axh, const ushort_t* __restrict__ Axl,
             const ushort_t* __restrict__ Bth, const ushort_t* __restrict__ Btl,
             __half* __restrict__ Hout, int M, int NC) {
    constexpr int BM = 128, BK = 32;
    __shared__ ushort_t sAh[BM * BK];
    __shared__ ushort_t sAl[BM * BK];
    __shared__ ushort_t sBh[BN * BK];
    __shared__ ushort_t sBl[BN * BK];
    const int tid = threadIdx.x;
    const int m0 = blockIdx.x * BM;
    const int n0 = blockIdx.y * BN;
    const int wv = tid >> 6, ln = tid & 63;
    const int lrow = ln & 15, lq = ln >> 4;
    constexpr int RT = (BN == 128) ? 4 : 2;
    int wm, wn;
    if constexpr (BN == 128) { wm = (wv >> 1) * 64; wn = (wv & 1) * 64; }
    else                     { wm = wv * 32;        wn = 0; }
    const int roff = ln >> 2;        // 0..15: row within 16-row chunk
    const int coff = (ln & 3) * 8;   // element offset within 32-elem row

    f32x4 acc[RT][4] = {};

    for (int k0 = 0; k0 < KD; k0 += BK) {
        // A tiles: each wave stages rows [wv*32, wv*32+32) of hi and lo
        #pragma unroll
        for (int ch = 0; ch < 2; ++ch) {
            int rb = wv * 32 + ch * 16;
            size_t ga = (size_t)(m0 + rb + roff) * KD + k0 + coff;
            gld16(Axh + ga, &sAh[rb * BK]);
            gld16(Axl + ga, &sAl[rb * BK]);
        }
        // B tiles
        if constexpr (BN == 128) {
            #pragma unroll
            for (int ch = 0; ch < 2; ++ch) {
                int rb = wv * 32 + ch * 16;
                size_t gb = (size_t)(n0 + rb + roff) * KD + k0 + coff;
                gld16(Bth + gb, &sBh[rb * BK]);
                gld16(Btl + gb, &sBl[rb * BK]);
            }
        } else {
            int rb = wv * 16;
            size_t gb = (size_t)(n0 + rb + roff) * KD + k0 + coff;
            gld16(Bth + gb, &sBh[rb * BK]);
            gld16(Btl + gb, &sBl[rb * BK]);
        }
        __syncthreads();
        short8 afh[RT], afl[RT], bfh[4], bfl[4];
        #pragma unroll
        for (int r = 0; r < RT; ++r) {
            afh[r] = *(const short8*)&sAh[(wm + r * 16 + lrow) * BK + lq * 8];
            afl[r] = *(const short8*)&sAl[(wm + r * 16 + lrow) * BK + lq * 8];
        }
        #pragma unroll
        for (int c = 0; c < 4; ++c) {
            bfh[c] = *(const short8*)&sBh[(wn + c * 16 + lrow) * BK + lq * 8];
            bfl[c] = *(const short8*)&sBl[(wn + c * 16 + lrow) * BK + lq * 8];
        }
        #pragma unroll
        for (int r = 0; r < RT; ++r)
            #pragma unroll
            for (int c = 0; c < 4; ++c) {
                acc[r][c] = __builtin_amdgcn_mfma_f32_16x16x32_bf16(afh[r], bfh[c], acc[r][c], 0, 0, 0);
                acc[r][c] = __builtin_amdgcn_mfma_f32_16x16x32_bf16(afh[r], bfl[c], acc[r][c], 0, 0, 0);
                acc[r][c] = __builtin_amdgcn_mfma_f32_16x16x32_bf16(afl[r], bfh[c], acc[r][c], 0, 0, 0);
            }
        __syncthreads();
    }
    // epilogue: C/D layout col=lane&15, row=(lane>>4)*4+reg
    #pragma unroll
    for (int r = 0; r < RT; ++r) {
        #pragma unroll
        for (int c = 0; c < 4; ++c) {
            int colg = n0 + wn + c * 16 + lrow;
            #pragma unroll
            for (int j = 0; j < 4; ++j) {
                int row = m0 + wm + r * 16 + lq * 4 + j;
                if (row < M) Hout[(size_t)row * NC + colg] = __float2half(acc[r][c][j]);
            }
        }
    }
}

// ---------------- attention logits: al_s/al_d [N][H] (h in fp16) ----------------
template<int H>
__global__ __launch_bounds__(256)
void k_al(const __half* __restrict__ h, const float* __restrict__ a_s,
          const float* __restrict__ a_d, float* __restrict__ als,
          float* __restrict__ ald, int M) {
    int node = blockIdx.x * 4 + (threadIdx.x >> 6);
    if (node >= M) return;
    int lane = threadIdx.x & 63;
    constexpr int HC = H * 64;
    float ss[H], dd[H];
    #pragma unroll
    for (int j = 0; j < H; ++j) {
        float hv = __half2float(h[(size_t)node * HC + j * 64 + lane]);
        float ps = hv * a_s[j * 64 + lane];
        float pd = hv * a_d[j * 64 + lane];
        #pragma unroll
        for (int off = 32; off; off >>= 1) {
            ps += __shfl_xor(ps, off);
            pd += __shfl_xor(pd, off);
        }
        ss[j] = ps; dd[j] = pd;
    }
    if (lane == 0) {
        #pragma unroll
        for (int j = 0; j < H; ++j) {
            als[node * H + j] = ss[j];
            ald[node * H + j] = dd[j];
        }
    }
}

// ---- fused aggregation + bias + BN + ELU (wave per dst node, fp16 h gather) ----
// SPLIT: write hi/lo bf16 (next GEMM input); else fp32 (pooling input).
template<int H, bool SPLIT>
__global__ __launch_bounds__(256)
void k_agg(const __half* __restrict__ h, const float* __restrict__ als,
           const float* __restrict__ ald, const int* __restrict__ rowp,
           const int* __restrict__ colv,
           const float* __restrict__ bias, const float* __restrict__ gam,
           const float* __restrict__ bet, const float* __restrict__ mu,
           const float* __restrict__ var,
           ushort_t* __restrict__ xh, ushort_t* __restrict__ xl,
           float* __restrict__ xf, int M) {
    constexpr int HC = H * 64;
    constexpr int LPH = 64 / H;
    constexpr int D = HC / 64;
    int node = blockIdx.x * 4 + (threadIdx.x >> 6);
    if (node >= M) return;
    int lane = threadIdx.x & 63;
    int rs = rowp[node], re = rowp[node + 1];
    int hh = lane / LPH;
    float ad = ald[node * H + hh];
    float mx = -3.0e38f;
    for (int i = rs + (lane % LPH); i < re; i += LPH) {
        int s = colv[i];
        float e = als[s * H + hh] + ad;
        e = e > 0.f ? e : 0.2f * e;
        mx = fmaxf(mx, e);
    }
    #pragma unroll
    for (int off = LPH >> 1; off; off >>= 1) mx = fmaxf(mx, __shfl_xor(mx, off));
    float den = 0.f;
    float acc[D] = {0.f};
    for (int i = rs; i < re; ++i) {
        int s = colv[i];
        float e = als[s * H + hh] + ad;
        e = e > 0.f ? e : 0.2f * e;
        float ee = __expf(e - mx);
        den += ee;
        if constexpr (D == 4) {
            const __half2* hp2 = (const __half2*)(h + (size_t)s * HC + lane * 4);
            float2 f01 = __half22float2(hp2[0]);
            float2 f23 = __half22float2(hp2[1]);
            acc[0] += ee * f01.x; acc[1] += ee * f01.y;
            acc[2] += ee * f23.x; acc[3] += ee * f23.y;
        } else {
            acc[0] += ee * __half2float(h[(size_t)s * HC + lane]);
        }
    }
    float inv = 1.f / (den + 1e-16f);
    #pragma unroll
    for (int j = 0; j < D; ++j) {
        int d = lane * D + j;
        float o = acc[j] * inv + bias[d];
        float bn = (o - mu[d]) * rsqrtf(var[d] + 1e-5f) * gam[d] + bet[d];
        float el = bn > 0.f ? bn : (__expf(bn) - 1.f);
        if constexpr (SPLIT) {
            uint_t u = __float_as_uint(el);
            ushort_t hi = (ushort_t)(u >> 16);
            float rem = el - __uint_as_float(u & 0xffff0000u);
            xh[(size_t)node * HC + d] = hi;
            xl[(size_t)node * HC + d] = f2b_rn(rem);
        } else {
            xf[(size_t)node * HC + d] = el;
        }
    }
}

// ---------------- pooling (block per graph, batch sorted -> binary search) ----------------
__global__ void k_pool(const float* __restrict__ x, const int* __restrict__ batch,
                       float* __restrict__ pooled, int M) {
    int g = blockIdx.x, lane = threadIdx.x; // 64 threads
    int lo = 0, hi = M;
    while (lo < hi) { int mid = (lo + hi) >> 1; if (batch[mid] < g) lo = mid + 1; else hi = mid; }
    int s = lo;
    lo = 0; hi = M;
    while (lo < hi) { int mid = (lo + hi) >> 1; if (batch[mid] < g + 1) lo = mid + 1; else hi = mid; }
    int e = lo;
    float sum = 0.f, mx = -3.0e38f;
    for (int n = s; n < e; ++n) {
        float v = x[(size_t)n * 64 + lane];
        sum += v; mx = fmaxf(mx, v);
    }
    int cnt = e - s;
    float mean = sum / (float)(cnt > 1 ? cnt : 1);
    if (cnt == 0) mx = 0.f;
    pooled[g * 192 + lane] = mean;
    pooled[g * 192 + 64 + lane] = mx;
    pooled[g * 192 + 128 + lane] = sum;
}

// ---------------- final MLP ----------------
__global__ void k_fc(const float* __restrict__ pooled,
                     const float* __restrict__ fc1w, const float* __restrict__ fc1b,
                     const float* __restrict__ fc2w, const float* __restrict__ fc2b,
                     const float* __restrict__ fc3w, const float* __restrict__ fc3b,
                     float* __restrict__ out) {
    __shared__ float hb[192];
    __shared__ float h1[64];
    __shared__ float h2[32];
    int g = blockIdx.x, t = threadIdx.x; // 64 threads
    for (int j = t; j < 192; j += 64) hb[j] = pooled[g * 192 + j];
    __syncthreads();
    float s = fc1b[t];
    for (int k = 0; k < 192; ++k) s += hb[k] * fc1w[k * 64 + t];
    h1[t] = fmaxf(s, 0.f);
    __syncthreads();
    if (t < 32) {
        float s2 = fc2b[t];
        for (int k = 0; k < 64; ++k) s2 += h1[k] * fc2w[k * 32 + t];
        h2[t] = fmaxf(s2, 0.f);
    }
    __syncthreads();
    if (t == 0) {
        float s3 = fc3b[0];
        for (int k = 0; k < 32; ++k) s3 += h2[k] * fc3w[k];
        out[g] = s3;
    }
}

extern "C" void kernel_launch(void* const* d_in, const int* in_sizes, int n_in,
                              void* d_out, int out_size, void* d_ws, size_t ws_size,
                              hipStream_t stream) {
    const float* x0     = (const float*)d_in[0];
    const int* ei       = (const int*)d_in[1];
    const int* batch    = (const int*)d_in[2];
    const float* W[3]   = {(const float*)d_in[3],  (const float*)d_in[11], (const float*)d_in[19]};
    const float* AS[3]  = {(const float*)d_in[4],  (const float*)d_in[12], (const float*)d_in[20]};
    const float* AD[3]  = {(const float*)d_in[5],  (const float*)d_in[13], (const float*)d_in[21]};
    const float* BI[3]  = {(const float*)d_in[6],  (const float*)d_in[14], (const float*)d_in[22]};
    const float* GA[3]  = {(const float*)d_in[7],  (const float*)d_in[15], (const float*)d_in[23]};
    const float* BE[3]  = {(const float*)d_in[8],  (const float*)d_in[16], (const float*)d_in[24]};
    const float* MU[3]  = {(const float*)d_in[9],  (const float*)d_in[17], (const float*)d_in[25]};
    const float* VA[3]  = {(const float*)d_in[10], (const float*)d_in[18], (const float*)d_in[26]};
    const float* fc1w = (const float*)d_in[27];
    const float* fc1b = (const float*)d_in[28];
    const float* fc2w = (const float*)d_in[29];
    const float* fc2b = (const float*)d_in[30];
    const float* fc3w = (const float*)d_in[31];
    const float* fc3b = (const float*)d_in[32];

    // top of use = 95,310,336 B (< 108,953,600 B proven safe)
    char* ws = (char*)d_ws;
    int*   rowp   = (int*)  (ws);                      // 200,004 B
    int*   colv   = (int*)  (ws + 200704);             // 3,400,000 B
    int*   bsum   = (int*)  (ws + 3600704);            // 1,024 B
    float* als    = (float*)(ws + 3602432);            // 800,000 B
    int*   cur    = (int*)  (ws + 3602432);            // 200,000 B (aliases als; dead before k_al)
    float* ald    = (float*)(ws + 4402432);            // 800,000 B
    ushort_t* wTh = (ushort_t*)(ws + 5202432);         // 131,072 B
    ushort_t* wTl = (ushort_t*)(ws + 5333504);         // 131,072 B
    float* pooled = (float*)(ws + 5464576);            // 196,608 B
    __half* h_buf = (__half*)(ws + 5661184);           // 25,600,000 B
    ushort_t* xh  = (ushort_t*)(ws + 31261184);        // 25,624,576 B (50048 rows x 256)
    ushort_t* xl  = (ushort_t*)(ws + 56885760);        // 25,624,576 B
    float* xpool  = (float*)(ws + 82510336);           // 12,800,000 B -> 95,310,336 B

    const int* esrc = ei;
    const int* edst = ei + NE;
    const int NB_SCAN = (NN + 255) / 256; // 196

    // CSR build
    hipMemsetAsync(cur, 0, NN * sizeof(int), stream);
    k_deg<<<(NE + 255) / 256, 256, 0, stream>>>(edst, cur, NE);
    k_scan1<<<NB_SCAN, 256, 0, stream>>>(cur, rowp, bsum, NN);
    k_scan2<<<1, 256, 0, stream>>>(bsum, NB_SCAN);
    k_scan3<<<NB_SCAN, 256, 0, stream>>>(rowp, bsum, NN, NE + NN);
    hipMemsetAsync(cur, 0, NN * sizeof(int), stream);
    k_fill<<<(NE + NN + 255) / 256, 256, 0, stream>>>(esrc, edst, rowp, cur, colv, NE, NN);

    // split input x (50000 x 128 fp32 -> bf16 hi/lo)
    k_asplit<<<(NN * 128 / 4 + 255) / 256, 256, 0, stream>>>(x0, xh, xl, NN * 128 / 4);

    const int GB = (NN + 127) / 128; // 391
    int nwb = (NN + 3) / 4;          // 12500

    // ---- layer 0 (K=128, HC=256, H=4)
    k_wsplit<<<(128 * 256 + 255) / 256, 256, 0, stream>>>(W[0], wTh, wTl, 128, 256);
    k_mgemm<128, 128><<<dim3(GB, 2), 256, 0, stream>>>(xh, xl, wTh, wTl, h_buf, NN, 256);
    k_al<4><<<nwb, 256, 0, stream>>>(h_buf, AS[0], AD[0], als, ald, NN);
    k_agg<4, true><<<nwb, 256, 0, stream>>>(h_buf, als, ald, rowp, colv,
                                            BI[0], GA[0], BE[0], MU[0], VA[0],
                                            xh, xl, nullptr, NN);
    // ---- layer 1 (K=256, HC=256, H=4)
    k_wsplit<<<(256 * 256 + 255) / 256, 256, 0, stream>>>(W[1], wTh, wTl, 256, 256);
    k_mgemm<256, 128><<<dim3(GB, 2), 256, 0, stream>>>(xh, xl, wTh, wTl, h_buf, NN, 256);
    k_al<4><<<nwb, 256, 0, stream>>>(h_buf, AS[1], AD[1], als, ald, NN);
    k_agg<4, true><<<nwb, 256, 0, stream>>>(h_buf, als, ald, rowp, colv,
                                            BI[1], GA[1], BE[1], MU[1], VA[1],
                                            xh, xl, nullptr, NN);
    // ---- layer 2 (K=256, HC=64, H=1)
    k_wsplit<<<(256 * 64 + 255) / 256, 256, 0, stream>>>(W[2], wTh, wTl, 256, 64);
    k_mgemm<256, 64><<<dim3(GB, 1), 256, 0, stream>>>(xh, xl, wTh, wTl, h_buf, NN, 64);
    k_al<1><<<nwb, 256, 0, stream>>>(h_buf, AS[2], AD[2], als, ald, NN);
    k_agg<1, false><<<nwb, 256, 0, stream>>>(h_buf, als, ald, rowp, colv,
                                             BI[2], GA[2], BE[2], MU[2], VA[2],
                                             nullptr, nullptr, xpool, NN);

    // readout + MLP
    k_pool<<<NGR, 64, 0, stream>>>(xpool, batch, pooled, NN);
    k_fc<<<NGR, 64, 0, stream>>>(pooled, fc1w, fc1b, fc2w, fc2b, fc3w, fc3b,
                                 (float*)d_out);
    (void)in_sizes; (void)n_in; (void)out_size; (void)ws_size;
}

// Round 9
// 641.376 us; speedup vs baseline: 2.3387x; 1.1717x over previous
//
#include <hip/hip_runtime.h>
#include <hip/hip_fp16.h>

typedef unsigned short ushort_t;
typedef unsigned int uint_t;
typedef __attribute__((ext_vector_type(8))) short short8;
typedef __attribute__((ext_vector_type(4))) float f32x4;

#define NN 50000
#define NE 800000
#define NGR 256

__device__ __forceinline__ ushort_t f2b_rn(float f) {
    uint_t u = __float_as_uint(f);
    return (ushort_t)((u + 0x7fffu + ((u >> 16) & 1u)) >> 16);
}

// async global->LDS, 16B per lane; LDS dest = wave-uniform base + lane*16
typedef __attribute__((address_space(3))) unsigned int as3_u32;
typedef const __attribute__((address_space(1))) unsigned int as1_u32c;
__device__ __forceinline__ void gld16(const ushort_t* g, void* lds_base) {
    __builtin_amdgcn_global_load_lds((as1_u32c*)g, (as3_u32*)lds_base, 16, 0, 0);
}

// ---------------- CSR build ----------------
__global__ void k_deg(const int* __restrict__ dst, int* __restrict__ deg, int E) {
    int i = blockIdx.x * 256 + threadIdx.x;
    if (i < E) atomicAdd(&deg[dst[i]], 1);
}

__global__ void k_scan1(const int* __restrict__ deg, int* __restrict__ rowp,
                        int* __restrict__ bsum, int M) {
    __shared__ int sm[256];
    int t = threadIdx.x, i = blockIdx.x * 256 + t;
    int v = (i < M) ? deg[i] + 1 : 0;   // +1 self loop
    sm[t] = v; __syncthreads();
    for (int off = 1; off < 256; off <<= 1) {
        int x = (t >= off) ? sm[t - off] : 0;
        __syncthreads();
        sm[t] += x;
        __syncthreads();
    }
    if (i < M) rowp[i] = sm[t] - v;     // exclusive
    if (t == 255) bsum[blockIdx.x] = sm[255];
}

__global__ void k_scan2(int* bsum, int NB) {
    __shared__ int sm[256];
    int t = threadIdx.x;
    int v = (t < NB) ? bsum[t] : 0;
    sm[t] = v; __syncthreads();
    for (int off = 1; off < 256; off <<= 1) {
        int x = (t >= off) ? sm[t - off] : 0;
        __syncthreads();
        sm[t] += x;
        __syncthreads();
    }
    if (t < NB) bsum[t] = sm[t] - v;    // exclusive block offsets
}

__global__ void k_scan3(int* rowp, const int* __restrict__ bsum, int M, int total) {
    int i = blockIdx.x * 256 + threadIdx.x;
    if (i < M) rowp[i] += bsum[blockIdx.x];
    if (i == 0) rowp[M] = total;
}

__global__ void k_fill(const int* __restrict__ src, const int* __restrict__ dst,
                       const int* __restrict__ rowp, int* __restrict__ cur,
                       int* __restrict__ colv, int E, int M) {
    int i = blockIdx.x * 256 + threadIdx.x;
    if (i < E) {
        int d = dst[i];
        int pos = rowp[d] + atomicAdd(&cur[d], 1);
        colv[pos] = src[i];
    } else if (i < E + M) {
        int nn = i - E;
        int pos = rowp[nn] + atomicAdd(&cur[nn], 1);
        colv[pos] = nn;
    }
}

// ---- all-layer weight transpose + hi/lo bf16 split into packed regions ----
// L0: 256x128 @0 ; L1: 256x256 @32768 ; L2: 64x256 @98304  (wT[NC][K])
__global__ void k_wsplit_all(const float* __restrict__ W0, const float* __restrict__ W1,
                             const float* __restrict__ W2, ushort_t* __restrict__ th,
                             ushort_t* __restrict__ tl) {
    int i = blockIdx.x * 256 + threadIdx.x;
    if (i >= 114688) return;
    const float* W; int K, NC, idx, base;
    if (i < 32768)      { W = W0; K = 128; NC = 256; idx = i;         base = 0; }
    else if (i < 98304) { W = W1; K = 256; NC = 256; idx = i - 32768; base = 32768; }
    else                { W = W2; K = 256; NC = 64;  idx = i - 98304; base = 98304; }
    int k = idx / NC, n = idx % NC;
    float f = W[idx];
    uint_t u = __float_as_uint(f);
    th[base + n * K + k] = (ushort_t)(u >> 16);
    tl[base + n * K + k] = f2b_rn(f - __uint_as_float(u & 0xffff0000u));
}

// -------- activation hi/lo bf16 split (x fp32 -> xh, xl), 4 elems/thread --------
__global__ void k_asplit(const float* __restrict__ x, ushort_t* __restrict__ xh,
                         ushort_t* __restrict__ xl, int n4) {
    int i = blockIdx.x * 256 + threadIdx.x;
    if (i < n4) {
        float4 v = ((const float4*)x)[i];
        float vv[4] = {v.x, v.y, v.z, v.w};
        ushort_t hs[4], ls[4];
        #pragma unroll
        for (int j = 0; j < 4; ++j) {
            uint_t u = __float_as_uint(vv[j]);
            hs[j] = (ushort_t)(u >> 16);
            ls[j] = f2b_rn(vv[j] - __uint_as_float(u & 0xffff0000u));
        }
        uint2 ph, pl;
        ph.x = (uint_t)hs[0] | ((uint_t)hs[1] << 16);
        ph.y = (uint_t)hs[2] | ((uint_t)hs[3] << 16);
        pl.x = (uint_t)ls[0] | ((uint_t)ls[1] << 16);
        pl.y = (uint_t)ls[2] | ((uint_t)ls[3] << 16);
        ((uint2*)xh)[i] = ph;
        ((uint2*)xl)[i] = pl;
    }
}

// ---------------- MFMA GEMM: H = A @ W, all inputs pre-split bf16 ----------------
template<int KD, int BN>
__global__ __launch_bounds__(256)
void k_mgemm(const ushort_t* __restrict__ Axh, const ushort_t* __restrict__ Axl,
             const ushort_t* __restrict__ Bth, const ushort_t* __restrict__ Btl,
             __half* __restrict__ Hout, int M, int NC) {
    constexpr int BM = 128, BK = 32;
    __shared__ ushort_t sAh[BM * BK];
    __shared__ ushort_t sAl[BM * BK];
    __shared__ ushort_t sBh[BN * BK];
    __shared__ ushort_t sBl[BN * BK];
    const int tid = threadIdx.x;
    const int m0 = blockIdx.x * BM;
    const int n0 = blockIdx.y * BN;
    const int wv = tid >> 6, ln = tid & 63;
    const int lrow = ln & 15, lq = ln >> 4;
    constexpr int RT = (BN == 128) ? 4 : 2;
    int wm, wn;
    if constexpr (BN == 128) { wm = (wv >> 1) * 64; wn = (wv & 1) * 64; }
    else                     { wm = wv * 32;        wn = 0; }
    const int roff = ln >> 2;
    const int coff = (ln & 3) * 8;

    f32x4 acc[RT][4] = {};

    for (int k0 = 0; k0 < KD; k0 += BK) {
        #pragma unroll
        for (int ch = 0; ch < 2; ++ch) {
            int rb = wv * 32 + ch * 16;
            size_t ga = (size_t)(m0 + rb + roff) * KD + k0 + coff;
            gld16(Axh + ga, &sAh[rb * BK]);
            gld16(Axl + ga, &sAl[rb * BK]);
        }
        if constexpr (BN == 128) {
            #pragma unroll
            for (int ch = 0; ch < 2; ++ch) {
                int rb = wv * 32 + ch * 16;
                size_t gb = (size_t)(n0 + rb + roff) * KD + k0 + coff;
                gld16(Bth + gb, &sBh[rb * BK]);
                gld16(Btl + gb, &sBl[rb * BK]);
            }
        } else {
            int rb = wv * 16;
            size_t gb = (size_t)(n0 + rb + roff) * KD + k0 + coff;
            gld16(Bth + gb, &sBh[rb * BK]);
            gld16(Btl + gb, &sBl[rb * BK]);
        }
        __syncthreads();
        short8 afh[RT], afl[RT], bfh[4], bfl[4];
        #pragma unroll
        for (int r = 0; r < RT; ++r) {
            afh[r] = *(const short8*)&sAh[(wm + r * 16 + lrow) * BK + lq * 8];
            afl[r] = *(const short8*)&sAl[(wm + r * 16 + lrow) * BK + lq * 8];
        }
        #pragma unroll
        for (int c = 0; c < 4; ++c) {
            bfh[c] = *(const short8*)&sBh[(wn + c * 16 + lrow) * BK + lq * 8];
            bfl[c] = *(const short8*)&sBl[(wn + c * 16 + lrow) * BK + lq * 8];
        }
        #pragma unroll
        for (int r = 0; r < RT; ++r)
            #pragma unroll
            for (int c = 0; c < 4; ++c) {
                acc[r][c] = __builtin_amdgcn_mfma_f32_16x16x32_bf16(afh[r], bfh[c], acc[r][c], 0, 0, 0);
                acc[r][c] = __builtin_amdgcn_mfma_f32_16x16x32_bf16(afh[r], bfl[c], acc[r][c], 0, 0, 0);
                acc[r][c] = __builtin_amdgcn_mfma_f32_16x16x32_bf16(afl[r], bfh[c], acc[r][c], 0, 0, 0);
            }
        __syncthreads();
    }
    #pragma unroll
    for (int r = 0; r < RT; ++r) {
        #pragma unroll
        for (int c = 0; c < 4; ++c) {
            int colg = n0 + wn + c * 16 + lrow;
            #pragma unroll
            for (int j = 0; j < 4; ++j) {
                int row = m0 + wm + r * 16 + lq * 4 + j;
                if (row < M) Hout[(size_t)row * NC + colg] = __float2half(acc[r][c][j]);
            }
        }
    }
}

// ---------------- attention logits: al_s/al_d [N][H] (h in fp16) ----------------
template<int H>
__global__ __launch_bounds__(256)
void k_al(const __half* __restrict__ h, const float* __restrict__ a_s,
          const float* __restrict__ a_d, float* __restrict__ als,
          float* __restrict__ ald, int M) {
    int node = blockIdx.x * 4 + (threadIdx.x >> 6);
    if (node >= M) return;
    int lane = threadIdx.x & 63;
    constexpr int HC = H * 64;
    float ss[H], dd[H];
    #pragma unroll
    for (int j = 0; j < H; ++j) {
        float hv = __half2float(h[(size_t)node * HC + j * 64 + lane]);
        float ps = hv * a_s[j * 64 + lane];
        float pd = hv * a_d[j * 64 + lane];
        #pragma unroll
        for (int off = 32; off; off >>= 1) {
            ps += __shfl_xor(ps, off);
            pd += __shfl_xor(pd, off);
        }
        ss[j] = ps; dd[j] = pd;
    }
    if (lane == 0) {
        #pragma unroll
        for (int j = 0; j < H; ++j) {
            als[node * H + j] = ss[j];
            ald[node * H + j] = dd[j];
        }
    }
}

// ---- fused aggregation + bias + BN + ELU: wave per node, EG edges x 8 dims/lane ----
// H=4: 2 edges x 32 lanes (x2 unroll);  H=1: 8 edges x 8 lanes.
template<int H, bool SPLIT>
__global__ __launch_bounds__(256)
void k_agg(const __half* __restrict__ h, const float* __restrict__ als,
           const float* __restrict__ ald, const int* __restrict__ rowp,
           const int* __restrict__ colv,
           const float* __restrict__ bias, const float* __restrict__ gam,
           const float* __restrict__ bet, const float* __restrict__ mu,
           const float* __restrict__ var,
           ushort_t* __restrict__ xh, ushort_t* __restrict__ xl,
           float* __restrict__ xf, int M) {
    constexpr int HC = H * 64;
    constexpr int EG = 512 / HC;        // edge groups: 2 (H=4), 8 (H=1)
    constexpr int L  = 64 / EG;         // lanes per edge: 32, 8
    constexpr int LPH = 64 / H;
    constexpr int UN = (H == 4) ? 2 : 1;
    int node = blockIdx.x * 4 + (threadIdx.x >> 6);
    if (node >= M) return;
    int lane = threadIdx.x & 63;
    int rs = rowp[node], re = rowp[node + 1];
    // pass A: per-head max
    int hhA = lane / LPH;
    float adA = ald[node * H + hhA];
    float mxA = -3.0e38f;
    for (int i = rs + (lane % LPH); i < re; i += LPH) {
        float e = als[colv[i] * H + hhA] + adA;
        e = e > 0.f ? e : 0.2f * e;
        mxA = fmaxf(mxA, e);
    }
    #pragma unroll
    for (int off = LPH >> 1; off; off >>= 1) mxA = fmaxf(mxA, __shfl_xor(mxA, off));
    // pass B: lane = eg*L + l; lane handles dims [l*8, l*8+8)
    int l = lane & (L - 1), eg = lane / L;
    int hB = (l * 8) >> 6;
    float mx = __shfl(mxA, hB * LPH);
    float ad = ald[node * H + hB];
    float den = 0.f;
    float acc[8] = {};
    for (int i = rs; i < re; i += EG * UN) {
        #pragma unroll
        for (int k = 0; k < UN; ++k) {
            int idx = i + eg + k * EG;
            bool vld = idx < re;
            int s = colv[vld ? idx : rs];
            float e = als[s * H + hB] + ad;
            e = e > 0.f ? e : 0.2f * e;
            float ee = vld ? __expf(e - mx) : 0.f;
            den += ee;
            uint4 hv = *(const uint4*)(h + (size_t)s * HC + l * 8);
            float2 f0 = __half22float2(*(__half2*)&hv.x);
            float2 f1 = __half22float2(*(__half2*)&hv.y);
            float2 f2 = __half22float2(*(__half2*)&hv.z);
            float2 f3 = __half22float2(*(__half2*)&hv.w);
            acc[0] += ee * f0.x; acc[1] += ee * f0.y;
            acc[2] += ee * f1.x; acc[3] += ee * f1.y;
            acc[4] += ee * f2.x; acc[5] += ee * f2.y;
            acc[6] += ee * f3.x; acc[7] += ee * f3.y;
        }
    }
    #pragma unroll
    for (int off = L; off < 64; off <<= 1) {
        den += __shfl_xor(den, off);
        #pragma unroll
        for (int j = 0; j < 8; ++j) acc[j] += __shfl_xor(acc[j], off);
    }
    if (eg == 0) {
        float inv = 1.f / (den + 1e-16f);
        ushort_t hs[8], ls[8];
        float fo[8];
        #pragma unroll
        for (int j = 0; j < 8; ++j) {
            int d = l * 8 + j;
            float o = acc[j] * inv + bias[d];
            float bn = (o - mu[d]) * rsqrtf(var[d] + 1e-5f) * gam[d] + bet[d];
            float el = bn > 0.f ? bn : (__expf(bn) - 1.f);
            if constexpr (SPLIT) {
                uint_t u = __float_as_uint(el);
                hs[j] = (ushort_t)(u >> 16);
                ls[j] = f2b_rn(el - __uint_as_float(u & 0xffff0000u));
            } else {
                fo[j] = el;
            }
        }
        if constexpr (SPLIT) {
            uint4 ph, pl;
            ph.x = (uint_t)hs[0] | ((uint_t)hs[1] << 16);
            ph.y = (uint_t)hs[2] | ((uint_t)hs[3] << 16);
            ph.z = (uint_t)hs[4] | ((uint_t)hs[5] << 16);
            ph.w = (uint_t)hs[6] | ((uint_t)hs[7] << 16);
            pl.x = (uint_t)ls[0] | ((uint_t)ls[1] << 16);
            pl.y = (uint_t)ls[2] | ((uint_t)ls[3] << 16);
            pl.z = (uint_t)ls[4] | ((uint_t)ls[5] << 16);
            pl.w = (uint_t)ls[6] | ((uint_t)ls[7] << 16);
            *(uint4*)&xh[(size_t)node * HC + l * 8] = ph;
            *(uint4*)&xl[(size_t)node * HC + l * 8] = pl;
        } else {
            *(float4*)&xf[(size_t)node * HC + l * 8] = make_float4(fo[0], fo[1], fo[2], fo[3]);
            *(float4*)&xf[(size_t)node * HC + l * 8 + 4] = make_float4(fo[4], fo[5], fo[6], fo[7]);
        }
    }
}

// ---------------- fused pooling + MLP (block per graph, 64 threads) ----------------
__global__ void k_poolfc(const float* __restrict__ x, const int* __restrict__ batch,
                         const float* __restrict__ fc1w, const float* __restrict__ fc1b,
                         const float* __restrict__ fc2w, const float* __restrict__ fc2b,
                         const float* __restrict__ fc3w, const float* __restrict__ fc3b,
                         float* __restrict__ out, int M) {
    __shared__ float hb[192];
    __shared__ float h1[64];
    __shared__ float h2[32];
    int g = blockIdx.x, t = threadIdx.x;
    int lo = 0, hi = M;
    while (lo < hi) { int mid = (lo + hi) >> 1; if (batch[mid] < g) lo = mid + 1; else hi = mid; }
    int s = lo;
    lo = 0; hi = M;
    while (lo < hi) { int mid = (lo + hi) >> 1; if (batch[mid] < g + 1) lo = mid + 1; else hi = mid; }
    int e = lo;
    float sum = 0.f, mx = -3.0e38f;
    for (int n = s; n < e; ++n) {
        float v = x[(size_t)n * 64 + t];
        sum += v; mx = fmaxf(mx, v);
    }
    int cnt = e - s;
    hb[t] = sum / (float)(cnt > 1 ? cnt : 1);
    hb[64 + t] = (cnt == 0) ? 0.f : mx;
    hb[128 + t] = sum;
    __syncthreads();
    float s1 = fc1b[t];
    for (int k = 0; k < 192; ++k) s1 += hb[k] * fc1w[k * 64 + t];
    h1[t] = fmaxf(s1, 0.f);
    __syncthreads();
    if (t < 32) {
        float s2 = fc2b[t];
        for (int k = 0; k < 64; ++k) s2 += h1[k] * fc2w[k * 32 + t];
        h2[t] = fmaxf(s2, 0.f);
    }
    __syncthreads();
    if (t == 0) {
        float s3 = fc3b[0];
        for (int k = 0; k < 32; ++k) s3 += h2[k] * fc3w[k];
        out[g] = s3;
    }
}

extern "C" void kernel_launch(void* const* d_in, const int* in_sizes, int n_in,
                              void* d_out, int out_size, void* d_ws, size_t ws_size,
                              hipStream_t stream) {
    const float* x0     = (const float*)d_in[0];
    const int* ei       = (const int*)d_in[1];
    const int* batch    = (const int*)d_in[2];
    const float* W[3]   = {(const float*)d_in[3],  (const float*)d_in[11], (const float*)d_in[19]};
    const float* AS[3]  = {(const float*)d_in[4],  (const float*)d_in[12], (const float*)d_in[20]};
    const float* AD[3]  = {(const float*)d_in[5],  (const float*)d_in[13], (const float*)d_in[21]};
    const float* BI[3]  = {(const float*)d_in[6],  (const float*)d_in[14], (const float*)d_in[22]};
    const float* GA[3]  = {(const float*)d_in[7],  (const float*)d_in[15], (const float*)d_in[23]};
    const float* BE[3]  = {(const float*)d_in[8],  (const float*)d_in[16], (const float*)d_in[24]};
    const float* MU[3]  = {(const float*)d_in[9],  (const float*)d_in[17], (const float*)d_in[25]};
    const float* VA[3]  = {(const float*)d_in[10], (const float*)d_in[18], (const float*)d_in[26]};
    const float* fc1w = (const float*)d_in[27];
    const float* fc1b = (const float*)d_in[28];
    const float* fc2w = (const float*)d_in[29];
    const float* fc2b = (const float*)d_in[30];
    const float* fc3w = (const float*)d_in[31];
    const float* fc3b = (const float*)d_in[32];

    // top of use = 95,310,336 B (< 108,953,600 B proven safe)
    char* ws = (char*)d_ws;
    int*   rowp   = (int*)  (ws);                      // 200,004 B
    int*   colv   = (int*)  (ws + 200704);             // 3,400,000 B
    int*   bsum   = (int*)  (ws + 3600704);            // 1,024 B
    float* als    = (float*)(ws + 3602432);            // 800,000 B
    int*   cur    = (int*)  (ws + 3602432);            // 200,000 B (aliases als; dead before k_al)
    float* ald    = (float*)(ws + 4402432);            // 800,000 B
    ushort_t* wTh = (ushort_t*)(ws + 5202432);         // 229,376 B (3 layers packed)
    ushort_t* wTl = (ushort_t*)(ws + 5431808);         // 229,376 B
    __half* h_buf = (__half*)(ws + 5661184);           // 25,600,000 B
    ushort_t* xh  = (ushort_t*)(ws + 31261184);        // 25,624,576 B (50048 rows x 256)
    ushort_t* xl  = (ushort_t*)(ws + 56885760);        // 25,624,576 B
    float* xpool  = (float*)(ws + 82510336);           // 12,800,000 B -> 95,310,336 B

    const int* esrc = ei;
    const int* edst = ei + NE;
    const int NB_SCAN = (NN + 255) / 256; // 196

    // CSR build
    hipMemsetAsync(cur, 0, NN * sizeof(int), stream);
    k_deg<<<(NE + 255) / 256, 256, 0, stream>>>(edst, cur, NE);
    k_scan1<<<NB_SCAN, 256, 0, stream>>>(cur, rowp, bsum, NN);
    k_scan2<<<1, 256, 0, stream>>>(bsum, NB_SCAN);
    k_scan3<<<NB_SCAN, 256, 0, stream>>>(rowp, bsum, NN, NE + NN);
    hipMemsetAsync(cur, 0, NN * sizeof(int), stream);
    k_fill<<<(NE + NN + 255) / 256, 256, 0, stream>>>(esrc, edst, rowp, cur, colv, NE, NN);

    // split input x and all weights
    k_asplit<<<(NN * 128 / 4 + 255) / 256, 256, 0, stream>>>(x0, xh, xl, NN * 128 / 4);
    k_wsplit_all<<<(114688 + 255) / 256, 256, 0, stream>>>(W[0], W[1], W[2], wTh, wTl);

    const int GB = (NN + 127) / 128; // 391
    int nwb = (NN + 3) / 4;          // 12500

    // ---- layer 0 (K=128, HC=256, H=4)
    k_mgemm<128, 128><<<dim3(GB, 2), 256, 0, stream>>>(xh, xl, wTh, wTl, h_buf, NN, 256);
    k_al<4><<<nwb, 256, 0, stream>>>(h_buf, AS[0], AD[0], als, ald, NN);
    k_agg<4, true><<<nwb, 256, 0, stream>>>(h_buf, als, ald, rowp, colv,
                                            BI[0], GA[0], BE[0], MU[0], VA[0],
                                            xh, xl, nullptr, NN);
    // ---- layer 1 (K=256, HC=256, H=4)
    k_mgemm<256, 128><<<dim3(GB, 2), 256, 0, stream>>>(xh, xl, wTh + 32768, wTl + 32768, h_buf, NN, 256);
    k_al<4><<<nwb, 256, 0, stream>>>(h_buf, AS[1], AD[1], als, ald, NN);
    k_agg<4, true><<<nwb, 256, 0, stream>>>(h_buf, als, ald, rowp, colv,
                                            BI[1], GA[1], BE[1], MU[1], VA[1],
                                            xh, xl, nullptr, NN);
    // ---- layer 2 (K=256, HC=64, H=1)
    k_mgemm<256, 64><<<dim3(GB, 1), 256, 0, stream>>>(xh, xl, wTh + 98304, wTl + 98304, h_buf, NN, 64);
    k_al<1><<<nwb, 256, 0, stream>>>(h_buf, AS[2], AD[2], als, ald, NN);
    k_agg<1, false><<<nwb, 256, 0, stream>>>(h_buf, als, ald, rowp, colv,
                                             BI[2], GA[2], BE[2], MU[2], VA[2],
                                             nullptr, nullptr, xpool, NN);

    // fused readout + MLP
    k_poolfc<<<NGR, 64, 0, stream>>>(xpool, batch, fc1w, fc1b, fc2w, fc2b, fc3w, fc3b,
                                     (float*)d_out, NN);
    (void)in_sizes; (void)n_in; (void)out_size; (void)ws_size;
}

// Round 10
// 579.318 us; speedup vs baseline: 2.5892x; 1.1071x over previous
//
#include <hip/hip_runtime.h>
#include <hip/hip_fp16.h>

typedef unsigned short ushort_t;
typedef unsigned int uint_t;
typedef __attribute__((ext_vector_type(8))) short short8;
typedef __attribute__((ext_vector_type(4))) float f32x4;

#define NN 50000
#define NE 800000
#define NGR 256

__device__ __forceinline__ ushort_t f2b_rn(float f) {
    uint_t u = __float_as_uint(f);
    return (ushort_t)((u + 0x7fffu + ((u >> 16) & 1u)) >> 16);
}

// async global->LDS, 16B per lane; LDS dest = wave-uniform base + lane*16
typedef __attribute__((address_space(3))) unsigned int as3_u32;
typedef const __attribute__((address_space(1))) unsigned int as1_u32c;
__device__ __forceinline__ void gld16(const ushort_t* g, void* lds_base) {
    __builtin_amdgcn_global_load_lds((as1_u32c*)g, (as3_u32*)lds_base, 16, 0, 0);
}

// ---------------- CSR build ----------------
__global__ void k_deg(const int* __restrict__ dst, int* __restrict__ deg, int E) {
    int i = blockIdx.x * 256 + threadIdx.x;
    if (i < E) atomicAdd(&deg[dst[i]], 1);
}

__global__ void k_scan1(const int* __restrict__ deg, int* __restrict__ rowp,
                        int* __restrict__ bsum, int M) {
    __shared__ int sm[256];
    int t = threadIdx.x, i = blockIdx.x * 256 + t;
    int v = (i < M) ? deg[i] + 1 : 0;   // +1 self loop
    sm[t] = v; __syncthreads();
    for (int off = 1; off < 256; off <<= 1) {
        int x = (t >= off) ? sm[t - off] : 0;
        __syncthreads();
        sm[t] += x;
        __syncthreads();
    }
    if (i < M) rowp[i] = sm[t] - v;     // exclusive
    if (t == 255) bsum[blockIdx.x] = sm[255];
}

__global__ void k_scan2(int* bsum, int NB) {
    __shared__ int sm[256];
    int t = threadIdx.x;
    int v = (t < NB) ? bsum[t] : 0;
    sm[t] = v; __syncthreads();
    for (int off = 1; off < 256; off <<= 1) {
        int x = (t >= off) ? sm[t - off] : 0;
        __syncthreads();
        sm[t] += x;
        __syncthreads();
    }
    if (t < NB) bsum[t] = sm[t] - v;    // exclusive block offsets
}

// also zeroes cur (aliases als) for k_fill
__global__ void k_scan3(int* rowp, const int* __restrict__ bsum, int* __restrict__ cur,
                        int M, int total) {
    int i = blockIdx.x * 256 + threadIdx.x;
    if (i < M) { rowp[i] += bsum[blockIdx.x]; cur[i] = 0; }
    if (i == 0) rowp[M] = total;
}

__global__ void k_fill(const int* __restrict__ src, const int* __restrict__ dst,
                       const int* __restrict__ rowp, int* __restrict__ cur,
                       int* __restrict__ colv, int E, int M) {
    int i = blockIdx.x * 256 + threadIdx.x;
    if (i < E) {
        int d = dst[i];
        int pos = rowp[d] + atomicAdd(&cur[d], 1);
        colv[pos] = src[i];
    } else if (i < E + M) {
        int nn = i - E;
        int pos = rowp[nn] + atomicAdd(&cur[nn], 1);
        colv[pos] = nn;
    }
}

// ---- all-layer weight transpose + hi/lo bf16 split into packed regions ----
__global__ void k_wsplit_all(const float* __restrict__ W0, const float* __restrict__ W1,
                             const float* __restrict__ W2, ushort_t* __restrict__ th,
                             ushort_t* __restrict__ tl) {
    int i = blockIdx.x * 256 + threadIdx.x;
    if (i >= 114688) return;
    const float* W; int K, NC, idx, base;
    if (i < 32768)      { W = W0; K = 128; NC = 256; idx = i;         base = 0; }
    else if (i < 98304) { W = W1; K = 256; NC = 256; idx = i - 32768; base = 32768; }
    else                { W = W2; K = 256; NC = 64;  idx = i - 98304; base = 98304; }
    int k = idx / NC, n = idx % NC;
    float f = W[idx];
    uint_t u = __float_as_uint(f);
    th[base + n * K + k] = (ushort_t)(u >> 16);
    tl[base + n * K + k] = f2b_rn(f - __uint_as_float(u & 0xffff0000u));
}

// -------- activation hi/lo bf16 split (x fp32 -> xh, xl), 4 elems/thread --------
__global__ void k_asplit(const float* __restrict__ x, ushort_t* __restrict__ xh,
                         ushort_t* __restrict__ xl, int n4) {
    int i = blockIdx.x * 256 + threadIdx.x;
    if (i < n4) {
        float4 v = ((const float4*)x)[i];
        float vv[4] = {v.x, v.y, v.z, v.w};
        ushort_t hs[4], ls[4];
        #pragma unroll
        for (int j = 0; j < 4; ++j) {
            uint_t u = __float_as_uint(vv[j]);
            hs[j] = (ushort_t)(u >> 16);
            ls[j] = f2b_rn(vv[j] - __uint_as_float(u & 0xffff0000u));
        }
        uint2 ph, pl;
        ph.x = (uint_t)hs[0] | ((uint_t)hs[1] << 16);
        ph.y = (uint_t)hs[2] | ((uint_t)hs[3] << 16);
        pl.x = (uint_t)ls[0] | ((uint_t)ls[1] << 16);
        pl.y = (uint_t)ls[2] | ((uint_t)ls[3] << 16);
        ((uint2*)xh)[i] = ph;
        ((uint2*)xl)[i] = pl;
    }
}

// ------- MFMA GEMM + fused attention-logit epilogue -------
// Each (row, head) pair is owned by exactly one wave -> plain stores of als/ald.
template<int KD, int BN>
__global__ __launch_bounds__(256)
void k_mgemm(const ushort_t* __restrict__ Axh, const ushort_t* __restrict__ Axl,
             const ushort_t* __restrict__ Bth, const ushort_t* __restrict__ Btl,
             __half* __restrict__ Hout, const float* __restrict__ a_s,
             const float* __restrict__ a_d, float* __restrict__ als,
             float* __restrict__ ald, int H, int M, int NC) {
    constexpr int BM = 128, BK = 32;
    __shared__ ushort_t sAh[BM * BK];
    __shared__ ushort_t sAl[BM * BK];
    __shared__ ushort_t sBh[BN * BK];
    __shared__ ushort_t sBl[BN * BK];
    const int tid = threadIdx.x;
    const int m0 = blockIdx.x * BM;
    const int n0 = blockIdx.y * BN;
    const int wv = tid >> 6, ln = tid & 63;
    const int lrow = ln & 15, lq = ln >> 4;
    constexpr int RT = (BN == 128) ? 4 : 2;
    int wm, wn;
    if constexpr (BN == 128) { wm = (wv >> 1) * 64; wn = (wv & 1) * 64; }
    else                     { wm = wv * 32;        wn = 0; }
    const int roff = ln >> 2;
    const int coff = (ln & 3) * 8;

    f32x4 acc[RT][4] = {};

    for (int k0 = 0; k0 < KD; k0 += BK) {
        #pragma unroll
        for (int ch = 0; ch < 2; ++ch) {
            int rb = wv * 32 + ch * 16;
            size_t ga = (size_t)(m0 + rb + roff) * KD + k0 + coff;
            gld16(Axh + ga, &sAh[rb * BK]);
            gld16(Axl + ga, &sAl[rb * BK]);
        }
        if constexpr (BN == 128) {
            #pragma unroll
            for (int ch = 0; ch < 2; ++ch) {
                int rb = wv * 32 + ch * 16;
                size_t gb = (size_t)(n0 + rb + roff) * KD + k0 + coff;
                gld16(Bth + gb, &sBh[rb * BK]);
                gld16(Btl + gb, &sBl[rb * BK]);
            }
        } else {
            int rb = wv * 16;
            size_t gb = (size_t)(n0 + rb + roff) * KD + k0 + coff;
            gld16(Bth + gb, &sBh[rb * BK]);
            gld16(Btl + gb, &sBl[rb * BK]);
        }
        __syncthreads();
        short8 afh[RT], afl[RT], bfh[4], bfl[4];
        #pragma unroll
        for (int r = 0; r < RT; ++r) {
            afh[r] = *(const short8*)&sAh[(wm + r * 16 + lrow) * BK + lq * 8];
            afl[r] = *(const short8*)&sAl[(wm + r * 16 + lrow) * BK + lq * 8];
        }
        #pragma unroll
        for (int c = 0; c < 4; ++c) {
            bfh[c] = *(const short8*)&sBh[(wn + c * 16 + lrow) * BK + lq * 8];
            bfl[c] = *(const short8*)&sBl[(wn + c * 16 + lrow) * BK + lq * 8];
        }
        #pragma unroll
        for (int r = 0; r < RT; ++r)
            #pragma unroll
            for (int c = 0; c < 4; ++c) {
                acc[r][c] = __builtin_amdgcn_mfma_f32_16x16x32_bf16(afh[r], bfh[c], acc[r][c], 0, 0, 0);
                acc[r][c] = __builtin_amdgcn_mfma_f32_16x16x32_bf16(afh[r], bfl[c], acc[r][c], 0, 0, 0);
                acc[r][c] = __builtin_amdgcn_mfma_f32_16x16x32_bf16(afl[r], bfh[c], acc[r][c], 0, 0, 0);
            }
        __syncthreads();
    }
    // H-store (C/D layout: col=lane&15, row=(lane>>4)*4+reg)
    #pragma unroll
    for (int r = 0; r < RT; ++r) {
        #pragma unroll
        for (int c = 0; c < 4; ++c) {
            int colg = n0 + wn + c * 16 + lrow;
            #pragma unroll
            for (int j = 0; j < 4; ++j) {
                int row = m0 + wm + r * 16 + lq * 4 + j;
                if (row < M) Hout[(size_t)row * NC + colg] = __float2half(acc[r][c][j]);
            }
        }
    }
    // fused attention logits: this wave's 64 cols lie in exactly one head
    int hh = (n0 + wn) >> 6;
    float asv[4], adv[4];
    #pragma unroll
    for (int c = 0; c < 4; ++c) {
        int cg = (n0 + wn + c * 16 + lrow) & 63;
        asv[c] = a_s[hh * 64 + cg];
        adv[c] = a_d[hh * 64 + cg];
    }
    #pragma unroll
    for (int r = 0; r < RT; ++r) {
        #pragma unroll
        for (int j = 0; j < 4; ++j) {
            float ts = 0.f, td = 0.f;
            #pragma unroll
            for (int c = 0; c < 4; ++c) {
                float v = acc[r][c][j];
                ts += v * asv[c];
                td += v * adv[c];
            }
            #pragma unroll
            for (int m = 1; m < 16; m <<= 1) {
                ts += __shfl_xor(ts, m);
                td += __shfl_xor(td, m);
            }
            int row = m0 + wm + r * 16 + lq * 4 + j;
            if (lrow == 0 && row < M) {
                als[row * H + hh] = ts;
                ald[row * H + hh] = td;
            }
        }
    }
}

// ---- fused aggregation + bias + BN + ELU: single pass, no max-subtraction ----
// (logits bounded ~|8| -> exp safe in fp32; softmax is shift-invariant)
// H=4: 2 edges x 32 lanes (x2 unroll);  H=1: 8 edges x 8 lanes.
template<int H, bool SPLIT>
__global__ __launch_bounds__(256)
void k_agg(const __half* __restrict__ h, const float* __restrict__ als,
           const float* __restrict__ ald, const int* __restrict__ rowp,
           const int* __restrict__ colv,
           const float* __restrict__ bias, const float* __restrict__ gam,
           const float* __restrict__ bet, const float* __restrict__ mu,
           const float* __restrict__ var,
           ushort_t* __restrict__ xh, ushort_t* __restrict__ xl,
           float* __restrict__ xf, int M) {
    constexpr int HC = H * 64;
    constexpr int EG = 512 / HC;        // edge groups: 2 (H=4), 8 (H=1)
    constexpr int L  = 64 / EG;         // lanes per edge: 32, 8
    constexpr int UN = (H == 4) ? 2 : 1;
    int node = blockIdx.x * 4 + (threadIdx.x >> 6);
    if (node >= M) return;
    int lane = threadIdx.x & 63;
    int rs = rowp[node], re = rowp[node + 1];
    int l = lane & (L - 1), eg = lane / L;
    int hB = (l * 8) >> 6;
    float ad = ald[node * H + hB];
    float den = 0.f;
    float acc[8] = {};
    for (int i = rs; i < re; i += EG * UN) {
        #pragma unroll
        for (int k = 0; k < UN; ++k) {
            int idx = i + eg + k * EG;
            bool vld = idx < re;
            int s = colv[vld ? idx : rs];
            float e = als[s * H + hB] + ad;
            e = e > 0.f ? e : 0.2f * e;
            float ee = vld ? __expf(e) : 0.f;
            den += ee;
            uint4 hv = *(const uint4*)(h + (size_t)s * HC + l * 8);
            float2 f0 = __half22float2(*(__half2*)&hv.x);
            float2 f1 = __half22float2(*(__half2*)&hv.y);
            float2 f2 = __half22float2(*(__half2*)&hv.z);
            float2 f3 = __half22float2(*(__half2*)&hv.w);
            acc[0] += ee * f0.x; acc[1] += ee * f0.y;
            acc[2] += ee * f1.x; acc[3] += ee * f1.y;
            acc[4] += ee * f2.x; acc[5] += ee * f2.y;
            acc[6] += ee * f3.x; acc[7] += ee * f3.y;
        }
    }
    #pragma unroll
    for (int off = L; off < 64; off <<= 1) {
        den += __shfl_xor(den, off);
        #pragma unroll
        for (int j = 0; j < 8; ++j) acc[j] += __shfl_xor(acc[j], off);
    }
    if (eg == 0) {
        float inv = 1.f / (den + 1e-16f);
        ushort_t hs[8], ls[8];
        float fo[8];
        #pragma unroll
        for (int j = 0; j < 8; ++j) {
            int d = l * 8 + j;
            float o = acc[j] * inv + bias[d];
            float bn = (o - mu[d]) * rsqrtf(var[d] + 1e-5f) * gam[d] + bet[d];
            float el = bn > 0.f ? bn : (__expf(bn) - 1.f);
            if constexpr (SPLIT) {
                uint_t u = __float_as_uint(el);
                hs[j] = (ushort_t)(u >> 16);
                ls[j] = f2b_rn(el - __uint_as_float(u & 0xffff0000u));
            } else {
                fo[j] = el;
            }
        }
        if constexpr (SPLIT) {
            uint4 ph, pl;
            ph.x = (uint_t)hs[0] | ((uint_t)hs[1] << 16);
            ph.y = (uint_t)hs[2] | ((uint_t)hs[3] << 16);
            ph.z = (uint_t)hs[4] | ((uint_t)hs[5] << 16);
            ph.w = (uint_t)hs[6] | ((uint_t)hs[7] << 16);
            pl.x = (uint_t)ls[0] | ((uint_t)ls[1] << 16);
            pl.y = (uint_t)ls[2] | ((uint_t)ls[3] << 16);
            pl.z = (uint_t)ls[4] | ((uint_t)ls[5] << 16);
            pl.w = (uint_t)ls[6] | ((uint_t)ls[7] << 16);
            *(uint4*)&xh[(size_t)node * HC + l * 8] = ph;
            *(uint4*)&xl[(size_t)node * HC + l * 8] = pl;
        } else {
            *(float4*)&xf[(size_t)node * HC + l * 8] = make_float4(fo[0], fo[1], fo[2], fo[3]);
            *(float4*)&xf[(size_t)node * HC + l * 8 + 4] = make_float4(fo[4], fo[5], fo[6], fo[7]);
        }
    }
}

// ---------------- fused pooling + MLP (block per graph, 64 threads) ----------------
__global__ void k_poolfc(const float* __restrict__ x, const int* __restrict__ batch,
                         const float* __restrict__ fc1w, const float* __restrict__ fc1b,
                         const float* __restrict__ fc2w, const float* __restrict__ fc2b,
                         const float* __restrict__ fc3w, const float* __restrict__ fc3b,
                         float* __restrict__ out, int M) {
    __shared__ float hb[192];
    __shared__ float h1[64];
    __shared__ float h2[32];
    int g = blockIdx.x, t = threadIdx.x;
    int lo = 0, hi = M;
    while (lo < hi) { int mid = (lo + hi) >> 1; if (batch[mid] < g) lo = mid + 1; else hi = mid; }
    int s = lo;
    lo = 0; hi = M;
    while (lo < hi) { int mid = (lo + hi) >> 1; if (batch[mid] < g + 1) lo = mid + 1; else hi = mid; }
    int e = lo;
    float sum = 0.f, mx = -3.0e38f;
    for (int n = s; n < e; ++n) {
        float v = x[(size_t)n * 64 + t];
        sum += v; mx = fmaxf(mx, v);
    }
    int cnt = e - s;
    hb[t] = sum / (float)(cnt > 1 ? cnt : 1);
    hb[64 + t] = (cnt == 0) ? 0.f : mx;
    hb[128 + t] = sum;
    __syncthreads();
    float s1 = fc1b[t];
    for (int k = 0; k < 192; ++k) s1 += hb[k] * fc1w[k * 64 + t];
    h1[t] = fmaxf(s1, 0.f);
    __syncthreads();
    if (t < 32) {
        float s2 = fc2b[t];
        for (int k = 0; k < 64; ++k) s2 += h1[k] * fc2w[k * 32 + t];
        h2[t] = fmaxf(s2, 0.f);
    }
    __syncthreads();
    if (t == 0) {
        float s3 = fc3b[0];
        for (int k = 0; k < 32; ++k) s3 += h2[k] * fc3w[k];
        out[g] = s3;
    }
}

extern "C" void kernel_launch(void* const* d_in, const int* in_sizes, int n_in,
                              void* d_out, int out_size, void* d_ws, size_t ws_size,
                              hipStream_t stream) {
    const float* x0     = (const float*)d_in[0];
    const int* ei       = (const int*)d_in[1];
    const int* batch    = (const int*)d_in[2];
    const float* W[3]   = {(const float*)d_in[3],  (const float*)d_in[11], (const float*)d_in[19]};
    const float* AS[3]  = {(const float*)d_in[4],  (const float*)d_in[12], (const float*)d_in[20]};
    const float* AD[3]  = {(const float*)d_in[5],  (const float*)d_in[13], (const float*)d_in[21]};
    const float* BI[3]  = {(const float*)d_in[6],  (const float*)d_in[14], (const float*)d_in[22]};
    const float* GA[3]  = {(const float*)d_in[7],  (const float*)d_in[15], (const float*)d_in[23]};
    const float* BE[3]  = {(const float*)d_in[8],  (const float*)d_in[16], (const float*)d_in[24]};
    const float* MU[3]  = {(const float*)d_in[9],  (const float*)d_in[17], (const float*)d_in[25]};
    const float* VA[3]  = {(const float*)d_in[10], (const float*)d_in[18], (const float*)d_in[26]};
    const float* fc1w = (const float*)d_in[27];
    const float* fc1b = (const float*)d_in[28];
    const float* fc2w = (const float*)d_in[29];
    const float* fc2b = (const float*)d_in[30];
    const float* fc3w = (const float*)d_in[31];
    const float* fc3b = (const float*)d_in[32];

    // top of use = 95,310,336 B (< 108,953,600 B proven safe)
    char* ws = (char*)d_ws;
    int*   rowp   = (int*)  (ws);                      // 200,004 B
    int*   colv   = (int*)  (ws + 200704);             // 3,400,000 B
    int*   bsum   = (int*)  (ws + 3600704);            // 1,024 B
    float* als    = (float*)(ws + 3602432);            // 800,000 B
    int*   cur    = (int*)  (ws + 3602432);            // 200,000 B (aliases als; dead before GEMM)
    float* ald    = (float*)(ws + 4402432);            // 800,000 B
    ushort_t* wTh = (ushort_t*)(ws + 5202432);         // 229,376 B (3 layers packed)
    ushort_t* wTl = (ushort_t*)(ws + 5431808);         // 229,376 B
    __half* h_buf = (__half*)(ws + 5661184);           // 25,600,000 B
    ushort_t* xh  = (ushort_t*)(ws + 31261184);        // 25,624,576 B (50048 rows x 256)
    ushort_t* xl  = (ushort_t*)(ws + 56885760);        // 25,624,576 B
    float* xpool  = (float*)(ws + 82510336);           // 12,800,000 B -> 95,310,336 B

    const int* esrc = ei;
    const int* edst = ei + NE;
    const int NB_SCAN = (NN + 255) / 256; // 196

    // CSR build
    hipMemsetAsync(cur, 0, NN * sizeof(int), stream);
    k_deg<<<(NE + 255) / 256, 256, 0, stream>>>(edst, cur, NE);
    k_scan1<<<NB_SCAN, 256, 0, stream>>>(cur, rowp, bsum, NN);
    k_scan2<<<1, 256, 0, stream>>>(bsum, NB_SCAN);
    k_scan3<<<NB_SCAN, 256, 0, stream>>>(rowp, bsum, cur, NN, NE + NN);
    k_fill<<<(NE + NN + 255) / 256, 256, 0, stream>>>(esrc, edst, rowp, cur, colv, NE, NN);

    // split input x and all weights
    k_asplit<<<(NN * 128 / 4 + 255) / 256, 256, 0, stream>>>(x0, xh, xl, NN * 128 / 4);
    k_wsplit_all<<<(114688 + 255) / 256, 256, 0, stream>>>(W[0], W[1], W[2], wTh, wTl);

    const int GB = (NN + 127) / 128; // 391
    int nwb = (NN + 3) / 4;          // 12500

    // ---- layer 0 (K=128, HC=256, H=4)
    k_mgemm<128, 128><<<dim3(GB, 2), 256, 0, stream>>>(xh, xl, wTh, wTl, h_buf,
                                                       AS[0], AD[0], als, ald, 4, NN, 256);
    k_agg<4, true><<<nwb, 256, 0, stream>>>(h_buf, als, ald, rowp, colv,
                                            BI[0], GA[0], BE[0], MU[0], VA[0],
                                            xh, xl, nullptr, NN);
    // ---- layer 1 (K=256, HC=256, H=4)
    k_mgemm<256, 128><<<dim3(GB, 2), 256, 0, stream>>>(xh, xl, wTh + 32768, wTl + 32768, h_buf,
                                                       AS[1], AD[1], als, ald, 4, NN, 256);
    k_agg<4, true><<<nwb, 256, 0, stream>>>(h_buf, als, ald, rowp, colv,
                                            BI[1], GA[1], BE[1], MU[1], VA[1],
                                            xh, xl, nullptr, NN);
    // ---- layer 2 (K=256, HC=64, H=1)
    k_mgemm<256, 64><<<dim3(GB, 1), 256, 0, stream>>>(xh, xl, wTh + 98304, wTl + 98304, h_buf,
                                                      AS[2], AD[2], als, ald, 1, NN, 64);
    k_agg<1, false><<<nwb, 256, 0, stream>>>(h_buf, als, ald, rowp, colv,
                                             BI[2], GA[2], BE[2], MU[2], VA[2],
                                             nullptr, nullptr, xpool, NN);

    // fused readout + MLP
    k_poolfc<<<NGR, 64, 0, stream>>>(xpool, batch, fc1w, fc1b, fc2w, fc2b, fc3w, fc3b,
                                     (float*)d_out, NN);
    (void)in_sizes; (void)n_in; (void)out_size; (void)ws_size;
}

// Round 11
// 556.179 us; speedup vs baseline: 2.6969x; 1.0416x over previous
//
#include <hip/hip_runtime.h>
#include <hip/hip_fp16.h>

typedef unsigned short ushort_t;
typedef unsigned int uint_t;
typedef __attribute__((ext_vector_type(8))) _Float16 half8;
typedef __attribute__((ext_vector_type(4))) float f32x4;

#define NN 50000
#define NE 800000
#define NGR 256

// async global->LDS, 16B per lane; LDS dest = wave-uniform base + lane*16
typedef __attribute__((address_space(3))) unsigned int as3_u32;
typedef const __attribute__((address_space(1))) unsigned int as1_u32c;
__device__ __forceinline__ void gld16(const ushort_t* g, void* lds_base) {
    __builtin_amdgcn_global_load_lds((as1_u32c*)g, (as3_u32*)lds_base, 16, 0, 0);
}

// ---------------- CSR build ----------------
__global__ void k_deg(const int* __restrict__ dst, int* __restrict__ deg, int E) {
    int i = blockIdx.x * 256 + threadIdx.x;
    if (i < E) atomicAdd(&deg[dst[i]], 1);
}

__global__ void k_scan1(const int* __restrict__ deg, int* __restrict__ rowp,
                        int* __restrict__ bsum, int M) {
    __shared__ int sm[256];
    int t = threadIdx.x, i = blockIdx.x * 256 + t;
    int v = (i < M) ? deg[i] + 1 : 0;   // +1 self loop
    sm[t] = v; __syncthreads();
    for (int off = 1; off < 256; off <<= 1) {
        int x = (t >= off) ? sm[t - off] : 0;
        __syncthreads();
        sm[t] += x;
        __syncthreads();
    }
    if (i < M) rowp[i] = sm[t] - v;     // exclusive
    if (t == 255) bsum[blockIdx.x] = sm[255];
}

__global__ void k_scan2(int* bsum, int NB) {
    __shared__ int sm[256];
    int t = threadIdx.x;
    int v = (t < NB) ? bsum[t] : 0;
    sm[t] = v; __syncthreads();
    for (int off = 1; off < 256; off <<= 1) {
        int x = (t >= off) ? sm[t - off] : 0;
        __syncthreads();
        sm[t] += x;
        __syncthreads();
    }
    if (t < NB) bsum[t] = sm[t] - v;    // exclusive block offsets
}

// also zeroes cur (aliases als) for k_fill
__global__ void k_scan3(int* rowp, const int* __restrict__ bsum, int* __restrict__ cur,
                        int M, int total) {
    int i = blockIdx.x * 256 + threadIdx.x;
    if (i < M) { rowp[i] += bsum[blockIdx.x]; cur[i] = 0; }
    if (i == 0) rowp[M] = total;
}

__global__ void k_fill(const int* __restrict__ src, const int* __restrict__ dst,
                       const int* __restrict__ rowp, int* __restrict__ cur,
                       int* __restrict__ colv, int E, int M) {
    int i = blockIdx.x * 256 + threadIdx.x;
    if (i < E) {
        int d = dst[i];
        int pos = rowp[d] + atomicAdd(&cur[d], 1);
        colv[pos] = src[i];
    } else if (i < E + M) {
        int nn = i - E;
        int pos = rowp[nn] + atomicAdd(&cur[nn], 1);
        colv[pos] = nn;
    }
}

// ---- fused prep: x0 fp32 -> fp16 (cast) AND all weights -> transposed fp16 hi/lo ----
// x part: 1,600,000 float4 groups. weight part: 114,688 elems after that.
__global__ void k_prep(const float* __restrict__ x0, __half* __restrict__ xf,
                       const float* __restrict__ W0, const float* __restrict__ W1,
                       const float* __restrict__ W2, __half* __restrict__ th,
                       __half* __restrict__ tl) {
    int i = blockIdx.x * 256 + threadIdx.x;
    if (i < 1600000) {
        float4 v = ((const float4*)x0)[i];
        __half2 a = __floats2half2_rn(v.x, v.y);
        __half2 b = __floats2half2_rn(v.z, v.w);
        *(__half2*)(xf + i * 4) = a;
        *(__half2*)(xf + i * 4 + 2) = b;
    } else if (i < 1600000 + 114688) {
        int w = i - 1600000;
        const float* W; int K, NC, idx, base;
        if (w < 32768)      { W = W0; K = 128; NC = 256; idx = w;         base = 0; }
        else if (w < 98304) { W = W1; K = 256; NC = 256; idx = w - 32768; base = 32768; }
        else                { W = W2; K = 256; NC = 64;  idx = w - 98304; base = 98304; }
        int k = idx / NC, n = idx % NC;
        float f = W[idx];
        __half hi = __float2half(f);
        th[base + n * K + k] = hi;
        tl[base + n * K + k] = __float2half(f - __half2float(hi));
    }
}

// ------- MFMA GEMM (fp16, 2-term W ladder) + fused attention-logit epilogue -------
// A[Mpad][KD] fp16; Bt{h,l}[NC][KD] fp16. acc = A*Wh + A*Wl.
template<int KD, int BN>
__global__ __launch_bounds__(256)
void k_mgemm(const __half* __restrict__ Ax, const __half* __restrict__ Bth,
             const __half* __restrict__ Btl, __half* __restrict__ Hout,
             const float* __restrict__ a_s, const float* __restrict__ a_d,
             float* __restrict__ als, float* __restrict__ ald,
             int H, int M, int NC) {
    constexpr int BM = 128, BK = 32;
    __shared__ ushort_t sA[BM * BK];
    __shared__ ushort_t sBh[BN * BK];
    __shared__ ushort_t sBl[BN * BK];
    const int tid = threadIdx.x;
    const int m0 = blockIdx.x * BM;
    const int n0 = blockIdx.y * BN;
    const int wv = tid >> 6, ln = tid & 63;
    const int lrow = ln & 15, lq = ln >> 4;
    constexpr int RT = (BN == 128) ? 4 : 2;
    int wm, wn;
    if constexpr (BN == 128) { wm = (wv >> 1) * 64; wn = (wv & 1) * 64; }
    else                     { wm = wv * 32;        wn = 0; }
    const int roff = ln >> 2;
    const int coff = (ln & 3) * 8;

    f32x4 acc[RT][4] = {};

    for (int k0 = 0; k0 < KD; k0 += BK) {
        #pragma unroll
        for (int ch = 0; ch < 2; ++ch) {
            int rb = wv * 32 + ch * 16;
            size_t ga = (size_t)(m0 + rb + roff) * KD + k0 + coff;
            gld16((const ushort_t*)Ax + ga, &sA[rb * BK]);
        }
        if constexpr (BN == 128) {
            #pragma unroll
            for (int ch = 0; ch < 2; ++ch) {
                int rb = wv * 32 + ch * 16;
                size_t gb = (size_t)(n0 + rb + roff) * KD + k0 + coff;
                gld16((const ushort_t*)Bth + gb, &sBh[rb * BK]);
                gld16((const ushort_t*)Btl + gb, &sBl[rb * BK]);
            }
        } else {
            int rb = wv * 16;
            size_t gb = (size_t)(n0 + rb + roff) * KD + k0 + coff;
            gld16((const ushort_t*)Bth + gb, &sBh[rb * BK]);
            gld16((const ushort_t*)Btl + gb, &sBl[rb * BK]);
        }
        __syncthreads();
        half8 af[RT], bfh[4], bfl[4];
        #pragma unroll
        for (int r = 0; r < RT; ++r)
            af[r] = *(const half8*)&sA[(wm + r * 16 + lrow) * BK + lq * 8];
        #pragma unroll
        for (int c = 0; c < 4; ++c) {
            bfh[c] = *(const half8*)&sBh[(wn + c * 16 + lrow) * BK + lq * 8];
            bfl[c] = *(const half8*)&sBl[(wn + c * 16 + lrow) * BK + lq * 8];
        }
        #pragma unroll
        for (int r = 0; r < RT; ++r)
            #pragma unroll
            for (int c = 0; c < 4; ++c) {
                acc[r][c] = __builtin_amdgcn_mfma_f32_16x16x32_f16(af[r], bfh[c], acc[r][c], 0, 0, 0);
                acc[r][c] = __builtin_amdgcn_mfma_f32_16x16x32_f16(af[r], bfl[c], acc[r][c], 0, 0, 0);
            }
        __syncthreads();
    }
    // H-store (C/D layout: col=lane&15, row=(lane>>4)*4+reg)
    #pragma unroll
    for (int r = 0; r < RT; ++r) {
        #pragma unroll
        for (int c = 0; c < 4; ++c) {
            int colg = n0 + wn + c * 16 + lrow;
            #pragma unroll
            for (int j = 0; j < 4; ++j) {
                int row = m0 + wm + r * 16 + lq * 4 + j;
                if (row < M) Hout[(size_t)row * NC + colg] = __float2half(acc[r][c][j]);
            }
        }
    }
    // fused attention logits: this wave's 64 cols lie in exactly one head
    int hh = (n0 + wn) >> 6;
    float asv[4], adv[4];
    #pragma unroll
    for (int c = 0; c < 4; ++c) {
        int cg = (n0 + wn + c * 16 + lrow) & 63;
        asv[c] = a_s[hh * 64 + cg];
        adv[c] = a_d[hh * 64 + cg];
    }
    #pragma unroll
    for (int r = 0; r < RT; ++r) {
        #pragma unroll
        for (int j = 0; j < 4; ++j) {
            float ts = 0.f, td = 0.f;
            #pragma unroll
            for (int c = 0; c < 4; ++c) {
                float v = acc[r][c][j];
                ts += v * asv[c];
                td += v * adv[c];
            }
            #pragma unroll
            for (int m = 1; m < 16; m <<= 1) {
                ts += __shfl_xor(ts, m);
                td += __shfl_xor(td, m);
            }
            int row = m0 + wm + r * 16 + lq * 4 + j;
            if (lrow == 0 && row < M) {
                als[row * H + hh] = ts;
                ald[row * H + hh] = td;
            }
        }
    }
}

// ---- fused aggregation + bias + BN + ELU: single pass, no max-subtraction ----
// H=4: 2 edges x 32 lanes (x4 unroll -> 8 in flight);  H=1: 8 edges x 8 lanes.
// SPLIT: write fp16 x (next GEMM input); else fp32 (pooling input).
template<int H, bool SPLIT>
__global__ __launch_bounds__(256)
void k_agg(const __half* __restrict__ h, const float* __restrict__ als,
           const float* __restrict__ ald, const int* __restrict__ rowp,
           const int* __restrict__ colv,
           const float* __restrict__ bias, const float* __restrict__ gam,
           const float* __restrict__ bet, const float* __restrict__ mu,
           const float* __restrict__ var,
           __half* __restrict__ xo, float* __restrict__ xf, int M) {
    constexpr int HC = H * 64;
    constexpr int EG = 512 / HC;        // edge groups: 2 (H=4), 8 (H=1)
    constexpr int L  = 64 / EG;         // lanes per edge: 32, 8
    constexpr int UN = (H == 4) ? 4 : 1;
    int node = blockIdx.x * 4 + (threadIdx.x >> 6);
    if (node >= M) return;
    int lane = threadIdx.x & 63;
    int rs = rowp[node], re = rowp[node + 1];
    int l = lane & (L - 1), eg = lane / L;
    int hB = (l * 8) >> 6;
    float ad = ald[node * H + hB];
    float den = 0.f;
    float acc[8] = {};
    for (int i = rs; i < re; i += EG * UN) {
        #pragma unroll
        for (int k = 0; k < UN; ++k) {
            int idx = i + eg + k * EG;
            bool vld = idx < re;
            int s = colv[vld ? idx : rs];
            float e = als[s * H + hB] + ad;
            e = e > 0.f ? e : 0.2f * e;
            float ee = vld ? __expf(e) : 0.f;
            den += ee;
            uint4 hv = *(const uint4*)(h + (size_t)s * HC + l * 8);
            float2 f0 = __half22float2(*(__half2*)&hv.x);
            float2 f1 = __half22float2(*(__half2*)&hv.y);
            float2 f2 = __half22float2(*(__half2*)&hv.z);
            float2 f3 = __half22float2(*(__half2*)&hv.w);
            acc[0] += ee * f0.x; acc[1] += ee * f0.y;
            acc[2] += ee * f1.x; acc[3] += ee * f1.y;
            acc[4] += ee * f2.x; acc[5] += ee * f2.y;
            acc[6] += ee * f3.x; acc[7] += ee * f3.y;
        }
    }
    #pragma unroll
    for (int off = L; off < 64; off <<= 1) {
        den += __shfl_xor(den, off);
        #pragma unroll
        for (int j = 0; j < 8; ++j) acc[j] += __shfl_xor(acc[j], off);
    }
    if (eg == 0) {
        float inv = 1.f / (den + 1e-16f);
        float fo[8];
        #pragma unroll
        for (int j = 0; j < 8; ++j) {
            int d = l * 8 + j;
            float o = acc[j] * inv + bias[d];
            float bn = (o - mu[d]) * rsqrtf(var[d] + 1e-5f) * gam[d] + bet[d];
            fo[j] = bn > 0.f ? bn : (__expf(bn) - 1.f);
        }
        if constexpr (SPLIT) {
            __half2 p0 = __floats2half2_rn(fo[0], fo[1]);
            __half2 p1 = __floats2half2_rn(fo[2], fo[3]);
            __half2 p2 = __floats2half2_rn(fo[4], fo[5]);
            __half2 p3 = __floats2half2_rn(fo[6], fo[7]);
            uint4 pk;
            pk.x = *(uint_t*)&p0; pk.y = *(uint_t*)&p1;
            pk.z = *(uint_t*)&p2; pk.w = *(uint_t*)&p3;
            *(uint4*)&xo[(size_t)node * HC + l * 8] = pk;
        } else {
            *(float4*)&xf[(size_t)node * HC + l * 8] = make_float4(fo[0], fo[1], fo[2], fo[3]);
            *(float4*)&xf[(size_t)node * HC + l * 8 + 4] = make_float4(fo[4], fo[5], fo[6], fo[7]);
        }
    }
}

// ---------------- fused pooling + MLP (block per graph, 64 threads) ----------------
__global__ void k_poolfc(const float* __restrict__ x, const int* __restrict__ batch,
                         const float* __restrict__ fc1w, const float* __restrict__ fc1b,
                         const float* __restrict__ fc2w, const float* __restrict__ fc2b,
                         const float* __restrict__ fc3w, const float* __restrict__ fc3b,
                         float* __restrict__ out, int M) {
    __shared__ float hb[192];
    __shared__ float h1[64];
    __shared__ float h2[32];
    int g = blockIdx.x, t = threadIdx.x;
    int lo = 0, hi = M;
    while (lo < hi) { int mid = (lo + hi) >> 1; if (batch[mid] < g) lo = mid + 1; else hi = mid; }
    int s = lo;
    lo = 0; hi = M;
    while (lo < hi) { int mid = (lo + hi) >> 1; if (batch[mid] < g + 1) lo = mid + 1; else hi = mid; }
    int e = lo;
    float sum = 0.f, mx = -3.0e38f;
    for (int n = s; n < e; ++n) {
        float v = x[(size_t)n * 64 + t];
        sum += v; mx = fmaxf(mx, v);
    }
    int cnt = e - s;
    hb[t] = sum / (float)(cnt > 1 ? cnt : 1);
    hb[64 + t] = (cnt == 0) ? 0.f : mx;
    hb[128 + t] = sum;
    __syncthreads();
    float s1 = fc1b[t];
    for (int k = 0; k < 192; ++k) s1 += hb[k] * fc1w[k * 64 + t];
    h1[t] = fmaxf(s1, 0.f);
    __syncthreads();
    if (t < 32) {
        float s2 = fc2b[t];
        for (int k = 0; k < 64; ++k) s2 += h1[k] * fc2w[k * 32 + t];
        h2[t] = fmaxf(s2, 0.f);
    }
    __syncthreads();
    if (t == 0) {
        float s3 = fc3b[0];
        for (int k = 0; k < 32; ++k) s3 += h2[k] * fc3w[k];
        out[g] = s3;
    }
}

extern "C" void kernel_launch(void* const* d_in, const int* in_sizes, int n_in,
                              void* d_out, int out_size, void* d_ws, size_t ws_size,
                              hipStream_t stream) {
    const float* x0     = (const float*)d_in[0];
    const int* ei       = (const int*)d_in[1];
    const int* batch    = (const int*)d_in[2];
    const float* W[3]   = {(const float*)d_in[3],  (const float*)d_in[11], (const float*)d_in[19]};
    const float* AS[3]  = {(const float*)d_in[4],  (const float*)d_in[12], (const float*)d_in[20]};
    const float* AD[3]  = {(const float*)d_in[5],  (const float*)d_in[13], (const float*)d_in[21]};
    const float* BI[3]  = {(const float*)d_in[6],  (const float*)d_in[14], (const float*)d_in[22]};
    const float* GA[3]  = {(const float*)d_in[7],  (const float*)d_in[15], (const float*)d_in[23]};
    const float* BE[3]  = {(const float*)d_in[8],  (const float*)d_in[16], (const float*)d_in[24]};
    const float* MU[3]  = {(const float*)d_in[9],  (const float*)d_in[17], (const float*)d_in[25]};
    const float* VA[3]  = {(const float*)d_in[10], (const float*)d_in[18], (const float*)d_in[26]};
    const float* fc1w = (const float*)d_in[27];
    const float* fc1b = (const float*)d_in[28];
    const float* fc2w = (const float*)d_in[29];
    const float* fc2b = (const float*)d_in[30];
    const float* fc3w = (const float*)d_in[31];
    const float* fc3b = (const float*)d_in[32];

    // top of use = 69,884,160 B (< 108,953,600 B proven safe)
    char* ws = (char*)d_ws;
    int*   rowp   = (int*)  (ws);                      // 200,004 B
    int*   colv   = (int*)  (ws + 200704);             // 3,400,000 B
    int*   bsum   = (int*)  (ws + 3600704);            // 1,024 B
    float* als    = (float*)(ws + 3602432);            // 800,000 B
    int*   cur    = (int*)  (ws + 3602432);            // 200,000 B (aliases als; dead before GEMM)
    float* ald    = (float*)(ws + 4402432);            // 800,000 B
    __half* wTh   = (__half*)(ws + 5202432);           // 229,376 B (3 layers packed)
    __half* wTl   = (__half*)(ws + 5431808);           // 229,376 B
    __half* h_buf = (__half*)(ws + 5661184);           // 25,600,000 B
    __half* xf16  = (__half*)(ws + 31261184);          // 25,624,576 B (50048 rows x 256)
    float* xpool  = (float*)(ws + 56885760);           // 12,800,000 B -> 69,685,760 B

    const int* esrc = ei;
    const int* edst = ei + NE;
    const int NB_SCAN = (NN + 255) / 256; // 196

    // CSR build
    hipMemsetAsync(cur, 0, NN * sizeof(int), stream);
    k_deg<<<(NE + 255) / 256, 256, 0, stream>>>(edst, cur, NE);
    k_scan1<<<NB_SCAN, 256, 0, stream>>>(cur, rowp, bsum, NN);
    k_scan2<<<1, 256, 0, stream>>>(bsum, NB_SCAN);
    k_scan3<<<NB_SCAN, 256, 0, stream>>>(rowp, bsum, cur, NN, NE + NN);
    k_fill<<<(NE + NN + 255) / 256, 256, 0, stream>>>(esrc, edst, rowp, cur, colv, NE, NN);

    // fused prep: x cast + weight transpose/split
    k_prep<<<(1600000 + 114688 + 255) / 256, 256, 0, stream>>>(x0, xf16, W[0], W[1], W[2],
                                                               wTh, wTl);

    const int GB = (NN + 127) / 128; // 391
    int nwb = (NN + 3) / 4;          // 12500

    // ---- layer 0 (K=128, HC=256, H=4)
    k_mgemm<128, 128><<<dim3(GB, 2), 256, 0, stream>>>(xf16, wTh, wTl, h_buf,
                                                       AS[0], AD[0], als, ald, 4, NN, 256);
    k_agg<4, true><<<nwb, 256, 0, stream>>>(h_buf, als, ald, rowp, colv,
                                            BI[0], GA[0], BE[0], MU[0], VA[0],
                                            xf16, nullptr, NN);
    // ---- layer 1 (K=256, HC=256, H=4)
    k_mgemm<256, 128><<<dim3(GB, 2), 256, 0, stream>>>(xf16, wTh + 32768, wTl + 32768, h_buf,
                                                       AS[1], AD[1], als, ald, 4, NN, 256);
    k_agg<4, true><<<nwb, 256, 0, stream>>>(h_buf, als, ald, rowp, colv,
                                            BI[1], GA[1], BE[1], MU[1], VA[1],
                                            xf16, nullptr, NN);
    // ---- layer 2 (K=256, HC=64, H=1)
    k_mgemm<256, 64><<<dim3(GB, 1), 256, 0, stream>>>(xf16, wTh + 98304, wTl + 98304, h_buf,
                                                      AS[2], AD[2], als, ald, 1, NN, 64);
    k_agg<1, false><<<nwb, 256, 0, stream>>>(h_buf, als, ald, rowp, colv,
                                             BI[2], GA[2], BE[2], MU[2], VA[2],
                                             nullptr, xpool, NN);

    // fused readout + MLP
    k_poolfc<<<NGR, 64, 0, stream>>>(xpool, batch, fc1w, fc1b, fc2w, fc2b, fc3w, fc3b,
                                     (float*)d_out, NN);
    (void)in_sizes; (void)n_in; (void)out_size; (void)ws_size;
}

// Round 12
// 534.162 us; speedup vs baseline: 2.8081x; 1.0412x over previous
//
#include <hip/hip_runtime.h>
#include <hip/hip_fp16.h>

typedef unsigned short ushort_t;
typedef unsigned int uint_t;
typedef __attribute__((ext_vector_type(8))) _Float16 half8;
typedef __attribute__((ext_vector_type(4))) float f32x4;

#define NN 50000
#define NE 800000
#define NGR 256

// async global->LDS, 16B per lane; LDS dest = wave-uniform base + lane*16
typedef __attribute__((address_space(3))) unsigned int as3_u32;
typedef const __attribute__((address_space(1))) unsigned int as1_u32c;
__device__ __forceinline__ void gld16(const ushort_t* g, void* lds_base) {
    __builtin_amdgcn_global_load_lds((as1_u32c*)g, (as3_u32*)lds_base, 16, 0, 0);
}

// ---------------- CSR build ----------------
__global__ void k_deg(const int* __restrict__ dst, int* __restrict__ deg, int E) {
    int i = blockIdx.x * 256 + threadIdx.x;
    if (i < E) atomicAdd(&deg[dst[i]], 1);
}

__global__ void k_scan1(const int* __restrict__ deg, int* __restrict__ rowp,
                        int* __restrict__ bsum, int M) {
    __shared__ int sm[256];
    int t = threadIdx.x, i = blockIdx.x * 256 + t;
    int v = (i < M) ? deg[i] + 1 : 0;   // +1 self loop
    sm[t] = v; __syncthreads();
    for (int off = 1; off < 256; off <<= 1) {
        int x = (t >= off) ? sm[t - off] : 0;
        __syncthreads();
        sm[t] += x;
        __syncthreads();
    }
    if (i < M) rowp[i] = sm[t] - v;     // exclusive
    if (t == 255) bsum[blockIdx.x] = sm[255];
}

__global__ void k_scan2(int* bsum, int NB) {
    __shared__ int sm[256];
    int t = threadIdx.x;
    int v = (t < NB) ? bsum[t] : 0;
    sm[t] = v; __syncthreads();
    for (int off = 1; off < 256; off <<= 1) {
        int x = (t >= off) ? sm[t - off] : 0;
        __syncthreads();
        sm[t] += x;
        __syncthreads();
    }
    if (t < NB) bsum[t] = sm[t] - v;    // exclusive block offsets
}

// also zeroes cur (aliases als) for k_fill
__global__ void k_scan3(int* rowp, const int* __restrict__ bsum, int* __restrict__ cur,
                        int M, int total) {
    int i = blockIdx.x * 256 + threadIdx.x;
    if (i < M) { rowp[i] += bsum[blockIdx.x]; cur[i] = 0; }
    if (i == 0) rowp[M] = total;
}

__global__ void k_fill(const int* __restrict__ src, const int* __restrict__ dst,
                       const int* __restrict__ rowp, int* __restrict__ cur,
                       int* __restrict__ colv, int E, int M) {
    int i = blockIdx.x * 256 + threadIdx.x;
    if (i < E) {
        int d = dst[i];
        int pos = rowp[d] + atomicAdd(&cur[d], 1);
        colv[pos] = src[i];
    } else if (i < E + M) {
        int nn = i - E;
        int pos = rowp[nn] + atomicAdd(&cur[nn], 1);
        colv[pos] = nn;
    }
}

// ---- fused prep: x0 fp32 -> fp16 (cast) AND all weights -> transposed fp16 hi/lo ----
__global__ void k_prep(const float* __restrict__ x0, __half* __restrict__ xf,
                       const float* __restrict__ W0, const float* __restrict__ W1,
                       const float* __restrict__ W2, __half* __restrict__ th,
                       __half* __restrict__ tl) {
    int i = blockIdx.x * 256 + threadIdx.x;
    if (i < 1600000) {
        float4 v = ((const float4*)x0)[i];
        __half2 a = __floats2half2_rn(v.x, v.y);
        __half2 b = __floats2half2_rn(v.z, v.w);
        *(__half2*)(xf + i * 4) = a;
        *(__half2*)(xf + i * 4 + 2) = b;
    } else if (i < 1600000 + 114688) {
        int w = i - 1600000;
        const float* W; int K, NC, idx, base;
        if (w < 32768)      { W = W0; K = 128; NC = 256; idx = w;         base = 0; }
        else if (w < 98304) { W = W1; K = 256; NC = 256; idx = w - 32768; base = 32768; }
        else                { W = W2; K = 256; NC = 64;  idx = w - 98304; base = 98304; }
        int k = idx / NC, n = idx % NC;
        float f = W[idx];
        __half hi = __float2half(f);
        th[base + n * K + k] = hi;
        tl[base + n * K + k] = __float2half(f - __half2float(hi));
    }
}

// ------- MFMA GEMM (fp16, 2-term W ladder) + fused attention-logit epilogue -------
template<int KD, int BN>
__global__ __launch_bounds__(256)
void k_mgemm(const __half* __restrict__ Ax, const __half* __restrict__ Bth,
             const __half* __restrict__ Btl, __half* __restrict__ Hout,
             const float* __restrict__ a_s, const float* __restrict__ a_d,
             float* __restrict__ als, float* __restrict__ ald,
             int H, int M, int NC) {
    constexpr int BM = 128, BK = 32;
    __shared__ ushort_t sA[BM * BK];
    __shared__ ushort_t sBh[BN * BK];
    __shared__ ushort_t sBl[BN * BK];
    const int tid = threadIdx.x;
    const int m0 = blockIdx.x * BM;
    const int n0 = blockIdx.y * BN;
    const int wv = tid >> 6, ln = tid & 63;
    const int lrow = ln & 15, lq = ln >> 4;
    constexpr int RT = (BN == 128) ? 4 : 2;
    int wm, wn;
    if constexpr (BN == 128) { wm = (wv >> 1) * 64; wn = (wv & 1) * 64; }
    else                     { wm = wv * 32;        wn = 0; }
    const int roff = ln >> 2;
    const int coff = (ln & 3) * 8;

    f32x4 acc[RT][4] = {};

    for (int k0 = 0; k0 < KD; k0 += BK) {
        #pragma unroll
        for (int ch = 0; ch < 2; ++ch) {
            int rb = wv * 32 + ch * 16;
            size_t ga = (size_t)(m0 + rb + roff) * KD + k0 + coff;
            gld16((const ushort_t*)Ax + ga, &sA[rb * BK]);
        }
        if constexpr (BN == 128) {
            #pragma unroll
            for (int ch = 0; ch < 2; ++ch) {
                int rb = wv * 32 + ch * 16;
                size_t gb = (size_t)(n0 + rb + roff) * KD + k0 + coff;
                gld16((const ushort_t*)Bth + gb, &sBh[rb * BK]);
                gld16((const ushort_t*)Btl + gb, &sBl[rb * BK]);
            }
        } else {
            int rb = wv * 16;
            size_t gb = (size_t)(n0 + rb + roff) * KD + k0 + coff;
            gld16((const ushort_t*)Bth + gb, &sBh[rb * BK]);
            gld16((const ushort_t*)Btl + gb, &sBl[rb * BK]);
        }
        __syncthreads();
        half8 af[RT], bfh[4], bfl[4];
        #pragma unroll
        for (int r = 0; r < RT; ++r)
            af[r] = *(const half8*)&sA[(wm + r * 16 + lrow) * BK + lq * 8];
        #pragma unroll
        for (int c = 0; c < 4; ++c) {
            bfh[c] = *(const half8*)&sBh[(wn + c * 16 + lrow) * BK + lq * 8];
            bfl[c] = *(const half8*)&sBl[(wn + c * 16 + lrow) * BK + lq * 8];
        }
        #pragma unroll
        for (int r = 0; r < RT; ++r)
            #pragma unroll
            for (int c = 0; c < 4; ++c) {
                acc[r][c] = __builtin_amdgcn_mfma_f32_16x16x32_f16(af[r], bfh[c], acc[r][c], 0, 0, 0);
                acc[r][c] = __builtin_amdgcn_mfma_f32_16x16x32_f16(af[r], bfl[c], acc[r][c], 0, 0, 0);
            }
        __syncthreads();
    }
    // H-store (C/D layout: col=lane&15, row=(lane>>4)*4+reg)
    #pragma unroll
    for (int r = 0; r < RT; ++r) {
        #pragma unroll
        for (int c = 0; c < 4; ++c) {
            int colg = n0 + wn + c * 16 + lrow;
            #pragma unroll
            for (int j = 0; j < 4; ++j) {
                int row = m0 + wm + r * 16 + lq * 4 + j;
                if (row < M) Hout[(size_t)row * NC + colg] = __float2half(acc[r][c][j]);
            }
        }
    }
    // fused attention logits: this wave's 64 cols lie in exactly one head
    int hh = (n0 + wn) >> 6;
    float asv[4], adv[4];
    #pragma unroll
    for (int c = 0; c < 4; ++c) {
        int cg = (n0 + wn + c * 16 + lrow) & 63;
        asv[c] = a_s[hh * 64 + cg];
        adv[c] = a_d[hh * 64 + cg];
    }
    #pragma unroll
    for (int r = 0; r < RT; ++r) {
        #pragma unroll
        for (int j = 0; j < 4; ++j) {
            float ts = 0.f, td = 0.f;
            #pragma unroll
            for (int c = 0; c < 4; ++c) {
                float v = acc[r][c][j];
                ts += v * asv[c];
                td += v * adv[c];
            }
            #pragma unroll
            for (int m = 1; m < 16; m <<= 1) {
                ts += __shfl_xor(ts, m);
                td += __shfl_xor(td, m);
            }
            int row = m0 + wm + r * 16 + lq * 4 + j;
            if (lrow == 0 && row < M) {
                als[row * H + hh] = ts;
                ald[row * H + hh] = td;
            }
        }
    }
}

// ---- per-edge raw exp + per-node 1/den: 16 lanes per node, edge-parallel ----
template<int H>
__global__ __launch_bounds__(256)
void k_att(const float* __restrict__ als, const float* __restrict__ ald,
           const int* __restrict__ rowp, const int* __restrict__ colv,
           float* __restrict__ alpha, float* __restrict__ invb, int M) {
    int node = blockIdx.x * 16 + (threadIdx.x >> 4);
    if (node >= M) return;
    int l = threadIdx.x & 15;
    int rs = rowp[node], re = rowp[node + 1];
    if constexpr (H == 4) {
        float4 ad = *(const float4*)(ald + node * 4);
        float d0 = 0.f, d1 = 0.f, d2 = 0.f, d3 = 0.f;
        for (int i = rs + l; i < re; i += 16) {
            int s = colv[i];
            float4 av = *(const float4*)(als + s * 4);
            float e0 = av.x + ad.x; e0 = e0 > 0.f ? e0 : 0.2f * e0; e0 = __expf(e0);
            float e1 = av.y + ad.y; e1 = e1 > 0.f ? e1 : 0.2f * e1; e1 = __expf(e1);
            float e2 = av.z + ad.z; e2 = e2 > 0.f ? e2 : 0.2f * e2; e2 = __expf(e2);
            float e3 = av.w + ad.w; e3 = e3 > 0.f ? e3 : 0.2f * e3; e3 = __expf(e3);
            d0 += e0; d1 += e1; d2 += e2; d3 += e3;
            *(float4*)(alpha + (size_t)i * 4) = make_float4(e0, e1, e2, e3);
        }
        #pragma unroll
        for (int off = 1; off < 16; off <<= 1) {
            d0 += __shfl_xor(d0, off); d1 += __shfl_xor(d1, off);
            d2 += __shfl_xor(d2, off); d3 += __shfl_xor(d3, off);
        }
        if (l == 0)
            *(float4*)(invb + node * 4) = make_float4(1.f / (d0 + 1e-16f), 1.f / (d1 + 1e-16f),
                                                      1.f / (d2 + 1e-16f), 1.f / (d3 + 1e-16f));
    } else {
        float ad = ald[node];
        float d = 0.f;
        for (int i = rs + l; i < re; i += 16) {
            int s = colv[i];
            float e = als[s] + ad; e = e > 0.f ? e : 0.2f * e; e = __expf(e);
            d += e;
            alpha[i] = e;
        }
        #pragma unroll
        for (int off = 1; off < 16; off <<= 1) d += __shfl_xor(d, off);
        if (l == 0) invb[node] = 1.f / (d + 1e-16f);
    }
}

// ---- aggregation + bias + BN + ELU: gather loop reads precomputed raw-exp alpha ----
// H=4: 2 edges x 32 lanes (x4 unroll);  H=1: 8 edges x 8 lanes (x2 unroll).
template<int H, bool SPLIT>
__global__ __launch_bounds__(256)
void k_agg(const __half* __restrict__ h, const float* __restrict__ alpha,
           const float* __restrict__ invb, const int* __restrict__ rowp,
           const int* __restrict__ colv,
           const float* __restrict__ bias, const float* __restrict__ gam,
           const float* __restrict__ bet, const float* __restrict__ mu,
           const float* __restrict__ var,
           __half* __restrict__ xo, float* __restrict__ xf, int M) {
    constexpr int HC = H * 64;
    constexpr int EG = 512 / HC;        // edge groups: 2 (H=4), 8 (H=1)
    constexpr int L  = 64 / EG;         // lanes per edge: 32, 8
    constexpr int UN = (H == 4) ? 4 : 2;
    int node = blockIdx.x * 4 + (threadIdx.x >> 6);
    if (node >= M) return;
    int lane = threadIdx.x & 63;
    int rs = rowp[node], re = rowp[node + 1];
    int l = lane & (L - 1), eg = lane / L;
    int hB = (l * 8) >> 6;
    float acc[8] = {};
    for (int i = rs; i < re; i += EG * UN) {
        #pragma unroll
        for (int k = 0; k < UN; ++k) {
            int idx = i + eg + k * EG;
            bool vld = idx < re;
            int idx2 = vld ? idx : rs;
            int s = colv[idx2];
            float a;
            if constexpr (H == 4) a = alpha[(size_t)idx2 * 4 + hB];
            else                  a = alpha[idx2];
            a = vld ? a : 0.f;
            uint4 hv = *(const uint4*)(h + (size_t)s * HC + l * 8);
            float2 f0 = __half22float2(*(__half2*)&hv.x);
            float2 f1 = __half22float2(*(__half2*)&hv.y);
            float2 f2 = __half22float2(*(__half2*)&hv.z);
            float2 f3 = __half22float2(*(__half2*)&hv.w);
            acc[0] += a * f0.x; acc[1] += a * f0.y;
            acc[2] += a * f1.x; acc[3] += a * f1.y;
            acc[4] += a * f2.x; acc[5] += a * f2.y;
            acc[6] += a * f3.x; acc[7] += a * f3.y;
        }
    }
    #pragma unroll
    for (int off = L; off < 64; off <<= 1) {
        #pragma unroll
        for (int j = 0; j < 8; ++j) acc[j] += __shfl_xor(acc[j], off);
    }
    if (eg == 0) {
        float inv = (H == 4) ? invb[node * 4 + hB] : invb[node];
        float fo[8];
        #pragma unroll
        for (int j = 0; j < 8; ++j) {
            int d = l * 8 + j;
            float o = acc[j] * inv + bias[d];
            float bn = (o - mu[d]) * rsqrtf(var[d] + 1e-5f) * gam[d] + bet[d];
            fo[j] = bn > 0.f ? bn : (__expf(bn) - 1.f);
        }
        if constexpr (SPLIT) {
            __half2 p0 = __floats2half2_rn(fo[0], fo[1]);
            __half2 p1 = __floats2half2_rn(fo[2], fo[3]);
            __half2 p2 = __floats2half2_rn(fo[4], fo[5]);
            __half2 p3 = __floats2half2_rn(fo[6], fo[7]);
            uint4 pk;
            pk.x = *(uint_t*)&p0; pk.y = *(uint_t*)&p1;
            pk.z = *(uint_t*)&p2; pk.w = *(uint_t*)&p3;
            *(uint4*)&xo[(size_t)node * HC + l * 8] = pk;
        } else {
            *(float4*)&xf[(size_t)node * HC + l * 8] = make_float4(fo[0], fo[1], fo[2], fo[3]);
            *(float4*)&xf[(size_t)node * HC + l * 8 + 4] = make_float4(fo[4], fo[5], fo[6], fo[7]);
        }
    }
}

// ---------------- fused pooling + MLP (block per graph, 64 threads) ----------------
__global__ void k_poolfc(const float* __restrict__ x, const int* __restrict__ batch,
                         const float* __restrict__ fc1w, const float* __restrict__ fc1b,
                         const float* __restrict__ fc2w, const float* __restrict__ fc2b,
                         const float* __restrict__ fc3w, const float* __restrict__ fc3b,
                         float* __restrict__ out, int M) {
    __shared__ float hb[192];
    __shared__ float h1[64];
    __shared__ float h2[32];
    int g = blockIdx.x, t = threadIdx.x;
    int lo = 0, hi = M;
    while (lo < hi) { int mid = (lo + hi) >> 1; if (batch[mid] < g) lo = mid + 1; else hi = mid; }
    int s = lo;
    lo = 0; hi = M;
    while (lo < hi) { int mid = (lo + hi) >> 1; if (batch[mid] < g + 1) lo = mid + 1; else hi = mid; }
    int e = lo;
    float sum = 0.f, mx = -3.0e38f;
    for (int n = s; n < e; ++n) {
        float v = x[(size_t)n * 64 + t];
        sum += v; mx = fmaxf(mx, v);
    }
    int cnt = e - s;
    hb[t] = sum / (float)(cnt > 1 ? cnt : 1);
    hb[64 + t] = (cnt == 0) ? 0.f : mx;
    hb[128 + t] = sum;
    __syncthreads();
    float s1 = fc1b[t];
    for (int k = 0; k < 192; ++k) s1 += hb[k] * fc1w[k * 64 + t];
    h1[t] = fmaxf(s1, 0.f);
    __syncthreads();
    if (t < 32) {
        float s2 = fc2b[t];
        for (int k = 0; k < 64; ++k) s2 += h1[k] * fc2w[k * 32 + t];
        h2[t] = fmaxf(s2, 0.f);
    }
    __syncthreads();
    if (t == 0) {
        float s3 = fc3b[0];
        for (int k = 0; k < 32; ++k) s3 += h2[k] * fc3w[k];
        out[g] = s3;
    }
}

extern "C" void kernel_launch(void* const* d_in, const int* in_sizes, int n_in,
                              void* d_out, int out_size, void* d_ws, size_t ws_size,
                              hipStream_t stream) {
    const float* x0     = (const float*)d_in[0];
    const int* ei       = (const int*)d_in[1];
    const int* batch    = (const int*)d_in[2];
    const float* W[3]   = {(const float*)d_in[3],  (const float*)d_in[11], (const float*)d_in[19]};
    const float* AS[3]  = {(const float*)d_in[4],  (const float*)d_in[12], (const float*)d_in[20]};
    const float* AD[3]  = {(const float*)d_in[5],  (const float*)d_in[13], (const float*)d_in[21]};
    const float* BI[3]  = {(const float*)d_in[6],  (const float*)d_in[14], (const float*)d_in[22]};
    const float* GA[3]  = {(const float*)d_in[7],  (const float*)d_in[15], (const float*)d_in[23]};
    const float* BE[3]  = {(const float*)d_in[8],  (const float*)d_in[16], (const float*)d_in[24]};
    const float* MU[3]  = {(const float*)d_in[9],  (const float*)d_in[17], (const float*)d_in[25]};
    const float* VA[3]  = {(const float*)d_in[10], (const float*)d_in[18], (const float*)d_in[26]};
    const float* fc1w = (const float*)d_in[27];
    const float* fc1b = (const float*)d_in[28];
    const float* fc2w = (const float*)d_in[29];
    const float* fc2b = (const float*)d_in[30];
    const float* fc3w = (const float*)d_in[31];
    const float* fc3b = (const float*)d_in[32];

    // top of use = 84,085,760 B (< 108,953,600 B proven safe)
    char* ws = (char*)d_ws;
    int*   rowp   = (int*)  (ws);                      // 200,004 B
    int*   colv   = (int*)  (ws + 200704);             // 3,400,000 B
    int*   bsum   = (int*)  (ws + 3600704);            // 1,024 B
    float* als    = (float*)(ws + 3602432);            // 800,000 B
    int*   cur    = (int*)  (ws + 3602432);            // 200,000 B (aliases als; dead before GEMM)
    float* ald    = (float*)(ws + 4402432);            // 800,000 B
    __half* wTh   = (__half*)(ws + 5202432);           // 229,376 B (3 layers packed)
    __half* wTl   = (__half*)(ws + 5431808);           // 229,376 B
    __half* h_buf = (__half*)(ws + 5661184);           // 25,600,000 B
    __half* xf16  = (__half*)(ws + 31261184);          // 25,624,576 B (50048 rows x 256)
    float* xpool  = (float*)(ws + 56885760);           // 12,800,000 B
    float* alpha  = (float*)(ws + 69685760);           // 13,600,000 B (850k x 4 fp32)
    float* invb   = (float*)(ws + 83285760);           // 800,000 B -> 84,085,760 B

    const int* esrc = ei;
    const int* edst = ei + NE;
    const int NB_SCAN = (NN + 255) / 256; // 196

    // CSR build
    hipMemsetAsync(cur, 0, NN * sizeof(int), stream);
    k_deg<<<(NE + 255) / 256, 256, 0, stream>>>(edst, cur, NE);
    k_scan1<<<NB_SCAN, 256, 0, stream>>>(cur, rowp, bsum, NN);
    k_scan2<<<1, 256, 0, stream>>>(bsum, NB_SCAN);
    k_scan3<<<NB_SCAN, 256, 0, stream>>>(rowp, bsum, cur, NN, NE + NN);
    k_fill<<<(NE + NN + 255) / 256, 256, 0, stream>>>(esrc, edst, rowp, cur, colv, NE, NN);

    // fused prep: x cast + weight transpose/split
    k_prep<<<(1600000 + 114688 + 255) / 256, 256, 0, stream>>>(x0, xf16, W[0], W[1], W[2],
                                                               wTh, wTl);

    const int GB = (NN + 127) / 128; // 391
    int nwb = (NN + 3) / 4;          // 12500
    int nab = (NN + 15) / 16;        // 3125

    // ---- layer 0 (K=128, HC=256, H=4)
    k_mgemm<128, 128><<<dim3(GB, 2), 256, 0, stream>>>(xf16, wTh, wTl, h_buf,
                                                       AS[0], AD[0], als, ald, 4, NN, 256);
    k_att<4><<<nab, 256, 0, stream>>>(als, ald, rowp, colv, alpha, invb, NN);
    k_agg<4, true><<<nwb, 256, 0, stream>>>(h_buf, alpha, invb, rowp, colv,
                                            BI[0], GA[0], BE[0], MU[0], VA[0],
                                            xf16, nullptr, NN);
    // ---- layer 1 (K=256, HC=256, H=4)
    k_mgemm<256, 128><<<dim3(GB, 2), 256, 0, stream>>>(xf16, wTh + 32768, wTl + 32768, h_buf,
                                                       AS[1], AD[1], als, ald, 4, NN, 256);
    k_att<4><<<nab, 256, 0, stream>>>(als, ald, rowp, colv, alpha, invb, NN);
    k_agg<4, true><<<nwb, 256, 0, stream>>>(h_buf, alpha, invb, rowp, colv,
                                            BI[1], GA[1], BE[1], MU[1], VA[1],
                                            xf16, nullptr, NN);
    // ---- layer 2 (K=256, HC=64, H=1)
    k_mgemm<256, 64><<<dim3(GB, 1), 256, 0, stream>>>(xf16, wTh + 98304, wTl + 98304, h_buf,
                                                      AS[2], AD[2], als, ald, 1, NN, 64);
    k_att<1><<<nab, 256, 0, stream>>>(als, ald, rowp, colv, alpha, invb, NN);
    k_agg<1, false><<<nwb, 256, 0, stream>>>(h_buf, alpha, invb, rowp, colv,
                                             BI[2], GA[2], BE[2], MU[2], VA[2],
                                             nullptr, xpool, NN);

    // fused readout + MLP
    k_poolfc<<<NGR, 64, 0, stream>>>(xpool, batch, fc1w, fc1b, fc2w, fc2b, fc3w, fc3b,
                                     (float*)d_out, NN);
    (void)in_sizes; (void)n_in; (void)out_size; (void)ws_size;
}

// Round 13
// 488.867 us; speedup vs baseline: 3.0682x; 1.0927x over previous
//
#include <hip/hip_runtime.h>
#include <hip/hip_fp16.h>

typedef unsigned short ushort_t;
typedef unsigned int uint_t;
typedef __attribute__((ext_vector_type(8))) _Float16 half8;
typedef __attribute__((ext_vector_type(4))) float f32x4;

#define NN 50000
#define NE 800000
#define NGR 256

// async global->LDS, 16B per lane; LDS dest = wave-uniform base + lane*16
typedef __attribute__((address_space(3))) unsigned int as3_u32;
typedef const __attribute__((address_space(1))) unsigned int as1_u32c;
__device__ __forceinline__ void gld16(const ushort_t* g, void* lds_base) {
    __builtin_amdgcn_global_load_lds((as1_u32c*)g, (as3_u32*)lds_base, 16, 0, 0);
}

// ---------------- CSR build ----------------
__global__ void k_deg(const int* __restrict__ dst, int* __restrict__ deg, int E) {
    int i = blockIdx.x * 256 + threadIdx.x;
    if (i < E) atomicAdd(&deg[dst[i]], 1);
}

__global__ void k_scan1(const int* __restrict__ deg, int* __restrict__ rowp,
                        int* __restrict__ bsum, int M) {
    __shared__ int sm[256];
    int t = threadIdx.x, i = blockIdx.x * 256 + t;
    int v = (i < M) ? deg[i] + 1 : 0;   // +1 self loop
    sm[t] = v; __syncthreads();
    for (int off = 1; off < 256; off <<= 1) {
        int x = (t >= off) ? sm[t - off] : 0;
        __syncthreads();
        sm[t] += x;
        __syncthreads();
    }
    if (i < M) rowp[i] = sm[t] - v;     // exclusive
    if (t == 255) bsum[blockIdx.x] = sm[255];
}

__global__ void k_scan2(int* bsum, int NB) {
    __shared__ int sm[256];
    int t = threadIdx.x;
    int v = (t < NB) ? bsum[t] : 0;
    sm[t] = v; __syncthreads();
    for (int off = 1; off < 256; off <<= 1) {
        int x = (t >= off) ? sm[t - off] : 0;
        __syncthreads();
        sm[t] += x;
        __syncthreads();
    }
    if (t < NB) bsum[t] = sm[t] - v;    // exclusive block offsets
}

// also zeroes cur (aliases als) for k_fill
__global__ void k_scan3(int* rowp, const int* __restrict__ bsum, int* __restrict__ cur,
                        int M, int total) {
    int i = blockIdx.x * 256 + threadIdx.x;
    if (i < M) { rowp[i] += bsum[blockIdx.x]; cur[i] = 0; }
    if (i == 0) rowp[M] = total;
}

__global__ void k_fill(const int* __restrict__ src, const int* __restrict__ dst,
                       const int* __restrict__ rowp, int* __restrict__ cur,
                       int* __restrict__ colv, int E, int M) {
    int i = blockIdx.x * 256 + threadIdx.x;
    if (i < E) {
        int d = dst[i];
        int pos = rowp[d] + atomicAdd(&cur[d], 1);
        colv[pos] = src[i];
    } else if (i < E + M) {
        int nn = i - E;
        int pos = rowp[nn] + atomicAdd(&cur[nn], 1);
        colv[pos] = nn;
    }
}

// ---- fused prep: x0 fp32 -> fp16 (cast) AND all weights -> transposed fp16 hi/lo ----
__global__ void k_prep(const float* __restrict__ x0, __half* __restrict__ xf,
                       const float* __restrict__ W0, const float* __restrict__ W1,
                       const float* __restrict__ W2, __half* __restrict__ th,
                       __half* __restrict__ tl) {
    int i = blockIdx.x * 256 + threadIdx.x;
    if (i < 1600000) {
        float4 v = ((const float4*)x0)[i];
        __half2 a = __floats2half2_rn(v.x, v.y);
        __half2 b = __floats2half2_rn(v.z, v.w);
        *(__half2*)(xf + i * 4) = a;
        *(__half2*)(xf + i * 4 + 2) = b;
    } else if (i < 1600000 + 114688) {
        int w = i - 1600000;
        const float* W; int K, NC, idx, base;
        if (w < 32768)      { W = W0; K = 128; NC = 256; idx = w;         base = 0; }
        else if (w < 98304) { W = W1; K = 256; NC = 256; idx = w - 32768; base = 32768; }
        else                { W = W2; K = 256; NC = 64;  idx = w - 98304; base = 98304; }
        int k = idx / NC, n = idx % NC;
        float f = W[idx];
        __half hi = __float2half(f);
        th[base + n * K + k] = hi;
        tl[base + n * K + k] = __float2half(f - __half2float(hi));
    }
}

// ------- MFMA GEMM (fp16, 2-term W ladder) + fused attention-logit epilogue -------
template<int KD, int BN>
__global__ __launch_bounds__(256)
void k_mgemm(const __half* __restrict__ Ax, const __half* __restrict__ Bth,
             const __half* __restrict__ Btl, __half* __restrict__ Hout,
             const float* __restrict__ a_s, const float* __restrict__ a_d,
             float* __restrict__ als, float* __restrict__ ald,
             int H, int M, int NC) {
    constexpr int BM = 128, BK = 32;
    __shared__ ushort_t sA[BM * BK];
    __shared__ ushort_t sBh[BN * BK];
    __shared__ ushort_t sBl[BN * BK];
    const int tid = threadIdx.x;
    const int m0 = blockIdx.x * BM;
    const int n0 = blockIdx.y * BN;
    const int wv = tid >> 6, ln = tid & 63;
    const int lrow = ln & 15, lq = ln >> 4;
    constexpr int RT = (BN == 128) ? 4 : 2;
    int wm, wn;
    if constexpr (BN == 128) { wm = (wv >> 1) * 64; wn = (wv & 1) * 64; }
    else                     { wm = wv * 32;        wn = 0; }
    const int roff = ln >> 2;
    const int coff = (ln & 3) * 8;

    f32x4 acc[RT][4] = {};

    for (int k0 = 0; k0 < KD; k0 += BK) {
        #pragma unroll
        for (int ch = 0; ch < 2; ++ch) {
            int rb = wv * 32 + ch * 16;
            size_t ga = (size_t)(m0 + rb + roff) * KD + k0 + coff;
            gld16((const ushort_t*)Ax + ga, &sA[rb * BK]);
        }
        if constexpr (BN == 128) {
            #pragma unroll
            for (int ch = 0; ch < 2; ++ch) {
                int rb = wv * 32 + ch * 16;
                size_t gb = (size_t)(n0 + rb + roff) * KD + k0 + coff;
                gld16((const ushort_t*)Bth + gb, &sBh[rb * BK]);
                gld16((const ushort_t*)Btl + gb, &sBl[rb * BK]);
            }
        } else {
            int rb = wv * 16;
            size_t gb = (size_t)(n0 + rb + roff) * KD + k0 + coff;
            gld16((const ushort_t*)Bth + gb, &sBh[rb * BK]);
            gld16((const ushort_t*)Btl + gb, &sBl[rb * BK]);
        }
        __syncthreads();
        half8 af[RT], bfh[4], bfl[4];
        #pragma unroll
        for (int r = 0; r < RT; ++r)
            af[r] = *(const half8*)&sA[(wm + r * 16 + lrow) * BK + lq * 8];
        #pragma unroll
        for (int c = 0; c < 4; ++c) {
            bfh[c] = *(const half8*)&sBh[(wn + c * 16 + lrow) * BK + lq * 8];
            bfl[c] = *(const half8*)&sBl[(wn + c * 16 + lrow) * BK + lq * 8];
        }
        #pragma unroll
        for (int r = 0; r < RT; ++r)
            #pragma unroll
            for (int c = 0; c < 4; ++c) {
                acc[r][c] = __builtin_amdgcn_mfma_f32_16x16x32_f16(af[r], bfh[c], acc[r][c], 0, 0, 0);
                acc[r][c] = __builtin_amdgcn_mfma_f32_16x16x32_f16(af[r], bfl[c], acc[r][c], 0, 0, 0);
            }
        __syncthreads();
    }
    // H-store (C/D layout: col=lane&15, row=(lane>>4)*4+reg)
    #pragma unroll
    for (int r = 0; r < RT; ++r) {
        #pragma unroll
        for (int c = 0; c < 4; ++c) {
            int colg = n0 + wn + c * 16 + lrow;
            #pragma unroll
            for (int j = 0; j < 4; ++j) {
                int row = m0 + wm + r * 16 + lq * 4 + j;
                if (row < M) Hout[(size_t)row * NC + colg] = __float2half(acc[r][c][j]);
            }
        }
    }
    // fused attention logits: this wave's 64 cols lie in exactly one head
    int hh = (n0 + wn) >> 6;
    float asv[4], adv[4];
    #pragma unroll
    for (int c = 0; c < 4; ++c) {
        int cg = (n0 + wn + c * 16 + lrow) & 63;
        asv[c] = a_s[hh * 64 + cg];
        adv[c] = a_d[hh * 64 + cg];
    }
    #pragma unroll
    for (int r = 0; r < RT; ++r) {
        #pragma unroll
        for (int j = 0; j < 4; ++j) {
            float ts = 0.f, td = 0.f;
            #pragma unroll
            for (int c = 0; c < 4; ++c) {
                float v = acc[r][c][j];
                ts += v * asv[c];
                td += v * adv[c];
            }
            #pragma unroll
            for (int m = 1; m < 16; m <<= 1) {
                ts += __shfl_xor(ts, m);
                td += __shfl_xor(td, m);
            }
            int row = m0 + wm + r * 16 + lq * 4 + j;
            if (lrow == 0 && row < M) {
                als[row * H + hh] = ts;
                ald[row * H + hh] = td;
            }
        }
    }
}

// ---- per-edge raw exp + per-node 1/den: 16 lanes per node, edge-parallel ----
template<int H>
__global__ __launch_bounds__(256)
void k_att(const float* __restrict__ als, const float* __restrict__ ald,
           const int* __restrict__ rowp, const int* __restrict__ colv,
           float* __restrict__ alpha, float* __restrict__ invb, int M) {
    int node = blockIdx.x * 16 + (threadIdx.x >> 4);
    if (node >= M) return;
    int l = threadIdx.x & 15;
    int rs = rowp[node], re = rowp[node + 1];
    if constexpr (H == 4) {
        float4 ad = *(const float4*)(ald + node * 4);
        float d0 = 0.f, d1 = 0.f, d2 = 0.f, d3 = 0.f;
        for (int i = rs + l; i < re; i += 16) {
            int s = colv[i];
            float4 av = *(const float4*)(als + s * 4);
            float e0 = av.x + ad.x; e0 = e0 > 0.f ? e0 : 0.2f * e0; e0 = __expf(e0);
            float e1 = av.y + ad.y; e1 = e1 > 0.f ? e1 : 0.2f * e1; e1 = __expf(e1);
            float e2 = av.z + ad.z; e2 = e2 > 0.f ? e2 : 0.2f * e2; e2 = __expf(e2);
            float e3 = av.w + ad.w; e3 = e3 > 0.f ? e3 : 0.2f * e3; e3 = __expf(e3);
            d0 += e0; d1 += e1; d2 += e2; d3 += e3;
            *(float4*)(alpha + (size_t)i * 4) = make_float4(e0, e1, e2, e3);
        }
        #pragma unroll
        for (int off = 1; off < 16; off <<= 1) {
            d0 += __shfl_xor(d0, off); d1 += __shfl_xor(d1, off);
            d2 += __shfl_xor(d2, off); d3 += __shfl_xor(d3, off);
        }
        if (l == 0)
            *(float4*)(invb + node * 4) = make_float4(1.f / (d0 + 1e-16f), 1.f / (d1 + 1e-16f),
                                                      1.f / (d2 + 1e-16f), 1.f / (d3 + 1e-16f));
    } else {
        float ad = ald[node];
        float d = 0.f;
        for (int i = rs + l; i < re; i += 16) {
            int s = colv[i];
            float e = als[s] + ad; e = e > 0.f ? e : 0.2f * e; e = __expf(e);
            d += e;
            alpha[i] = e;
        }
        #pragma unroll
        for (int off = 1; off < 16; off <<= 1) d += __shfl_xor(d, off);
        if (l == 0) invb[node] = 1.f / (d + 1e-16f);
    }
}

// ---- aggregation + bias + BN + ELU: gather loop reads precomputed raw-exp alpha ----
// H=4: 2 edges x 32 lanes (x4 unroll);  H=1: 8 edges x 8 lanes (x2 unroll).
template<int H, bool SPLIT>
__global__ __launch_bounds__(256)
void k_agg(const __half* __restrict__ h, const float* __restrict__ alpha,
           const float* __restrict__ invb, const int* __restrict__ rowp,
           const int* __restrict__ colv,
           const float* __restrict__ bias, const float* __restrict__ gam,
           const float* __restrict__ bet, const float* __restrict__ mu,
           const float* __restrict__ var,
           __half* __restrict__ xo, float* __restrict__ xf, int M) {
    constexpr int HC = H * 64;
    constexpr int EG = 512 / HC;        // edge groups: 2 (H=4), 8 (H=1)
    constexpr int L  = 64 / EG;         // lanes per edge: 32, 8
    constexpr int UN = (H == 4) ? 4 : 2;
    int node = blockIdx.x * 4 + (threadIdx.x >> 6);
    if (node >= M) return;
    int lane = threadIdx.x & 63;
    int rs = rowp[node], re = rowp[node + 1];
    int l = lane & (L - 1), eg = lane / L;
    int hB = (l * 8) >> 6;
    float acc[8] = {};
    for (int i = rs; i < re; i += EG * UN) {
        #pragma unroll
        for (int k = 0; k < UN; ++k) {
            int idx = i + eg + k * EG;
            bool vld = idx < re;
            int idx2 = vld ? idx : rs;
            int s = colv[idx2];
            float a;
            if constexpr (H == 4) a = alpha[(size_t)idx2 * 4 + hB];
            else                  a = alpha[idx2];
            a = vld ? a : 0.f;
            uint4 hv = *(const uint4*)(h + (size_t)s * HC + l * 8);
            float2 f0 = __half22float2(*(__half2*)&hv.x);
            float2 f1 = __half22float2(*(__half2*)&hv.y);
            float2 f2 = __half22float2(*(__half2*)&hv.z);
            float2 f3 = __half22float2(*(__half2*)&hv.w);
            acc[0] += a * f0.x; acc[1] += a * f0.y;
            acc[2] += a * f1.x; acc[3] += a * f1.y;
            acc[4] += a * f2.x; acc[5] += a * f2.y;
            acc[6] += a * f3.x; acc[7] += a * f3.y;
        }
    }
    #pragma unroll
    for (int off = L; off < 64; off <<= 1) {
        #pragma unroll
        for (int j = 0; j < 8; ++j) acc[j] += __shfl_xor(acc[j], off);
    }
    if (eg == 0) {
        float inv = (H == 4) ? invb[node * 4 + hB] : invb[node];
        float fo[8];
        #pragma unroll
        for (int j = 0; j < 8; ++j) {
            int d = l * 8 + j;
            float o = acc[j] * inv + bias[d];
            float bn = (o - mu[d]) * rsqrtf(var[d] + 1e-5f) * gam[d] + bet[d];
            fo[j] = bn > 0.f ? bn : (__expf(bn) - 1.f);
        }
        if constexpr (SPLIT) {
            __half2 p0 = __floats2half2_rn(fo[0], fo[1]);
            __half2 p1 = __floats2half2_rn(fo[2], fo[3]);
            __half2 p2 = __floats2half2_rn(fo[4], fo[5]);
            __half2 p3 = __floats2half2_rn(fo[6], fo[7]);
            uint4 pk;
            pk.x = *(uint_t*)&p0; pk.y = *(uint_t*)&p1;
            pk.z = *(uint_t*)&p2; pk.w = *(uint_t*)&p3;
            *(uint4*)&xo[(size_t)node * HC + l * 8] = pk;
        } else {
            *(float4*)&xf[(size_t)node * HC + l * 8] = make_float4(fo[0], fo[1], fo[2], fo[3]);
            *(float4*)&xf[(size_t)node * HC + l * 8 + 4] = make_float4(fo[4], fo[5], fo[6], fo[7]);
        }
    }
}

// ---- fused pooling + MLP: 512 threads = 8 node-subsets x 64 dims, LDS reduce ----
__global__ __launch_bounds__(512)
void k_poolfc(const float* __restrict__ x, const int* __restrict__ batch,
              const float* __restrict__ fc1w, const float* __restrict__ fc1b,
              const float* __restrict__ fc2w, const float* __restrict__ fc2b,
              const float* __restrict__ fc3w, const float* __restrict__ fc3b,
              float* __restrict__ out, int M) {
    __shared__ float ssum[8][64];
    __shared__ float smax[8][64];
    __shared__ float hb[192];
    __shared__ float h1[64];
    __shared__ float h2[32];
    int g = blockIdx.x, t = threadIdx.x;
    int d = t & 63, sub = t >> 6;    // 8 subsets
    int lo = 0, hi = M;
    while (lo < hi) { int mid = (lo + hi) >> 1; if (batch[mid] < g) lo = mid + 1; else hi = mid; }
    int s = lo;
    lo = 0; hi = M;
    while (lo < hi) { int mid = (lo + hi) >> 1; if (batch[mid] < g + 1) lo = mid + 1; else hi = mid; }
    int e = lo;
    float sum = 0.f, mx = -3.0e38f;
    for (int n = s + sub; n < e; n += 8) {
        float v = x[(size_t)n * 64 + d];
        sum += v; mx = fmaxf(mx, v);
    }
    ssum[sub][d] = sum; smax[sub][d] = mx;
    __syncthreads();
    if (t < 64) {
        float sm = 0.f, m2 = -3.0e38f;
        #pragma unroll
        for (int k = 0; k < 8; ++k) { sm += ssum[k][t]; m2 = fmaxf(m2, smax[k][t]); }
        int cnt = e - s;
        hb[t] = sm / (float)(cnt > 1 ? cnt : 1);
        hb[64 + t] = (cnt == 0) ? 0.f : m2;
        hb[128 + t] = sm;
    }
    __syncthreads();
    if (t < 64) {
        float s1 = fc1b[t];
        for (int k = 0; k < 192; ++k) s1 += hb[k] * fc1w[k * 64 + t];
        h1[t] = fmaxf(s1, 0.f);
    }
    __syncthreads();
    if (t < 32) {
        float s2 = fc2b[t];
        for (int k = 0; k < 64; ++k) s2 += h1[k] * fc2w[k * 32 + t];
        h2[t] = fmaxf(s2, 0.f);
    }
    __syncthreads();
    if (t == 0) {
        float s3 = fc3b[0];
        for (int k = 0; k < 32; ++k) s3 += h2[k] * fc3w[k];
        out[g] = s3;
    }
}

extern "C" void kernel_launch(void* const* d_in, const int* in_sizes, int n_in,
                              void* d_out, int out_size, void* d_ws, size_t ws_size,
                              hipStream_t stream) {
    const float* x0     = (const float*)d_in[0];
    const int* ei       = (const int*)d_in[1];
    const int* batch    = (const int*)d_in[2];
    const float* W[3]   = {(const float*)d_in[3],  (const float*)d_in[11], (const float*)d_in[19]};
    const float* AS[3]  = {(const float*)d_in[4],  (const float*)d_in[12], (const float*)d_in[20]};
    const float* AD[3]  = {(const float*)d_in[5],  (const float*)d_in[13], (const float*)d_in[21]};
    const float* BI[3]  = {(const float*)d_in[6],  (const float*)d_in[14], (const float*)d_in[22]};
    const float* GA[3]  = {(const float*)d_in[7],  (const float*)d_in[15], (const float*)d_in[23]};
    const float* BE[3]  = {(const float*)d_in[8],  (const float*)d_in[16], (const float*)d_in[24]};
    const float* MU[3]  = {(const float*)d_in[9],  (const float*)d_in[17], (const float*)d_in[25]};
    const float* VA[3]  = {(const float*)d_in[10], (const float*)d_in[18], (const float*)d_in[26]};
    const float* fc1w = (const float*)d_in[27];
    const float* fc1b = (const float*)d_in[28];
    const float* fc2w = (const float*)d_in[29];
    const float* fc2b = (const float*)d_in[30];
    const float* fc3w = (const float*)d_in[31];
    const float* fc3b = (const float*)d_in[32];

    // top of use = 84,085,760 B (< 108,953,600 B proven safe)
    char* ws = (char*)d_ws;
    int*   rowp   = (int*)  (ws);                      // 200,004 B
    int*   colv   = (int*)  (ws + 200704);             // 3,400,000 B
    int*   bsum   = (int*)  (ws + 3600704);            // 1,024 B
    float* als    = (float*)(ws + 3602432);            // 800,000 B
    int*   cur    = (int*)  (ws + 3602432);            // 200,000 B (aliases als; dead before GEMM)
    float* ald    = (float*)(ws + 4402432);            // 800,000 B
    __half* wTh   = (__half*)(ws + 5202432);           // 229,376 B (3 layers packed)
    __half* wTl   = (__half*)(ws + 5431808);           // 229,376 B
    __half* h_buf = (__half*)(ws + 5661184);           // 25,600,000 B
    __half* xf16  = (__half*)(ws + 31261184);          // 25,624,576 B (50048 rows x 256)
    float* xpool  = (float*)(ws + 56885760);           // 12,800,000 B
    float* alpha  = (float*)(ws + 69685760);           // 13,600,000 B (850k x 4 fp32)
    float* invb   = (float*)(ws + 83285760);           // 800,000 B -> 84,085,760 B

    const int* esrc = ei;
    const int* edst = ei + NE;
    const int NB_SCAN = (NN + 255) / 256; // 196

    // CSR build
    hipMemsetAsync(cur, 0, NN * sizeof(int), stream);
    k_deg<<<(NE + 255) / 256, 256, 0, stream>>>(edst, cur, NE);
    k_scan1<<<NB_SCAN, 256, 0, stream>>>(cur, rowp, bsum, NN);
    k_scan2<<<1, 256, 0, stream>>>(bsum, NB_SCAN);
    k_scan3<<<NB_SCAN, 256, 0, stream>>>(rowp, bsum, cur, NN, NE + NN);
    k_fill<<<(NE + NN + 255) / 256, 256, 0, stream>>>(esrc, edst, rowp, cur, colv, NE, NN);

    // fused prep: x cast + weight transpose/split
    k_prep<<<(1600000 + 114688 + 255) / 256, 256, 0, stream>>>(x0, xf16, W[0], W[1], W[2],
                                                               wTh, wTl);

    const int GB = (NN + 127) / 128; // 391
    int nwb = (NN + 3) / 4;          // 12500
    int nab = (NN + 15) / 16;        // 3125

    // ---- layer 0 (K=128, HC=256, H=4)
    k_mgemm<128, 128><<<dim3(GB, 2), 256, 0, stream>>>(xf16, wTh, wTl, h_buf,
                                                       AS[0], AD[0], als, ald, 4, NN, 256);
    k_att<4><<<nab, 256, 0, stream>>>(als, ald, rowp, colv, alpha, invb, NN);
    k_agg<4, true><<<nwb, 256, 0, stream>>>(h_buf, alpha, invb, rowp, colv,
                                            BI[0], GA[0], BE[0], MU[0], VA[0],
                                            xf16, nullptr, NN);
    // ---- layer 1 (K=256, HC=256, H=4)
    k_mgemm<256, 128><<<dim3(GB, 2), 256, 0, stream>>>(xf16, wTh + 32768, wTl + 32768, h_buf,
                                                       AS[1], AD[1], als, ald, 4, NN, 256);
    k_att<4><<<nab, 256, 0, stream>>>(als, ald, rowp, colv, alpha, invb, NN);
    k_agg<4, true><<<nwb, 256, 0, stream>>>(h_buf, alpha, invb, rowp, colv,
                                            BI[1], GA[1], BE[1], MU[1], VA[1],
                                            xf16, nullptr, NN);
    // ---- layer 2 (K=256, HC=64, H=1)
    k_mgemm<256, 64><<<dim3(GB, 1), 256, 0, stream>>>(xf16, wTh + 98304, wTl + 98304, h_buf,
                                                      AS[2], AD[2], als, ald, 1, NN, 64);
    k_att<1><<<nab, 256, 0, stream>>>(als, ald, rowp, colv, alpha, invb, NN);
    k_agg<1, false><<<nwb, 256, 0, stream>>>(h_buf, alpha, invb, rowp, colv,
                                             BI[2], GA[2], BE[2], MU[2], VA[2],
                                             nullptr, xpool, NN);

    // fused readout + MLP (512 threads: 8 node-subsets x 64 dims)
    k_poolfc<<<NGR, 512, 0, stream>>>(xpool, batch, fc1w, fc1b, fc2w, fc2b, fc3w, fc3b,
                                      (float*)d_out, NN);
    (void)in_sizes; (void)n_in; (void)out_size; (void)ws_size;
}

// Round 14
// 477.490 us; speedup vs baseline: 3.1413x; 1.0238x over previous
//
#include <hip/hip_runtime.h>
#include <hip/hip_fp16.h>

typedef unsigned short ushort_t;
typedef unsigned int uint_t;
typedef __attribute__((ext_vector_type(8))) _Float16 half8;
typedef __attribute__((ext_vector_type(4))) float f32x4;

#define NN 50000
#define NE 800000
#define NGR 256

// async global->LDS, 16B per lane; LDS dest = wave-uniform base + lane*16
typedef __attribute__((address_space(3))) unsigned int as3_u32;
typedef const __attribute__((address_space(1))) unsigned int as1_u32c;
__device__ __forceinline__ void gld16(const ushort_t* g, void* lds_base) {
    __builtin_amdgcn_global_load_lds((as1_u32c*)g, (as3_u32*)lds_base, 16, 0, 0);
}

// ---------------- CSR build ----------------
__global__ void k_scan1(const int* __restrict__ deg, int* __restrict__ rowp,
                        int* __restrict__ bsum, int M) {
    __shared__ int sm[256];
    int t = threadIdx.x, i = blockIdx.x * 256 + t;
    int v = (i < M) ? deg[i] + 1 : 0;   // +1 self loop
    sm[t] = v; __syncthreads();
    for (int off = 1; off < 256; off <<= 1) {
        int x = (t >= off) ? sm[t - off] : 0;
        __syncthreads();
        sm[t] += x;
        __syncthreads();
    }
    if (i < M) rowp[i] = sm[t] - v;     // exclusive
    if (t == 255) bsum[blockIdx.x] = sm[255];
}

__global__ void k_scan2(int* bsum, int NB) {
    __shared__ int sm[256];
    int t = threadIdx.x;
    int v = (t < NB) ? bsum[t] : 0;
    sm[t] = v; __syncthreads();
    for (int off = 1; off < 256; off <<= 1) {
        int x = (t >= off) ? sm[t - off] : 0;
        __syncthreads();
        sm[t] += x;
        __syncthreads();
    }
    if (t < NB) bsum[t] = sm[t] - v;    // exclusive block offsets
}

// also zeroes cur (aliases als) for k_fill
__global__ void k_scan3(int* rowp, const int* __restrict__ bsum, int* __restrict__ cur,
                        int M, int total) {
    int i = blockIdx.x * 256 + threadIdx.x;
    if (i < M) { rowp[i] += bsum[blockIdx.x]; cur[i] = 0; }
    if (i == 0) rowp[M] = total;
}

__global__ void k_fill(const int* __restrict__ src, const int* __restrict__ dst,
                       const int* __restrict__ rowp, int* __restrict__ cur,
                       int* __restrict__ colv, int E, int M) {
    int i = blockIdx.x * 256 + threadIdx.x;
    if (i < E) {
        int d = dst[i];
        int pos = rowp[d] + atomicAdd(&cur[d], 1);
        colv[pos] = src[i];
    } else if (i < E + M) {
        int nn = i - E;
        int pos = rowp[nn] + atomicAdd(&cur[nn], 1);
        colv[pos] = nn;
    }
}

// ---- fused prep: x cast -> fp16, weights -> transposed fp16, edge-degree count ----
__global__ void k_prep(const float* __restrict__ x0, __half* __restrict__ xf,
                       const float* __restrict__ W0, const float* __restrict__ W1,
                       const float* __restrict__ W2, __half* __restrict__ th,
                       const int* __restrict__ edst, int* __restrict__ deg) {
    int i = blockIdx.x * 256 + threadIdx.x;
    if (i < 1600000) {
        float4 v = ((const float4*)x0)[i];
        __half2 a = __floats2half2_rn(v.x, v.y);
        __half2 b = __floats2half2_rn(v.z, v.w);
        *(__half2*)(xf + i * 4) = a;
        *(__half2*)(xf + i * 4 + 2) = b;
    } else if (i < 1600000 + 114688) {
        int w = i - 1600000;
        const float* W; int K, NC, idx, base;
        if (w < 32768)      { W = W0; K = 128; NC = 256; idx = w;         base = 0; }
        else if (w < 98304) { W = W1; K = 256; NC = 256; idx = w - 32768; base = 32768; }
        else                { W = W2; K = 256; NC = 64;  idx = w - 98304; base = 98304; }
        int k = idx / NC, n = idx % NC;
        th[base + n * K + k] = __float2half(W[idx]);
    } else if (i < 1600000 + 114688 + NE) {
        atomicAdd(&deg[edst[i - 1714688]], 1);
    }
}

// ------- MFMA GEMM (fp16 single-term) + fused attention-logit epilogue -------
template<int KD, int BN>
__global__ __launch_bounds__(256)
void k_mgemm(const __half* __restrict__ Ax, const __half* __restrict__ Bth,
             __half* __restrict__ Hout,
             const float* __restrict__ a_s, const float* __restrict__ a_d,
             float* __restrict__ als, float* __restrict__ ald,
             int H, int M, int NC) {
    constexpr int BM = 128, BK = 32;
    __shared__ ushort_t sA[BM * BK];
    __shared__ ushort_t sB[BN * BK];
    const int tid = threadIdx.x;
    const int m0 = blockIdx.x * BM;
    const int n0 = blockIdx.y * BN;
    const int wv = tid >> 6, ln = tid & 63;
    const int lrow = ln & 15, lq = ln >> 4;
    constexpr int RT = (BN == 128) ? 4 : 2;
    int wm, wn;
    if constexpr (BN == 128) { wm = (wv >> 1) * 64; wn = (wv & 1) * 64; }
    else                     { wm = wv * 32;        wn = 0; }
    const int roff = ln >> 2;
    const int coff = (ln & 3) * 8;

    f32x4 acc[RT][4] = {};

    for (int k0 = 0; k0 < KD; k0 += BK) {
        #pragma unroll
        for (int ch = 0; ch < 2; ++ch) {
            int rb = wv * 32 + ch * 16;
            size_t ga = (size_t)(m0 + rb + roff) * KD + k0 + coff;
            gld16((const ushort_t*)Ax + ga, &sA[rb * BK]);
        }
        if constexpr (BN == 128) {
            #pragma unroll
            for (int ch = 0; ch < 2; ++ch) {
                int rb = wv * 32 + ch * 16;
                size_t gb = (size_t)(n0 + rb + roff) * KD + k0 + coff;
                gld16((const ushort_t*)Bth + gb, &sB[rb * BK]);
            }
        } else {
            int rb = wv * 16;
            size_t gb = (size_t)(n0 + rb + roff) * KD + k0 + coff;
            gld16((const ushort_t*)Bth + gb, &sB[rb * BK]);
        }
        __syncthreads();
        half8 af[RT], bf[4];
        #pragma unroll
        for (int r = 0; r < RT; ++r)
            af[r] = *(const half8*)&sA[(wm + r * 16 + lrow) * BK + lq * 8];
        #pragma unroll
        for (int c = 0; c < 4; ++c)
            bf[c] = *(const half8*)&sB[(wn + c * 16 + lrow) * BK + lq * 8];
        #pragma unroll
        for (int r = 0; r < RT; ++r)
            #pragma unroll
            for (int c = 0; c < 4; ++c)
                acc[r][c] = __builtin_amdgcn_mfma_f32_16x16x32_f16(af[r], bf[c], acc[r][c], 0, 0, 0);
        __syncthreads();
    }
    // H-store (C/D layout: col=lane&15, row=(lane>>4)*4+reg)
    #pragma unroll
    for (int r = 0; r < RT; ++r) {
        #pragma unroll
        for (int c = 0; c < 4; ++c) {
            int colg = n0 + wn + c * 16 + lrow;
            #pragma unroll
            for (int j = 0; j < 4; ++j) {
                int row = m0 + wm + r * 16 + lq * 4 + j;
                if (row < M) Hout[(size_t)row * NC + colg] = __float2half(acc[r][c][j]);
            }
        }
    }
    // fused attention logits: this wave's 64 cols lie in exactly one head
    int hh = (n0 + wn) >> 6;
    float asv[4], adv[4];
    #pragma unroll
    for (int c = 0; c < 4; ++c) {
        int cg = (n0 + wn + c * 16 + lrow) & 63;
        asv[c] = a_s[hh * 64 + cg];
        adv[c] = a_d[hh * 64 + cg];
    }
    #pragma unroll
    for (int r = 0; r < RT; ++r) {
        #pragma unroll
        for (int j = 0; j < 4; ++j) {
            float ts = 0.f, td = 0.f;
            #pragma unroll
            for (int c = 0; c < 4; ++c) {
                float v = acc[r][c][j];
                ts += v * asv[c];
                td += v * adv[c];
            }
            #pragma unroll
            for (int m = 1; m < 16; m <<= 1) {
                ts += __shfl_xor(ts, m);
                td += __shfl_xor(td, m);
            }
            int row = m0 + wm + r * 16 + lq * 4 + j;
            if (lrow == 0 && row < M) {
                als[row * H + hh] = ts;
                ald[row * H + hh] = td;
            }
        }
    }
}

// ---- per-edge raw exp + per-node 1/den: 16 lanes per node, edge-parallel ----
template<int H>
__global__ __launch_bounds__(256)
void k_att(const float* __restrict__ als, const float* __restrict__ ald,
           const int* __restrict__ rowp, const int* __restrict__ colv,
           float* __restrict__ alpha, float* __restrict__ invb, int M) {
    int node = blockIdx.x * 16 + (threadIdx.x >> 4);
    if (node >= M) return;
    int l = threadIdx.x & 15;
    int rs = rowp[node], re = rowp[node + 1];
    if constexpr (H == 4) {
        float4 ad = *(const float4*)(ald + node * 4);
        float d0 = 0.f, d1 = 0.f, d2 = 0.f, d3 = 0.f;
        for (int i = rs + l; i < re; i += 16) {
            int s = colv[i];
            float4 av = *(const float4*)(als + s * 4);
            float e0 = av.x + ad.x; e0 = e0 > 0.f ? e0 : 0.2f * e0; e0 = __expf(e0);
            float e1 = av.y + ad.y; e1 = e1 > 0.f ? e1 : 0.2f * e1; e1 = __expf(e1);
            float e2 = av.z + ad.z; e2 = e2 > 0.f ? e2 : 0.2f * e2; e2 = __expf(e2);
            float e3 = av.w + ad.w; e3 = e3 > 0.f ? e3 : 0.2f * e3; e3 = __expf(e3);
            d0 += e0; d1 += e1; d2 += e2; d3 += e3;
            *(float4*)(alpha + (size_t)i * 4) = make_float4(e0, e1, e2, e3);
        }
        #pragma unroll
        for (int off = 1; off < 16; off <<= 1) {
            d0 += __shfl_xor(d0, off); d1 += __shfl_xor(d1, off);
            d2 += __shfl_xor(d2, off); d3 += __shfl_xor(d3, off);
        }
        if (l == 0)
            *(float4*)(invb + node * 4) = make_float4(1.f / (d0 + 1e-16f), 1.f / (d1 + 1e-16f),
                                                      1.f / (d2 + 1e-16f), 1.f / (d3 + 1e-16f));
    } else {
        float ad = ald[node];
        float d = 0.f;
        for (int i = rs + l; i < re; i += 16) {
            int s = colv[i];
            float e = als[s] + ad; e = e > 0.f ? e : 0.2f * e; e = __expf(e);
            d += e;
            alpha[i] = e;
        }
        #pragma unroll
        for (int off = 1; off < 16; off <<= 1) d += __shfl_xor(d, off);
        if (l == 0) invb[node] = 1.f / (d + 1e-16f);
    }
}

// ---- aggregation + bias + BN + ELU: gather loop reads precomputed raw-exp alpha ----
// H=4: 2 edges x 32 lanes (x4 unroll);  H=1: 8 edges x 8 lanes (x2 unroll).
template<int H, bool SPLIT>
__global__ __launch_bounds__(256)
void k_agg(const __half* __restrict__ h, const float* __restrict__ alpha,
           const float* __restrict__ invb, const int* __restrict__ rowp,
           const int* __restrict__ colv,
           const float* __restrict__ bias, const float* __restrict__ gam,
           const float* __restrict__ bet, const float* __restrict__ mu,
           const float* __restrict__ var,
           __half* __restrict__ xo, float* __restrict__ xf, int M) {
    constexpr int HC = H * 64;
    constexpr int EG = 512 / HC;        // edge groups: 2 (H=4), 8 (H=1)
    constexpr int L  = 64 / EG;         // lanes per edge: 32, 8
    constexpr int UN = (H == 4) ? 4 : 2;
    int node = blockIdx.x * 4 + (threadIdx.x >> 6);
    if (node >= M) return;
    int lane = threadIdx.x & 63;
    int rs = rowp[node], re = rowp[node + 1];
    int l = lane & (L - 1), eg = lane / L;
    int hB = (l * 8) >> 6;
    float acc[8] = {};
    for (int i = rs; i < re; i += EG * UN) {
        #pragma unroll
        for (int k = 0; k < UN; ++k) {
            int idx = i + eg + k * EG;
            bool vld = idx < re;
            int idx2 = vld ? idx : rs;
            int s = colv[idx2];
            float a;
            if constexpr (H == 4) a = alpha[(size_t)idx2 * 4 + hB];
            else                  a = alpha[idx2];
            a = vld ? a : 0.f;
            uint4 hv = *(const uint4*)(h + (size_t)s * HC + l * 8);
            float2 f0 = __half22float2(*(__half2*)&hv.x);
            float2 f1 = __half22float2(*(__half2*)&hv.y);
            float2 f2 = __half22float2(*(__half2*)&hv.z);
            float2 f3 = __half22float2(*(__half2*)&hv.w);
            acc[0] += a * f0.x; acc[1] += a * f0.y;
            acc[2] += a * f1.x; acc[3] += a * f1.y;
            acc[4] += a * f2.x; acc[5] += a * f2.y;
            acc[6] += a * f3.x; acc[7] += a * f3.y;
        }
    }
    #pragma unroll
    for (int off = L; off < 64; off <<= 1) {
        #pragma unroll
        for (int j = 0; j < 8; ++j) acc[j] += __shfl_xor(acc[j], off);
    }
    if (eg == 0) {
        float inv = (H == 4) ? invb[node * 4 + hB] : invb[node];
        float fo[8];
        #pragma unroll
        for (int j = 0; j < 8; ++j) {
            int d = l * 8 + j;
            float o = acc[j] * inv + bias[d];
            float bn = (o - mu[d]) * rsqrtf(var[d] + 1e-5f) * gam[d] + bet[d];
            fo[j] = bn > 0.f ? bn : (__expf(bn) - 1.f);
        }
        if constexpr (SPLIT) {
            __half2 p0 = __floats2half2_rn(fo[0], fo[1]);
            __half2 p1 = __floats2half2_rn(fo[2], fo[3]);
            __half2 p2 = __floats2half2_rn(fo[4], fo[5]);
            __half2 p3 = __floats2half2_rn(fo[6], fo[7]);
            uint4 pk;
            pk.x = *(uint_t*)&p0; pk.y = *(uint_t*)&p1;
            pk.z = *(uint_t*)&p2; pk.w = *(uint_t*)&p3;
            *(uint4*)&xo[(size_t)node * HC + l * 8] = pk;
        } else {
            *(float4*)&xf[(size_t)node * HC + l * 8] = make_float4(fo[0], fo[1], fo[2], fo[3]);
            *(float4*)&xf[(size_t)node * HC + l * 8 + 4] = make_float4(fo[4], fo[5], fo[6], fo[7]);
        }
    }
}

// ---- fused pooling + MLP: 512 threads = 8 node-subsets x 64 dims, LDS reduce ----
__global__ __launch_bounds__(512)
void k_poolfc(const float* __restrict__ x, const int* __restrict__ batch,
              const float* __restrict__ fc1w, const float* __restrict__ fc1b,
              const float* __restrict__ fc2w, const float* __restrict__ fc2b,
              const float* __restrict__ fc3w, const float* __restrict__ fc3b,
              float* __restrict__ out, int M) {
    __shared__ float ssum[8][64];
    __shared__ float smax[8][64];
    __shared__ float hb[192];
    __shared__ float h1[64];
    __shared__ float h2[32];
    int g = blockIdx.x, t = threadIdx.x;
    int d = t & 63, sub = t >> 6;    // 8 subsets
    int lo = 0, hi = M;
    while (lo < hi) { int mid = (lo + hi) >> 1; if (batch[mid] < g) lo = mid + 1; else hi = mid; }
    int s = lo;
    lo = 0; hi = M;
    while (lo < hi) { int mid = (lo + hi) >> 1; if (batch[mid] < g + 1) lo = mid + 1; else hi = mid; }
    int e = lo;
    float sum = 0.f, mx = -3.0e38f;
    for (int n = s + sub; n < e; n += 8) {
        float v = x[(size_t)n * 64 + d];
        sum += v; mx = fmaxf(mx, v);
    }
    ssum[sub][d] = sum; smax[sub][d] = mx;
    __syncthreads();
    if (t < 64) {
        float sm = 0.f, m2 = -3.0e38f;
        #pragma unroll
        for (int k = 0; k < 8; ++k) { sm += ssum[k][t]; m2 = fmaxf(m2, smax[k][t]); }
        int cnt = e - s;
        hb[t] = sm / (float)(cnt > 1 ? cnt : 1);
        hb[64 + t] = (cnt == 0) ? 0.f : m2;
        hb[128 + t] = sm;
    }
    __syncthreads();
    if (t < 64) {
        float s1 = fc1b[t];
        for (int k = 0; k < 192; ++k) s1 += hb[k] * fc1w[k * 64 + t];
        h1[t] = fmaxf(s1, 0.f);
    }
    __syncthreads();
    if (t < 32) {
        float s2 = fc2b[t];
        for (int k = 0; k < 64; ++k) s2 += h1[k] * fc2w[k * 32 + t];
        h2[t] = fmaxf(s2, 0.f);
    }
    __syncthreads();
    if (t == 0) {
        float s3 = fc3b[0];
        for (int k = 0; k < 32; ++k) s3 += h2[k] * fc3w[k];
        out[g] = s3;
    }
}

extern "C" void kernel_launch(void* const* d_in, const int* in_sizes, int n_in,
                              void* d_out, int out_size, void* d_ws, size_t ws_size,
                              hipStream_t stream) {
    const float* x0     = (const float*)d_in[0];
    const int* ei       = (const int*)d_in[1];
    const int* batch    = (const int*)d_in[2];
    const float* W[3]   = {(const float*)d_in[3],  (const float*)d_in[11], (const float*)d_in[19]};
    const float* AS[3]  = {(const float*)d_in[4],  (const float*)d_in[12], (const float*)d_in[20]};
    const float* AD[3]  = {(const float*)d_in[5],  (const float*)d_in[13], (const float*)d_in[21]};
    const float* BI[3]  = {(const float*)d_in[6],  (const float*)d_in[14], (const float*)d_in[22]};
    const float* GA[3]  = {(const float*)d_in[7],  (const float*)d_in[15], (const float*)d_in[23]};
    const float* BE[3]  = {(const float*)d_in[8],  (const float*)d_in[16], (const float*)d_in[24]};
    const float* MU[3]  = {(const float*)d_in[9],  (const float*)d_in[17], (const float*)d_in[25]};
    const float* VA[3]  = {(const float*)d_in[10], (const float*)d_in[18], (const float*)d_in[26]};
    const float* fc1w = (const float*)d_in[27];
    const float* fc1b = (const float*)d_in[28];
    const float* fc2w = (const float*)d_in[29];
    const float* fc2b = (const float*)d_in[30];
    const float* fc3w = (const float*)d_in[31];
    const float* fc3b = (const float*)d_in[32];

    // top of use = 84,085,760 B (< 108,953,600 B proven safe)
    char* ws = (char*)d_ws;
    int*   rowp   = (int*)  (ws);                      // 200,004 B
    int*   colv   = (int*)  (ws + 200704);             // 3,400,000 B
    int*   bsum   = (int*)  (ws + 3600704);            // 1,024 B
    float* als    = (float*)(ws + 3602432);            // 800,000 B
    int*   cur    = (int*)  (ws + 3602432);            // 200,000 B (aliases als; dead before GEMM)
    float* ald    = (float*)(ws + 4402432);            // 800,000 B
    __half* wTh   = (__half*)(ws + 5202432);           // 229,376 B (3 layers packed)
    __half* h_buf = (__half*)(ws + 5661184);           // 25,600,000 B
    __half* xf16  = (__half*)(ws + 31261184);          // 25,624,576 B (50048 rows x 256)
    float* xpool  = (float*)(ws + 56885760);           // 12,800,000 B
    float* alpha  = (float*)(ws + 69685760);           // 13,600,000 B (850k x 4 fp32)
    float* invb   = (float*)(ws + 83285760);           // 800,000 B -> 84,085,760 B

    const int* esrc = ei;
    const int* edst = ei + NE;
    const int NB_SCAN = (NN + 255) / 256; // 196

    // prep (x cast + W split + deg count; cur zeroed first)
    hipMemsetAsync(cur, 0, NN * sizeof(int), stream);
    k_prep<<<(1600000 + 114688 + NE + 255) / 256, 256, 0, stream>>>(x0, xf16, W[0], W[1], W[2],
                                                                    wTh, edst, cur);
    // CSR build
    k_scan1<<<NB_SCAN, 256, 0, stream>>>(cur, rowp, bsum, NN);
    k_scan2<<<1, 256, 0, stream>>>(bsum, NB_SCAN);
    k_scan3<<<NB_SCAN, 256, 0, stream>>>(rowp, bsum, cur, NN, NE + NN);
    k_fill<<<(NE + NN + 255) / 256, 256, 0, stream>>>(esrc, edst, rowp, cur, colv, NE, NN);

    const int GB = (NN + 127) / 128; // 391
    int nwb = (NN + 3) / 4;          // 12500
    int nab = (NN + 15) / 16;        // 3125

    // ---- layer 0 (K=128, HC=256, H=4)
    k_mgemm<128, 128><<<dim3(GB, 2), 256, 0, stream>>>(xf16, wTh, h_buf,
                                                       AS[0], AD[0], als, ald, 4, NN, 256);
    k_att<4><<<nab, 256, 0, stream>>>(als, ald, rowp, colv, alpha, invb, NN);
    k_agg<4, true><<<nwb, 256, 0, stream>>>(h_buf, alpha, invb, rowp, colv,
                                            BI[0], GA[0], BE[0], MU[0], VA[0],
                                            xf16, nullptr, NN);
    // ---- layer 1 (K=256, HC=256, H=4)
    k_mgemm<256, 128><<<dim3(GB, 2), 256, 0, stream>>>(xf16, wTh + 32768, h_buf,
                                                       AS[1], AD[1], als, ald, 4, NN, 256);
    k_att<4><<<nab, 256, 0, stream>>>(als, ald, rowp, colv, alpha, invb, NN);
    k_agg<4, true><<<nwb, 256, 0, stream>>>(h_buf, alpha, invb, rowp, colv,
                                            BI[1], GA[1], BE[1], MU[1], VA[1],
                                            xf16, nullptr, NN);
    // ---- layer 2 (K=256, HC=64, H=1)
    k_mgemm<256, 64><<<dim3(GB, 1), 256, 0, stream>>>(xf16, wTh + 98304, h_buf,
                                                      AS[2], AD[2], als, ald, 1, NN, 64);
    k_att<1><<<nab, 256, 0, stream>>>(als, ald, rowp, colv, alpha, invb, NN);
    k_agg<1, false><<<nwb, 256, 0, stream>>>(h_buf, alpha, invb, rowp, colv,
                                             BI[2], GA[2], BE[2], MU[2], VA[2],
                                             nullptr, xpool, NN);

    // fused readout + MLP (512 threads: 8 node-subsets x 64 dims)
    k_poolfc<<<NGR, 512, 0, stream>>>(xpool, batch, fc1w, fc1b, fc2w, fc2b, fc3w, fc3b,
                                      (float*)d_out, NN);
    (void)in_sizes; (void)n_in; (void)out_size; (void)ws_size;
}

// Round 15
// 475.039 us; speedup vs baseline: 3.1575x; 1.0052x over previous
//
#include <hip/hip_runtime.h>
#include <hip/hip_fp16.h>

typedef unsigned short ushort_t;
typedef unsigned int uint_t;
typedef __attribute__((ext_vector_type(8))) _Float16 half8;
typedef __attribute__((ext_vector_type(4))) float f32x4;

#define NN 50000
#define NE 800000
#define NGR 256

// async global->LDS, 16B per lane; LDS dest = wave-uniform base + lane*16
typedef __attribute__((address_space(3))) unsigned int as3_u32;
typedef const __attribute__((address_space(1))) unsigned int as1_u32c;
__device__ __forceinline__ void gld16(const ushort_t* g, void* lds_base) {
    __builtin_amdgcn_global_load_lds((as1_u32c*)g, (as3_u32*)lds_base, 16, 0, 0);
}

// ---------------- CSR build ----------------
__global__ void k_scan1(const int* __restrict__ deg, int* __restrict__ rowp,
                        int* __restrict__ bsum, int M) {
    __shared__ int sm[256];
    int t = threadIdx.x, i = blockIdx.x * 256 + t;
    int v = (i < M) ? deg[i] + 1 : 0;   // +1 self loop
    sm[t] = v; __syncthreads();
    for (int off = 1; off < 256; off <<= 1) {
        int x = (t >= off) ? sm[t - off] : 0;
        __syncthreads();
        sm[t] += x;
        __syncthreads();
    }
    if (i < M) rowp[i] = sm[t] - v;     // exclusive
    if (t == 255) bsum[blockIdx.x] = sm[255];
}

__global__ void k_scan2(int* bsum, int NB) {
    __shared__ int sm[256];
    int t = threadIdx.x;
    int v = (t < NB) ? bsum[t] : 0;
    sm[t] = v; __syncthreads();
    for (int off = 1; off < 256; off <<= 1) {
        int x = (t >= off) ? sm[t - off] : 0;
        __syncthreads();
        sm[t] += x;
        __syncthreads();
    }
    if (t < NB) bsum[t] = sm[t] - v;    // exclusive block offsets
}

// also zeroes cur (aliases als) for k_fill
__global__ void k_scan3(int* rowp, const int* __restrict__ bsum, int* __restrict__ cur,
                        int M, int total) {
    int i = blockIdx.x * 256 + threadIdx.x;
    if (i < M) { rowp[i] += bsum[blockIdx.x]; cur[i] = 0; }
    if (i == 0) rowp[M] = total;
}

__global__ void k_fill(const int* __restrict__ src, const int* __restrict__ dst,
                       const int* __restrict__ rowp, int* __restrict__ cur,
                       int* __restrict__ colv, int E, int M) {
    int i = blockIdx.x * 256 + threadIdx.x;
    if (i < E) {
        int d = dst[i];
        int pos = rowp[d] + atomicAdd(&cur[d], 1);
        colv[pos] = src[i];
    } else if (i < E + M) {
        int nn = i - E;
        int pos = rowp[nn] + atomicAdd(&cur[nn], 1);
        colv[pos] = nn;
    }
}

// ---- fused prep: x cast -> fp16, weights -> transposed fp16, edge-degree count ----
__global__ void k_prep(const float* __restrict__ x0, __half* __restrict__ xf,
                       const float* __restrict__ W0, const float* __restrict__ W1,
                       const float* __restrict__ W2, __half* __restrict__ th,
                       const int* __restrict__ edst, int* __restrict__ deg) {
    int i = blockIdx.x * 256 + threadIdx.x;
    if (i < 1600000) {
        float4 v = ((const float4*)x0)[i];
        __half2 a = __floats2half2_rn(v.x, v.y);
        __half2 b = __floats2half2_rn(v.z, v.w);
        *(__half2*)(xf + i * 4) = a;
        *(__half2*)(xf + i * 4 + 2) = b;
    } else if (i < 1600000 + 114688) {
        int w = i - 1600000;
        const float* W; int K, NC, idx, base;
        if (w < 32768)      { W = W0; K = 128; NC = 256; idx = w;         base = 0; }
        else if (w < 98304) { W = W1; K = 256; NC = 256; idx = w - 32768; base = 32768; }
        else                { W = W2; K = 256; NC = 64;  idx = w - 98304; base = 98304; }
        int k = idx / NC, n = idx % NC;
        th[base + n * K + k] = __float2half(W[idx]);
    } else if (i < 1600000 + 114688 + NE) {
        atomicAdd(&deg[edst[i - 1714688]], 1);
    }
}

// ------- MFMA GEMM (fp16 single-term) + fused attention-logit epilogue -------
template<int KD, int BN>
__global__ __launch_bounds__(256)
void k_mgemm(const __half* __restrict__ Ax, const __half* __restrict__ Bth,
             __half* __restrict__ Hout,
             const float* __restrict__ a_s, const float* __restrict__ a_d,
             float* __restrict__ als, float* __restrict__ ald,
             int H, int M, int NC) {
    constexpr int BM = 128, BK = 32;
    __shared__ ushort_t sA[BM * BK];
    __shared__ ushort_t sB[BN * BK];
    const int tid = threadIdx.x;
    const int m0 = blockIdx.x * BM;
    const int n0 = blockIdx.y * BN;
    const int wv = tid >> 6, ln = tid & 63;
    const int lrow = ln & 15, lq = ln >> 4;
    constexpr int RT = (BN == 128) ? 4 : 2;
    int wm, wn;
    if constexpr (BN == 128) { wm = (wv >> 1) * 64; wn = (wv & 1) * 64; }
    else                     { wm = wv * 32;        wn = 0; }
    const int roff = ln >> 2;
    const int coff = (ln & 3) * 8;

    f32x4 acc[RT][4] = {};

    for (int k0 = 0; k0 < KD; k0 += BK) {
        #pragma unroll
        for (int ch = 0; ch < 2; ++ch) {
            int rb = wv * 32 + ch * 16;
            size_t ga = (size_t)(m0 + rb + roff) * KD + k0 + coff;
            gld16((const ushort_t*)Ax + ga, &sA[rb * BK]);
        }
        if constexpr (BN == 128) {
            #pragma unroll
            for (int ch = 0; ch < 2; ++ch) {
                int rb = wv * 32 + ch * 16;
                size_t gb = (size_t)(n0 + rb + roff) * KD + k0 + coff;
                gld16((const ushort_t*)Bth + gb, &sB[rb * BK]);
            }
        } else {
            int rb = wv * 16;
            size_t gb = (size_t)(n0 + rb + roff) * KD + k0 + coff;
            gld16((const ushort_t*)Bth + gb, &sB[rb * BK]);
        }
        __syncthreads();
        half8 af[RT], bf[4];
        #pragma unroll
        for (int r = 0; r < RT; ++r)
            af[r] = *(const half8*)&sA[(wm + r * 16 + lrow) * BK + lq * 8];
        #pragma unroll
        for (int c = 0; c < 4; ++c)
            bf[c] = *(const half8*)&sB[(wn + c * 16 + lrow) * BK + lq * 8];
        #pragma unroll
        for (int r = 0; r < RT; ++r)
            #pragma unroll
            for (int c = 0; c < 4; ++c)
                acc[r][c] = __builtin_amdgcn_mfma_f32_16x16x32_f16(af[r], bf[c], acc[r][c], 0, 0, 0);
        __syncthreads();
    }
    // H-store (C/D layout: col=lane&15, row=(lane>>4)*4+reg)
    #pragma unroll
    for (int r = 0; r < RT; ++r) {
        #pragma unroll
        for (int c = 0; c < 4; ++c) {
            int colg = n0 + wn + c * 16 + lrow;
            #pragma unroll
            for (int j = 0; j < 4; ++j) {
                int row = m0 + wm + r * 16 + lq * 4 + j;
                if (row < M) Hout[(size_t)row * NC + colg] = __float2half(acc[r][c][j]);
            }
        }
    }
    // fused attention logits: this wave's 64 cols lie in exactly one head
    int hh = (n0 + wn) >> 6;
    float asv[4], adv[4];
    #pragma unroll
    for (int c = 0; c < 4; ++c) {
        int cg = (n0 + wn + c * 16 + lrow) & 63;
        asv[c] = a_s[hh * 64 + cg];
        adv[c] = a_d[hh * 64 + cg];
    }
    #pragma unroll
    for (int r = 0; r < RT; ++r) {
        #pragma unroll
        for (int j = 0; j < 4; ++j) {
            float ts = 0.f, td = 0.f;
            #pragma unroll
            for (int c = 0; c < 4; ++c) {
                float v = acc[r][c][j];
                ts += v * asv[c];
                td += v * adv[c];
            }
            #pragma unroll
            for (int m = 1; m < 16; m <<= 1) {
                ts += __shfl_xor(ts, m);
                td += __shfl_xor(td, m);
            }
            int row = m0 + wm + r * 16 + lq * 4 + j;
            if (lrow == 0 && row < M) {
                als[row * H + hh] = ts;
                ald[row * H + hh] = td;
            }
        }
    }
}

// ---- per-edge raw exp (stored fp16) + per-node 1/den: 16 lanes/node ----
template<int H>
__global__ __launch_bounds__(256)
void k_att(const float* __restrict__ als, const float* __restrict__ ald,
           const int* __restrict__ rowp, const int* __restrict__ colv,
           __half* __restrict__ alpha, float* __restrict__ invb, int M) {
    int node = blockIdx.x * 16 + (threadIdx.x >> 4);
    if (node >= M) return;
    int l = threadIdx.x & 15;
    int rs = rowp[node], re = rowp[node + 1];
    if constexpr (H == 4) {
        float4 ad = *(const float4*)(ald + node * 4);
        float d0 = 0.f, d1 = 0.f, d2 = 0.f, d3 = 0.f;
        for (int i = rs + l; i < re; i += 16) {
            int s = colv[i];
            float4 av = *(const float4*)(als + s * 4);
            float e0 = av.x + ad.x; e0 = e0 > 0.f ? e0 : 0.2f * e0; e0 = __expf(e0);
            float e1 = av.y + ad.y; e1 = e1 > 0.f ? e1 : 0.2f * e1; e1 = __expf(e1);
            float e2 = av.z + ad.z; e2 = e2 > 0.f ? e2 : 0.2f * e2; e2 = __expf(e2);
            float e3 = av.w + ad.w; e3 = e3 > 0.f ? e3 : 0.2f * e3; e3 = __expf(e3);
            d0 += e0; d1 += e1; d2 += e2; d3 += e3;
            __half2 p0 = __floats2half2_rn(e0, e1);
            __half2 p1 = __floats2half2_rn(e2, e3);
            uint2 pk;
            pk.x = *(uint_t*)&p0; pk.y = *(uint_t*)&p1;
            *(uint2*)(alpha + (size_t)i * 4) = pk;
        }
        #pragma unroll
        for (int off = 1; off < 16; off <<= 1) {
            d0 += __shfl_xor(d0, off); d1 += __shfl_xor(d1, off);
            d2 += __shfl_xor(d2, off); d3 += __shfl_xor(d3, off);
        }
        if (l == 0)
            *(float4*)(invb + node * 4) = make_float4(1.f / (d0 + 1e-16f), 1.f / (d1 + 1e-16f),
                                                      1.f / (d2 + 1e-16f), 1.f / (d3 + 1e-16f));
    } else {
        float ad = ald[node];
        float d = 0.f;
        for (int i = rs + l; i < re; i += 16) {
            int s = colv[i];
            float e = als[s] + ad; e = e > 0.f ? e : 0.2f * e; e = __expf(e);
            d += e;
            alpha[i] = __float2half(e);
        }
        #pragma unroll
        for (int off = 1; off < 16; off <<= 1) d += __shfl_xor(d, off);
        if (l == 0) invb[node] = 1.f / (d + 1e-16f);
    }
}

// ---- aggregation + bias + BN + ELU: fp16 alpha, mix-FMA inner loop ----
// H=4: 2 edges x 32 lanes (x4 unroll);  H=1: 8 edges x 8 lanes (x2 unroll).
template<int H, bool SPLIT>
__global__ __launch_bounds__(256)
void k_agg(const __half* __restrict__ h, const __half* __restrict__ alpha,
           const float* __restrict__ invb, const int* __restrict__ rowp,
           const int* __restrict__ colv,
           const float* __restrict__ bias, const float* __restrict__ gam,
           const float* __restrict__ bet, const float* __restrict__ mu,
           const float* __restrict__ var,
           __half* __restrict__ xo, float* __restrict__ xf, int M) {
    constexpr int HC = H * 64;
    constexpr int EG = 512 / HC;        // edge groups: 2 (H=4), 8 (H=1)
    constexpr int L  = 64 / EG;         // lanes per edge: 32, 8
    constexpr int UN = (H == 4) ? 4 : 2;
    int node = blockIdx.x * 4 + (threadIdx.x >> 6);
    if (node >= M) return;
    int lane = threadIdx.x & 63;
    int rs = rowp[node], re = rowp[node + 1];
    int l = lane & (L - 1), eg = lane / L;
    int hB = (l * 8) >> 6;
    const ushort_t* ab = (const ushort_t*)alpha;
    float acc[8] = {};
    for (int i = rs; i < re; i += EG * UN) {
        #pragma unroll
        for (int k = 0; k < UN; ++k) {
            int idx = i + eg + k * EG;
            bool vld = idx < re;
            int idx2 = vld ? idx : rs;
            int s = colv[idx2];
            ushort_t abits;
            if constexpr (H == 4) abits = ab[(size_t)idx2 * 4 + hB];
            else                  abits = ab[idx2];
            float a = __half2float(__ushort_as_half(vld ? abits : (ushort_t)0));
            uint4 hv = *(const uint4*)(h + (size_t)s * HC + l * 8);
            const __half* hp = (const __half*)&hv;
            #pragma unroll
            for (int j = 0; j < 8; ++j)
                acc[j] = fmaf(a, __half2float(hp[j]), acc[j]);
        }
    }
    #pragma unroll
    for (int off = L; off < 64; off <<= 1) {
        #pragma unroll
        for (int j = 0; j < 8; ++j) acc[j] += __shfl_xor(acc[j], off);
    }
    if (eg == 0) {
        float inv = (H == 4) ? invb[node * 4 + hB] : invb[node];
        float fo[8];
        #pragma unroll
        for (int j = 0; j < 8; ++j) {
            int d = l * 8 + j;
            float o = acc[j] * inv + bias[d];
            float bn = (o - mu[d]) * rsqrtf(var[d] + 1e-5f) * gam[d] + bet[d];
            fo[j] = bn > 0.f ? bn : (__expf(bn) - 1.f);
        }
        if constexpr (SPLIT) {
            __half2 p0 = __floats2half2_rn(fo[0], fo[1]);
            __half2 p1 = __floats2half2_rn(fo[2], fo[3]);
            __half2 p2 = __floats2half2_rn(fo[4], fo[5]);
            __half2 p3 = __floats2half2_rn(fo[6], fo[7]);
            uint4 pk;
            pk.x = *(uint_t*)&p0; pk.y = *(uint_t*)&p1;
            pk.z = *(uint_t*)&p2; pk.w = *(uint_t*)&p3;
            *(uint4*)&xo[(size_t)node * HC + l * 8] = pk;
        } else {
            *(float4*)&xf[(size_t)node * HC + l * 8] = make_float4(fo[0], fo[1], fo[2], fo[3]);
            *(float4*)&xf[(size_t)node * HC + l * 8 + 4] = make_float4(fo[4], fo[5], fo[6], fo[7]);
        }
    }
}

// ---- fused pooling + MLP: 512 threads = 8 node-subsets x 64 dims, LDS reduce ----
__global__ __launch_bounds__(512)
void k_poolfc(const float* __restrict__ x, const int* __restrict__ batch,
              const float* __restrict__ fc1w, const float* __restrict__ fc1b,
              const float* __restrict__ fc2w, const float* __restrict__ fc2b,
              const float* __restrict__ fc3w, const float* __restrict__ fc3b,
              float* __restrict__ out, int M) {
    __shared__ float ssum[8][64];
    __shared__ float smax[8][64];
    __shared__ float hb[192];
    __shared__ float h1[64];
    __shared__ float h2[32];
    int g = blockIdx.x, t = threadIdx.x;
    int d = t & 63, sub = t >> 6;    // 8 subsets
    int lo = 0, hi = M;
    while (lo < hi) { int mid = (lo + hi) >> 1; if (batch[mid] < g) lo = mid + 1; else hi = mid; }
    int s = lo;
    lo = 0; hi = M;
    while (lo < hi) { int mid = (lo + hi) >> 1; if (batch[mid] < g + 1) lo = mid + 1; else hi = mid; }
    int e = lo;
    float sum = 0.f, mx = -3.0e38f;
    for (int n = s + sub; n < e; n += 8) {
        float v = x[(size_t)n * 64 + d];
        sum += v; mx = fmaxf(mx, v);
    }
    ssum[sub][d] = sum; smax[sub][d] = mx;
    __syncthreads();
    if (t < 64) {
        float sm = 0.f, m2 = -3.0e38f;
        #pragma unroll
        for (int k = 0; k < 8; ++k) { sm += ssum[k][t]; m2 = fmaxf(m2, smax[k][t]); }
        int cnt = e - s;
        hb[t] = sm / (float)(cnt > 1 ? cnt : 1);
        hb[64 + t] = (cnt == 0) ? 0.f : m2;
        hb[128 + t] = sm;
    }
    __syncthreads();
    if (t < 64) {
        float s1 = fc1b[t];
        for (int k = 0; k < 192; ++k) s1 += hb[k] * fc1w[k * 64 + t];
        h1[t] = fmaxf(s1, 0.f);
    }
    __syncthreads();
    if (t < 32) {
        float s2 = fc2b[t];
        for (int k = 0; k < 64; ++k) s2 += h1[k] * fc2w[k * 32 + t];
        h2[t] = fmaxf(s2, 0.f);
    }
    __syncthreads();
    if (t == 0) {
        float s3 = fc3b[0];
        for (int k = 0; k < 32; ++k) s3 += h2[k] * fc3w[k];
        out[g] = s3;
    }
}

extern "C" void kernel_launch(void* const* d_in, const int* in_sizes, int n_in,
                              void* d_out, int out_size, void* d_ws, size_t ws_size,
                              hipStream_t stream) {
    const float* x0     = (const float*)d_in[0];
    const int* ei       = (const int*)d_in[1];
    const int* batch    = (const int*)d_in[2];
    const float* W[3]   = {(const float*)d_in[3],  (const float*)d_in[11], (const float*)d_in[19]};
    const float* AS[3]  = {(const float*)d_in[4],  (const float*)d_in[12], (const float*)d_in[20]};
    const float* AD[3]  = {(const float*)d_in[5],  (const float*)d_in[13], (const float*)d_in[21]};
    const float* BI[3]  = {(const float*)d_in[6],  (const float*)d_in[14], (const float*)d_in[22]};
    const float* GA[3]  = {(const float*)d_in[7],  (const float*)d_in[15], (const float*)d_in[23]};
    const float* BE[3]  = {(const float*)d_in[8],  (const float*)d_in[16], (const float*)d_in[24]};
    const float* MU[3]  = {(const float*)d_in[9],  (const float*)d_in[17], (const float*)d_in[25]};
    const float* VA[3]  = {(const float*)d_in[10], (const float*)d_in[18], (const float*)d_in[26]};
    const float* fc1w = (const float*)d_in[27];
    const float* fc1b = (const float*)d_in[28];
    const float* fc2w = (const float*)d_in[29];
    const float* fc2b = (const float*)d_in[30];
    const float* fc3w = (const float*)d_in[31];
    const float* fc3b = (const float*)d_in[32];

    // top of use = 84,085,760 B (< 108,953,600 B proven safe)
    char* ws = (char*)d_ws;
    int*   rowp   = (int*)  (ws);                      // 200,004 B
    int*   colv   = (int*)  (ws + 200704);             // 3,400,000 B
    int*   bsum   = (int*)  (ws + 3600704);            // 1,024 B
    float* als    = (float*)(ws + 3602432);            // 800,000 B
    int*   cur    = (int*)  (ws + 3602432);            // 200,000 B (aliases als; dead before GEMM)
    float* ald    = (float*)(ws + 4402432);            // 800,000 B
    __half* wTh   = (__half*)(ws + 5202432);           // 229,376 B (3 layers packed)
    __half* h_buf = (__half*)(ws + 5661184);           // 25,600,000 B
    __half* xf16  = (__half*)(ws + 31261184);          // 25,624,576 B (50048 rows x 256)
    float* xpool  = (float*)(ws + 56885760);           // 12,800,000 B
    __half* alpha = (__half*)(ws + 69685760);          // 6,800,000 B (850k x 4 fp16)
    float* invb   = (float*)(ws + 83285760);           // 800,000 B -> 84,085,760 B

    const int* esrc = ei;
    const int* edst = ei + NE;
    const int NB_SCAN = (NN + 255) / 256; // 196

    // prep (x cast + W split + deg count; cur zeroed first)
    hipMemsetAsync(cur, 0, NN * sizeof(int), stream);
    k_prep<<<(1600000 + 114688 + NE + 255) / 256, 256, 0, stream>>>(x0, xf16, W[0], W[1], W[2],
                                                                    wTh, edst, cur);
    // CSR build
    k_scan1<<<NB_SCAN, 256, 0, stream>>>(cur, rowp, bsum, NN);
    k_scan2<<<1, 256, 0, stream>>>(bsum, NB_SCAN);
    k_scan3<<<NB_SCAN, 256, 0, stream>>>(rowp, bsum, cur, NN, NE + NN);
    k_fill<<<(NE + NN + 255) / 256, 256, 0, stream>>>(esrc, edst, rowp, cur, colv, NE, NN);

    const int GB = (NN + 127) / 128; // 391
    int nwb = (NN + 3) / 4;          // 12500
    int nab = (NN + 15) / 16;        // 3125

    // ---- layer 0 (K=128, HC=256, H=4)
    k_mgemm<128, 128><<<dim3(GB, 2), 256, 0, stream>>>(xf16, wTh, h_buf,
                                                       AS[0], AD[0], als, ald, 4, NN, 256);
    k_att<4><<<nab, 256, 0, stream>>>(als, ald, rowp, colv, alpha, invb, NN);
    k_agg<4, true><<<nwb, 256, 0, stream>>>(h_buf, alpha, invb, rowp, colv,
                                            BI[0], GA[0], BE[0], MU[0], VA[0],
                                            xf16, nullptr, NN);
    // ---- layer 1 (K=256, HC=256, H=4)
    k_mgemm<256, 128><<<dim3(GB, 2), 256, 0, stream>>>(xf16, wTh + 32768, h_buf,
                                                       AS[1], AD[1], als, ald, 4, NN, 256);
    k_att<4><<<nab, 256, 0, stream>>>(als, ald, rowp, colv, alpha, invb, NN);
    k_agg<4, true><<<nwb, 256, 0, stream>>>(h_buf, alpha, invb, rowp, colv,
                                            BI[1], GA[1], BE[1], MU[1], VA[1],
                                            xf16, nullptr, NN);
    // ---- layer 2 (K=256, HC=64, H=1)
    k_mgemm<256, 64><<<dim3(GB, 1), 256, 0, stream>>>(xf16, wTh + 98304, h_buf,
                                                      AS[2], AD[2], als, ald, 1, NN, 64);
    k_att<1><<<nab, 256, 0, stream>>>(als, ald, rowp, colv, alpha, invb, NN);
    k_agg<1, false><<<nwb, 256, 0, stream>>>(h_buf, alpha, invb, rowp, colv,
                                             BI[2], GA[2], BE[2], MU[2], VA[2],
                                             nullptr, xpool, NN);

    // fused readout + MLP (512 threads: 8 node-subsets x 64 dims)
    k_poolfc<<<NGR, 512, 0, stream>>>(xpool, batch, fc1w, fc1b, fc2w, fc2b, fc3w, fc3b,
                                      (float*)d_out, NN);
    (void)in_sizes; (void)n_in; (void)out_size; (void)ws_size;
}

// Round 17
// 453.427 us; speedup vs baseline: 3.3081x; 1.0477x over previous
//
#include <hip/hip_runtime.h>
#include <hip/hip_fp16.h>

typedef unsigned short ushort_t;
typedef unsigned int uint_t;
typedef __attribute__((ext_vector_type(8))) _Float16 half8;
typedef __attribute__((ext_vector_type(4))) float f32x4;

#define NN 50000
#define NE 800000
#define NGR 256

// async global->LDS, 16B per lane; LDS dest = wave-uniform base + lane*16
typedef __attribute__((address_space(3))) unsigned int as3_u32;
typedef const __attribute__((address_space(1))) unsigned int as1_u32c;
__device__ __forceinline__ void gld16(const ushort_t* g, void* lds_base) {
    __builtin_amdgcn_global_load_lds((as1_u32c*)g, (as3_u32*)lds_base, 16, 0, 0);
}

// ---------------- CSR build ----------------
__global__ void k_scan1(const int* __restrict__ deg, int* __restrict__ rowp,
                        int* __restrict__ bsum, int M) {
    __shared__ int sm[256];
    int t = threadIdx.x, i = blockIdx.x * 256 + t;
    int v = (i < M) ? deg[i] + 1 : 0;   // +1 self loop
    sm[t] = v; __syncthreads();
    for (int off = 1; off < 256; off <<= 1) {
        int x = (t >= off) ? sm[t - off] : 0;
        __syncthreads();
        sm[t] += x;
        __syncthreads();
    }
    if (i < M) rowp[i] = sm[t] - v;     // exclusive
    if (t == 255) bsum[blockIdx.x] = sm[255];
}

__global__ void k_scan2(int* bsum, int NB) {
    __shared__ int sm[256];
    int t = threadIdx.x;
    int v = (t < NB) ? bsum[t] : 0;
    sm[t] = v; __syncthreads();
    for (int off = 1; off < 256; off <<= 1) {
        int x = (t >= off) ? sm[t - off] : 0;
        __syncthreads();
        sm[t] += x;
        __syncthreads();
    }
    if (t < NB) bsum[t] = sm[t] - v;    // exclusive block offsets
}

// also zeroes cur for the fill phase
__global__ void k_scan3(int* rowp, const int* __restrict__ bsum, int* __restrict__ cur,
                        int M, int total) {
    int i = blockIdx.x * 256 + threadIdx.x;
    if (i < M) { rowp[i] += bsum[blockIdx.x]; cur[i] = 0; }
    if (i == 0) rowp[M] = total;
}

// ---- fused prep: x cast -> fp16, weights -> transposed fp16, edge-degree count ----
__global__ void k_prep(const float* __restrict__ x0, __half* __restrict__ xf,
                       const float* __restrict__ W0, const float* __restrict__ W1,
                       const float* __restrict__ W2, __half* __restrict__ th,
                       const int* __restrict__ edst, int* __restrict__ deg) {
    int i = blockIdx.x * 256 + threadIdx.x;
    if (i < 1600000) {
        float4 v = ((const float4*)x0)[i];
        __half2 a = __floats2half2_rn(v.x, v.y);
        __half2 b = __floats2half2_rn(v.z, v.w);
        *(__half2*)(xf + i * 4) = a;
        *(__half2*)(xf + i * 4 + 2) = b;
    } else if (i < 1600000 + 114688) {
        int w = i - 1600000;
        const float* W; int K, NC, idx, base;
        if (w < 32768)      { W = W0; K = 128; NC = 256; idx = w;         base = 0; }
        else if (w < 98304) { W = W1; K = 256; NC = 256; idx = w - 32768; base = 32768; }
        else                { W = W2; K = 256; NC = 64;  idx = w - 98304; base = 98304; }
        int k = idx / NC, n = idx % NC;
        th[base + n * K + k] = __float2half(W[idx]);
    } else if (i < 1600000 + 114688 + NE) {
        atomicAdd(&deg[edst[i - 1714688]], 1);
    }
}

// ------- GEMM body (fp16 single-term) + fused attention-logit epilogue -------
template<int KD, int BN>
__device__ __forceinline__ void gemm_body(int bx, int by,
    const __half* __restrict__ Ax, const __half* __restrict__ Bth,
    __half* __restrict__ Hout, const float* __restrict__ a_s,
    const float* __restrict__ a_d, float* __restrict__ als,
    float* __restrict__ ald, int H, int M, int NC) {
    constexpr int BM = 128, BK = 32;
    __shared__ ushort_t sA[BM * BK];
    __shared__ ushort_t sB[BN * BK];
    const int tid = threadIdx.x;
    const int m0 = bx * BM;
    const int n0 = by * BN;
    const int wv = tid >> 6, ln = tid & 63;
    const int lrow = ln & 15, lq = ln >> 4;
    constexpr int RT = (BN == 128) ? 4 : 2;
    int wm, wn;
    if constexpr (BN == 128) { wm = (wv >> 1) * 64; wn = (wv & 1) * 64; }
    else                     { wm = wv * 32;        wn = 0; }
    const int roff = ln >> 2;
    const int coff = (ln & 3) * 8;

    f32x4 acc[RT][4] = {};

    for (int k0 = 0; k0 < KD; k0 += BK) {
        #pragma unroll
        for (int ch = 0; ch < 2; ++ch) {
            int rb = wv * 32 + ch * 16;
            size_t ga = (size_t)(m0 + rb + roff) * KD + k0 + coff;
            gld16((const ushort_t*)Ax + ga, &sA[rb * BK]);
        }
        if constexpr (BN == 128) {
            #pragma unroll
            for (int ch = 0; ch < 2; ++ch) {
                int rb = wv * 32 + ch * 16;
                size_t gb = (size_t)(n0 + rb + roff) * KD + k0 + coff;
                gld16((const ushort_t*)Bth + gb, &sB[rb * BK]);
            }
        } else {
            int rb = wv * 16;
            size_t gb = (size_t)(n0 + rb + roff) * KD + k0 + coff;
            gld16((const ushort_t*)Bth + gb, &sB[rb * BK]);
        }
        __syncthreads();
        half8 af[RT], bf[4];
        #pragma unroll
        for (int r = 0; r < RT; ++r)
            af[r] = *(const half8*)&sA[(wm + r * 16 + lrow) * BK + lq * 8];
        #pragma unroll
        for (int c = 0; c < 4; ++c)
            bf[c] = *(const half8*)&sB[(wn + c * 16 + lrow) * BK + lq * 8];
        #pragma unroll
        for (int r = 0; r < RT; ++r)
            #pragma unroll
            for (int c = 0; c < 4; ++c)
                acc[r][c] = __builtin_amdgcn_mfma_f32_16x16x32_f16(af[r], bf[c], acc[r][c], 0, 0, 0);
        __syncthreads();
    }
    // H-store (C/D layout: col=lane&15, row=(lane>>4)*4+reg)
    #pragma unroll
    for (int r = 0; r < RT; ++r) {
        #pragma unroll
        for (int c = 0; c < 4; ++c) {
            int colg = n0 + wn + c * 16 + lrow;
            #pragma unroll
            for (int j = 0; j < 4; ++j) {
                int row = m0 + wm + r * 16 + lq * 4 + j;
                if (row < M) Hout[(size_t)row * NC + colg] = __float2half(acc[r][c][j]);
            }
        }
    }
    // fused attention logits: this wave's 64 cols lie in exactly one head
    int hh = (n0 + wn) >> 6;
    float asv[4], adv[4];
    #pragma unroll
    for (int c = 0; c < 4; ++c) {
        int cg = (n0 + wn + c * 16 + lrow) & 63;
        asv[c] = a_s[hh * 64 + cg];
        adv[c] = a_d[hh * 64 + cg];
    }
    #pragma unroll
    for (int r = 0; r < RT; ++r) {
        #pragma unroll
        for (int j = 0; j < 4; ++j) {
            float ts = 0.f, td = 0.f;
            #pragma unroll
            for (int c = 0; c < 4; ++c) {
                float v = acc[r][c][j];
                ts += v * asv[c];
                td += v * adv[c];
            }
            #pragma unroll
            for (int m = 1; m < 16; m <<= 1) {
                ts += __shfl_xor(ts, m);
                td += __shfl_xor(td, m);
            }
            int row = m0 + wm + r * 16 + lq * 4 + j;
            if (lrow == 0 && row < M) {
                als[row * H + hh] = ts;
                ald[row * H + hh] = td;
            }
        }
    }
}

template<int KD, int BN>
__global__ __launch_bounds__(256)
void k_mgemm(const __half* __restrict__ Ax, const __half* __restrict__ Bth,
             __half* __restrict__ Hout,
             const float* __restrict__ a_s, const float* __restrict__ a_d,
             float* __restrict__ als, float* __restrict__ ald,
             int H, int M, int NC) {
    gemm_body<KD, BN>(blockIdx.x, blockIdx.y, Ax, Bth, Hout, a_s, a_d, als, ald, H, M, NC);
}

// ---- co-scheduled GEMM-L0 + CSR fill: blocks [0,782) gemm, rest fill ----
// (cur must NOT alias anything the GEMM writes — dedicated region.)
__global__ __launch_bounds__(256)
void k_gf(const __half* __restrict__ Ax, const __half* __restrict__ Bth,
          __half* __restrict__ Hout,
          const float* __restrict__ a_s, const float* __restrict__ a_d,
          float* __restrict__ als, float* __restrict__ ald, int M,
          const int* __restrict__ esrc, const int* __restrict__ edst,
          const int* __restrict__ rowp, int* __restrict__ cur,
          int* __restrict__ colv) {
    if (blockIdx.x < 782) {
        gemm_body<128, 128>(blockIdx.x >> 1, blockIdx.x & 1, Ax, Bth, Hout,
                            a_s, a_d, als, ald, 4, M, 256);
    } else {
        int i = (blockIdx.x - 782) * 256 + threadIdx.x;
        if (i < NE) {
            int d = edst[i];
            int pos = rowp[d] + atomicAdd(&cur[d], 1);
            colv[pos] = esrc[i];
        } else if (i < NE + NN) {
            int nn = i - NE;
            int pos = rowp[nn] + atomicAdd(&cur[nn], 1);
            colv[pos] = nn;
        }
    }
}

// ---- per-edge raw exp (stored fp16) + per-node 1/den: 16 lanes/node ----
template<int H>
__global__ __launch_bounds__(256)
void k_att(const float* __restrict__ als, const float* __restrict__ ald,
           const int* __restrict__ rowp, const int* __restrict__ colv,
           __half* __restrict__ alpha, float* __restrict__ invb, int M) {
    int node = blockIdx.x * 16 + (threadIdx.x >> 4);
    if (node >= M) return;
    int l = threadIdx.x & 15;
    int rs = rowp[node], re = rowp[node + 1];
    if constexpr (H == 4) {
        float4 ad = *(const float4*)(ald + node * 4);
        float d0 = 0.f, d1 = 0.f, d2 = 0.f, d3 = 0.f;
        for (int i = rs + l; i < re; i += 16) {
            int s = colv[i];
            float4 av = *(const float4*)(als + s * 4);
            float e0 = av.x + ad.x; e0 = e0 > 0.f ? e0 : 0.2f * e0; e0 = __expf(e0);
            float e1 = av.y + ad.y; e1 = e1 > 0.f ? e1 : 0.2f * e1; e1 = __expf(e1);
            float e2 = av.z + ad.z; e2 = e2 > 0.f ? e2 : 0.2f * e2; e2 = __expf(e2);
            float e3 = av.w + ad.w; e3 = e3 > 0.f ? e3 : 0.2f * e3; e3 = __expf(e3);
            d0 += e0; d1 += e1; d2 += e2; d3 += e3;
            __half2 p0 = __floats2half2_rn(e0, e1);
            __half2 p1 = __floats2half2_rn(e2, e3);
            uint2 pk;
            pk.x = *(uint_t*)&p0; pk.y = *(uint_t*)&p1;
            *(uint2*)(alpha + (size_t)i * 4) = pk;
        }
        #pragma unroll
        for (int off = 1; off < 16; off <<= 1) {
            d0 += __shfl_xor(d0, off); d1 += __shfl_xor(d1, off);
            d2 += __shfl_xor(d2, off); d3 += __shfl_xor(d3, off);
        }
        if (l == 0)
            *(float4*)(invb + node * 4) = make_float4(1.f / (d0 + 1e-16f), 1.f / (d1 + 1e-16f),
                                                      1.f / (d2 + 1e-16f), 1.f / (d3 + 1e-16f));
    } else {
        float ad = ald[node];
        float d = 0.f;
        for (int i = rs + l; i < re; i += 16) {
            int s = colv[i];
            float e = als[s] + ad; e = e > 0.f ? e : 0.2f * e; e = __expf(e);
            d += e;
            alpha[i] = __float2half(e);
        }
        #pragma unroll
        for (int off = 1; off < 16; off <<= 1) d += __shfl_xor(d, off);
        if (l == 0) invb[node] = 1.f / (d + 1e-16f);
    }
}

// ---- aggregation + bias + BN + ELU: fp16 alpha, mix-FMA inner loop ----
// H=4: 2 edges x 32 lanes (x4 unroll);  H=1: 8 edges x 8 lanes (x2 unroll).
template<int H, bool SPLIT>
__global__ __launch_bounds__(256)
void k_agg(const __half* __restrict__ h, const __half* __restrict__ alpha,
           const float* __restrict__ invb, const int* __restrict__ rowp,
           const int* __restrict__ colv,
           const float* __restrict__ bias, const float* __restrict__ gam,
           const float* __restrict__ bet, const float* __restrict__ mu,
           const float* __restrict__ var,
           __half* __restrict__ xo, float* __restrict__ xf, int M) {
    constexpr int HC = H * 64;
    constexpr int EG = 512 / HC;        // edge groups: 2 (H=4), 8 (H=1)
    constexpr int L  = 64 / EG;         // lanes per edge: 32, 8
    constexpr int UN = (H == 4) ? 4 : 2;
    int node = blockIdx.x * 4 + (threadIdx.x >> 6);
    if (node >= M) return;
    int lane = threadIdx.x & 63;
    int rs = rowp[node], re = rowp[node + 1];
    int l = lane & (L - 1), eg = lane / L;
    int hB = (l * 8) >> 6;
    const ushort_t* ab = (const ushort_t*)alpha;
    float acc[8] = {};
    for (int i = rs; i < re; i += EG * UN) {
        #pragma unroll
        for (int k = 0; k < UN; ++k) {
            int idx = i + eg + k * EG;
            bool vld = idx < re;
            int idx2 = vld ? idx : rs;
            int s = colv[idx2];
            ushort_t abits;
            if constexpr (H == 4) abits = ab[(size_t)idx2 * 4 + hB];
            else                  abits = ab[idx2];
            float a = __half2float(__ushort_as_half(vld ? abits : (ushort_t)0));
            uint4 hv = *(const uint4*)(h + (size_t)s * HC + l * 8);
            const __half* hp = (const __half*)&hv;
            #pragma unroll
            for (int j = 0; j < 8; ++j)
                acc[j] = fmaf(a, __half2float(hp[j]), acc[j]);
        }
    }
    #pragma unroll
    for (int off = L; off < 64; off <<= 1) {
        #pragma unroll
        for (int j = 0; j < 8; ++j) acc[j] += __shfl_xor(acc[j], off);
    }
    if (eg == 0) {
        float inv = (H == 4) ? invb[node * 4 + hB] : invb[node];
        float fo[8];
        #pragma unroll
        for (int j = 0; j < 8; ++j) {
            int d = l * 8 + j;
            float o = acc[j] * inv + bias[d];
            float bn = (o - mu[d]) * rsqrtf(var[d] + 1e-5f) * gam[d] + bet[d];
            fo[j] = bn > 0.f ? bn : (__expf(bn) - 1.f);
        }
        if constexpr (SPLIT) {
            __half2 p0 = __floats2half2_rn(fo[0], fo[1]);
            __half2 p1 = __floats2half2_rn(fo[2], fo[3]);
            __half2 p2 = __floats2half2_rn(fo[4], fo[5]);
            __half2 p3 = __floats2half2_rn(fo[6], fo[7]);
            uint4 pk;
            pk.x = *(uint_t*)&p0; pk.y = *(uint_t*)&p1;
            pk.z = *(uint_t*)&p2; pk.w = *(uint_t*)&p3;
            *(uint4*)&xo[(size_t)node * HC + l * 8] = pk;
        } else {
            *(float4*)&xf[(size_t)node * HC + l * 8] = make_float4(fo[0], fo[1], fo[2], fo[3]);
            *(float4*)&xf[(size_t)node * HC + l * 8 + 4] = make_float4(fo[4], fo[5], fo[6], fo[7]);
        }
    }
}

// ---- fused pooling + MLP: 512 threads = 8 node-subsets x 64 dims, LDS reduce ----
__global__ __launch_bounds__(512)
void k_poolfc(const float* __restrict__ x, const int* __restrict__ batch,
              const float* __restrict__ fc1w, const float* __restrict__ fc1b,
              const float* __restrict__ fc2w, const float* __restrict__ fc2b,
              const float* __restrict__ fc3w, const float* __restrict__ fc3b,
              float* __restrict__ out, int M) {
    __shared__ float ssum[8][64];
    __shared__ float smax[8][64];
    __shared__ float hb[192];
    __shared__ float h1[64];
    __shared__ float h2[32];
    int g = blockIdx.x, t = threadIdx.x;
    int d = t & 63, sub = t >> 6;    // 8 subsets
    int lo = 0, hi = M;
    while (lo < hi) { int mid = (lo + hi) >> 1; if (batch[mid] < g) lo = mid + 1; else hi = mid; }
    int s = lo;
    lo = 0; hi = M;
    while (lo < hi) { int mid = (lo + hi) >> 1; if (batch[mid] < g + 1) lo = mid + 1; else hi = mid; }
    int e = lo;
    float sum = 0.f, mx = -3.0e38f;
    for (int n = s + sub; n < e; n += 8) {
        float v = x[(size_t)n * 64 + d];
        sum += v; mx = fmaxf(mx, v);
    }
    ssum[sub][d] = sum; smax[sub][d] = mx;
    __syncthreads();
    if (t < 64) {
        float sm = 0.f, m2 = -3.0e38f;
        #pragma unroll
        for (int k = 0; k < 8; ++k) { sm += ssum[k][t]; m2 = fmaxf(m2, smax[k][t]); }
        int cnt = e - s;
        hb[t] = sm / (float)(cnt > 1 ? cnt : 1);
        hb[64 + t] = (cnt == 0) ? 0.f : m2;
        hb[128 + t] = sm;
    }
    __syncthreads();
    if (t < 64) {
        float s1 = fc1b[t];
        for (int k = 0; k < 192; ++k) s1 += hb[k] * fc1w[k * 64 + t];
        h1[t] = fmaxf(s1, 0.f);
    }
    __syncthreads();
    if (t < 32) {
        float s2 = fc2b[t];
        for (int k = 0; k < 64; ++k) s2 += h1[k] * fc2w[k * 32 + t];
        h2[t] = fmaxf(s2, 0.f);
    }
    __syncthreads();
    if (t == 0) {
        float s3 = fc3b[0];
        for (int k = 0; k < 32; ++k) s3 += h2[k] * fc3w[k];
        out[g] = s3;
    }
}

extern "C" void kernel_launch(void* const* d_in, const int* in_sizes, int n_in,
                              void* d_out, int out_size, void* d_ws, size_t ws_size,
                              hipStream_t stream) {
    const float* x0     = (const float*)d_in[0];
    const int* ei       = (const int*)d_in[1];
    const int* batch    = (const int*)d_in[2];
    const float* W[3]   = {(const float*)d_in[3],  (const float*)d_in[11], (const float*)d_in[19]};
    const float* AS[3]  = {(const float*)d_in[4],  (const float*)d_in[12], (const float*)d_in[20]};
    const float* AD[3]  = {(const float*)d_in[5],  (const float*)d_in[13], (const float*)d_in[21]};
    const float* BI[3]  = {(const float*)d_in[6],  (const float*)d_in[14], (const float*)d_in[22]};
    const float* GA[3]  = {(const float*)d_in[7],  (const float*)d_in[15], (const float*)d_in[23]};
    const float* BE[3]  = {(const float*)d_in[8],  (const float*)d_in[16], (const float*)d_in[24]};
    const float* MU[3]  = {(const float*)d_in[9],  (const float*)d_in[17], (const float*)d_in[25]};
    const float* VA[3]  = {(const float*)d_in[10], (const float*)d_in[18], (const float*)d_in[26]};
    const float* fc1w = (const float*)d_in[27];
    const float* fc1b = (const float*)d_in[28];
    const float* fc2w = (const float*)d_in[29];
    const float* fc2b = (const float*)d_in[30];
    const float* fc3w = (const float*)d_in[31];
    const float* fc3b = (const float*)d_in[32];

    // top of use = 84,285,760 B (< 108,953,600 B proven safe).
    // cur has a DEDICATED region (k_gf runs fill concurrently with GEMM-L0's
    // als/ald stores — aliasing cur over als was R16's crash).
    char* ws = (char*)d_ws;
    int*   rowp   = (int*)  (ws);                      // 200,004 B
    int*   colv   = (int*)  (ws + 200704);             // 3,400,000 B
    int*   bsum   = (int*)  (ws + 3600704);            // 1,024 B
    float* als    = (float*)(ws + 3602432);            // 800,000 B
    float* ald    = (float*)(ws + 4402432);            // 800,000 B
    __half* wTh   = (__half*)(ws + 5202432);           // 229,376 B (3 layers packed)
    __half* h_buf = (__half*)(ws + 5661184);           // 25,600,000 B
    __half* xf16  = (__half*)(ws + 31261184);          // 25,624,576 B (50048 rows x 256)
    float* xpool  = (float*)(ws + 56885760);           // 12,800,000 B
    __half* alpha = (__half*)(ws + 69685760);          // 6,800,000 B (850k x 4 fp16)
    float* invb   = (float*)(ws + 83285760);           // 800,000 B
    int*   cur    = (int*)  (ws + 84085760);           // 200,000 B -> 84,285,760 B

    const int* esrc = ei;
    const int* edst = ei + NE;
    const int NB_SCAN = (NN + 255) / 256; // 196

    // prep (x cast + W split + deg count; cur zeroed first)
    hipMemsetAsync(cur, 0, NN * sizeof(int), stream);
    k_prep<<<(1600000 + 114688 + NE + 255) / 256, 256, 0, stream>>>(x0, xf16, W[0], W[1], W[2],
                                                                    wTh, edst, cur);
    // CSR scan (fill is co-scheduled with GEMM L0 below)
    k_scan1<<<NB_SCAN, 256, 0, stream>>>(cur, rowp, bsum, NN);
    k_scan2<<<1, 256, 0, stream>>>(bsum, NB_SCAN);
    k_scan3<<<NB_SCAN, 256, 0, stream>>>(rowp, bsum, cur, NN, NE + NN);

    const int GB = (NN + 127) / 128; // 391
    const int FILLB = (NE + NN + 255) / 256; // 3321
    int nwb = (NN + 3) / 4;          // 12500
    int nab = (NN + 15) / 16;        // 3125

    // ---- layer 0 (K=128, HC=256, H=4): GEMM co-scheduled with CSR fill
    k_gf<<<782 + FILLB, 256, 0, stream>>>(xf16, wTh, h_buf, AS[0], AD[0], als, ald, NN,
                                          esrc, edst, rowp, cur, colv);
    k_att<4><<<nab, 256, 0, stream>>>(als, ald, rowp, colv, alpha, invb, NN);
    k_agg<4, true><<<nwb, 256, 0, stream>>>(h_buf, alpha, invb, rowp, colv,
                                            BI[0], GA[0], BE[0], MU[0], VA[0],
                                            xf16, nullptr, NN);
    // ---- layer 1 (K=256, HC=256, H=4)
    k_mgemm<256, 128><<<dim3(GB, 2), 256, 0, stream>>>(xf16, wTh + 32768, h_buf,
                                                       AS[1], AD[1], als, ald, 4, NN, 256);
    k_att<4><<<nab, 256, 0, stream>>>(als, ald, rowp, colv, alpha, invb, NN);
    k_agg<4, true><<<nwb, 256, 0, stream>>>(h_buf, alpha, invb, rowp, colv,
                                            BI[1], GA[1], BE[1], MU[1], VA[1],
                                            xf16, nullptr, NN);
    // ---- layer 2 (K=256, HC=64, H=1)
    k_mgemm<256, 64><<<dim3(GB, 1), 256, 0, stream>>>(xf16, wTh + 98304, h_buf,
                                                      AS[2], AD[2], als, ald, 1, NN, 64);
    k_att<1><<<nab, 256, 0, stream>>>(als, ald, rowp, colv, alpha, invb, NN);
    k_agg<1, false><<<nwb, 256, 0, stream>>>(h_buf, alpha, invb, rowp, colv,
                                             BI[2], GA[2], BE[2], MU[2], VA[2],
                                             nullptr, xpool, NN);

    // fused readout + MLP (512 threads: 8 node-subsets x 64 dims)
    k_poolfc<<<NGR, 512, 0, stream>>>(xpool, batch, fc1w, fc1b, fc2w, fc2b, fc3w, fc3b,
                                      (float*)d_out, NN);
    (void)in_sizes; (void)n_in; (void)out_size; (void)ws_size;
}